// Round 1
// baseline (177.018 us; speedup 1.0000x reference)
//
#include <hip/hip_runtime.h>

typedef short short8 __attribute__((ext_vector_type(8)));
typedef __bf16 bf16x8 __attribute__((ext_vector_type(8)));
typedef float f32x4 __attribute__((ext_vector_type(4)));

__device__ __forceinline__ short f2bf(float f) {
  unsigned u = __builtin_bit_cast(unsigned, f);
  u = (u + 0x7FFFu + ((u >> 16) & 1u)) >> 16;
  return (short)u;
}
__device__ __forceinline__ f32x4 mfma16(short8 a, short8 b, f32x4 c) {
  return __builtin_amdgcn_mfma_f32_16x16x32_bf16(
      __builtin_bit_cast(bf16x8, a), __builtin_bit_cast(bf16x8, b), c, 0, 0, 0);
}
__device__ __forceinline__ float sigm(float x) { return 1.0f / (1.0f + __expf(-x)); }

// ---------------------------------------------------------------------------
// Weight pre-pack: f32 [CO][CI][3][3] -> bf16 [K/8][CO][8], K = tap*CI + ci,
// tap = kh*3+kw.  Entry e = kb8*CO + n holds 8 consecutive k (same tap).
// seg1: conv_w 320x128 (46080 entries), seg2: proj_w 192x64 (13824),
// seg3: out_w 64x64 (4608).  Total 64512 entries = 252 blocks * 256.
// ---------------------------------------------------------------------------
__global__ void pack_w(const float* __restrict__ w1, const float* __restrict__ w2,
                       const float* __restrict__ w3, short* __restrict__ out) {
  int e = blockIdx.x * 256 + threadIdx.x;
  if (e < 46080) {
    int kb8 = e / 320, n = e % 320;
    short8 v;
#pragma unroll
    for (int j = 0; j < 8; ++j) {
      int k = kb8 * 8 + j;
      int tap = k >> 7, ci = k & 127;
      v[j] = f2bf(w1[(n * 128 + ci) * 9 + tap]);
    }
    *(short8*)&out[e * 8] = v;
    return;
  }
  e -= 46080;
  if (e < 13824) {
    int kb8 = e / 192, n = e % 192;
    short8 v;
#pragma unroll
    for (int j = 0; j < 8; ++j) {
      int k = kb8 * 8 + j;
      int tap = k >> 6, ci = k & 63;
      v[j] = f2bf(w2[(n * 64 + ci) * 9 + tap]);
    }
    *(short8*)&out[(46080 + e) * 8] = v;
    return;
  }
  e -= 13824;
  {
    int kb8 = e / 64, n = e % 64;
    short8 v;
#pragma unroll
    for (int j = 0; j < 8; ++j) {
      int k = kb8 * 8 + j;
      int tap = k >> 6, ci = k & 63;
      v[j] = f2bf(w3[(n * 64 + ci) * 9 + tap]);
    }
    *(short8*)&out[(46080 + 13824 + e) * 8] = v;
  }
}

// ---------------------------------------------------------------------------
// One workgroup per batch sample. 256 threads = 4 waves.
// comb: zero-padded 10x10 x 128ch bf16 tile, channel slot rotated by pix*8
//       so ds_read_b128 of 8 consecutive ci stays <=2-way bank conflicted.
// Wave w owns output channels [16w,16w+16) for every conv (N-tiles strided
// by 4), so gates i/f/o/g/a and conv3 output for a (p,ch) live in ONE lane.
// ---------------------------------------------------------------------------
__launch_bounds__(256, 2)
__global__ void cell_k(
    const float* __restrict__ input, const float* __restrict__ h_cur,
    const float* __restrict__ c_cur, const float* __restrict__ ck,
    const float* __restrict__ cv, const int* __restrict__ amask,
    const float* __restrict__ conv_b, const float* __restrict__ proj_b,
    const float* __restrict__ out_b, const float* __restrict__ ln_w,
    const float* __restrict__ ln_b, const float* __restrict__ pos_w,
    const float* __restrict__ pos_b,
    const short* __restrict__ pk1, const short* __restrict__ pk2,
    const short* __restrict__ pk3,
    float* __restrict__ o_h, float* __restrict__ o_c,
    float* __restrict__ o_k, float* __restrict__ o_v) {
  __shared__ short comb[12800];            // 25.6 KB padded bf16 tile
  __shared__ float Xb[4160];               // c_cur -> k_new -> input restage
  __shared__ float Qb[4160];               // q_scaled -> h out
  __shared__ float Vb[4160];               // v_new -> c out
  __shared__ float sc[64], wt[64], red[8];

  const int b = blockIdx.x;
  const int tid = threadIdx.x;
  const int wave = tid >> 6, lane = tid & 63;
  const int col = lane & 15, g4 = lane >> 4;
  const int ch = wave * 16 + col;          // this lane's output channel

  // ---- Phase 0: stage input/h into comb (bf16), c_cur into Xb ----
#pragma unroll
  for (int i = 0; i < 16; ++i) {
    int idx = i * 256 + tid;
    int c = idx >> 6, p = idx & 63;
    int pp = ((p >> 3) + 1) * 10 + (p & 7) + 1;
    comb[pp * 128 + ((c + pp * 8) & 127)] = f2bf(input[b * 4096 + idx]);
    comb[pp * 128 + ((c + 64 + pp * 8) & 127)] = f2bf(h_cur[b * 4096 + idx]);
    Xb[c * 65 + p] = c_cur[b * 4096 + idx];
  }
  for (int i = tid; i < 4608; i += 256) {   // zero pad ring (36 pixels x 128)
    int pr = i >> 7, c = i & 127;
    int pp = (pr < 10) ? pr
             : (pr < 20) ? (80 + pr)
             : (pr < 28) ? ((pr - 19) * 10)
                         : ((pr - 27) * 10 + 9);
    comb[pp * 128 + c] = 0;
  }
  __syncthreads();

  // ---- Phase 1: conv1 gates, M=64 N=320 K=1152 ----
  f32x4 acc1[4][5];
#pragma unroll
  for (int m = 0; m < 4; ++m)
#pragma unroll
    for (int g = 0; g < 5; ++g) acc1[m][g] = (f32x4){0.f, 0.f, 0.f, 0.f};

  for (int s = 0; s < 36; ++s) {
    int tap = s >> 2, cib = s & 3;
    int kh = tap / 3, kw = tap % 3;
    short8 a[4];
#pragma unroll
    for (int m = 0; m < 4; ++m) {
      int p = m * 16 + col;
      int pp = ((p >> 3) + kh) * 10 + (p & 7) + kw;
      int slot = (cib * 32 + g4 * 8 + pp * 8) & 127;
      a[m] = *(const short8*)&comb[pp * 128 + slot];
    }
    int kb8 = s * 4 + g4;
    short8 bb[5];
#pragma unroll
    for (int g = 0; g < 5; ++g)
      bb[g] = *(const short8*)&pk1[(kb8 * 320 + g * 64 + ch) * 8];
#pragma unroll
    for (int m = 0; m < 4; ++m)
#pragma unroll
      for (int g = 0; g < 5; ++g) acc1[m][g] = mfma16(a[m], bb[g], acc1[m][g]);
  }

  // gates in-register (lane owns i,f,o,g,a for its (p,ch))
  float ct_r[16], o_r[16], a_r[16];
  {
    float bi0 = conv_b[ch], bi1 = conv_b[64 + ch], bi2 = conv_b[128 + ch];
    float bi3 = conv_b[192 + ch], bi4 = conv_b[256 + ch];
#pragma unroll
    for (int m = 0; m < 4; ++m)
#pragma unroll
      for (int r = 0; r < 4; ++r) {
        int p = m * 16 + g4 * 4 + r;
        float iv = sigm(acc1[m][0][r] + bi0);
        float fv = sigm(acc1[m][1][r] + bi1);
        float ov = sigm(acc1[m][2][r] + bi2);
        float gv = tanhf(acc1[m][3][r] + bi3);
        float av = sigm(acc1[m][4][r] + bi4);
        ct_r[m * 4 + r] = fv * Xb[ch * 65 + p] + iv * gv;
        o_r[m * 4 + r] = ov;
        a_r[m * 4 + r] = av;
      }
  }
  __syncthreads();  // c_cur consumed; Xb reusable

  // ---- Phase 2: conv2 kqv, M=64 N=192 K=576 ----
  f32x4 acc2[4][3];
#pragma unroll
  for (int m = 0; m < 4; ++m)
#pragma unroll
    for (int g = 0; g < 3; ++g) acc2[m][g] = (f32x4){0.f, 0.f, 0.f, 0.f};

  for (int s = 0; s < 18; ++s) {
    int tap = s >> 1, cib = s & 1;
    int kh = tap / 3, kw = tap % 3;
    short8 a[4];
#pragma unroll
    for (int m = 0; m < 4; ++m) {
      int p = m * 16 + col;
      int pp = ((p >> 3) + kh) * 10 + (p & 7) + kw;
      int slot = (cib * 32 + g4 * 8 + pp * 8) & 127;
      a[m] = *(const short8*)&comb[pp * 128 + slot];
    }
    int kb8 = s * 4 + g4;
    short8 bb[3];
#pragma unroll
    for (int g = 0; g < 3; ++g)
      bb[g] = *(const short8*)&pk2[(kb8 * 192 + g * 64 + ch) * 8];
#pragma unroll
    for (int m = 0; m < 4; ++m)
#pragma unroll
      for (int g = 0; g < 3; ++g) acc2[m][g] = mfma16(a[m], bb[g], acc2[m][g]);
  }
  {
    float pb0 = proj_b[ch], pb1 = proj_b[64 + ch], pb2 = proj_b[128 + ch];
    const float rsq = 0.044194173824159216f;  // 1/sqrt(512)
#pragma unroll
    for (int m = 0; m < 4; ++m)
#pragma unroll
      for (int r = 0; r < 4; ++r) {
        int p = m * 16 + g4 * 4 + r;
        Xb[ch * 65 + p] = acc2[m][0][r] + pb0;          // k_new
        Qb[ch * 65 + p] = (acc2[m][1][r] + pb1) * rsq;  // q_scaled
        Vb[ch * 65 + p] = acc2[m][2][r] + pb2;          // v_new
      }
  }
  __syncthreads();

  // ---- Phase 3: scores + k stream-copy (32 threads per head) ----
  const int hd = tid >> 5;   // head 0..7
  const int l32 = tid & 31;
  float qv[16];
#pragma unroll
  for (int i = 0; i < 16; ++i) {
    int d = l32 + 32 * i;
    qv[i] = Qb[(hd * 8 + (d >> 6)) * 65 + (d & 63)];
  }
#pragma unroll 1
  for (int m = 0; m < 7; ++m) {
    const float* src = ck + ((size_t)((b * 8 + m + 1) * 8 + hd)) * 512;
    float* dst = o_k + ((size_t)((b * 8 + m) * 8 + hd)) * 512;
    const float* pw = pos_w + m * 4096 + hd * 512;
    float part = 0.f;
#pragma unroll
    for (int i = 0; i < 16; ++i) {
      int d = l32 + 32 * i;
      float kf = src[d] + pw[d];
      dst[d] = kf;
      part = fmaf(qv[i], kf, part);
    }
#pragma unroll
    for (int off = 16; off >= 1; off >>= 1) part += __shfl_xor(part, off);
    if (l32 == 0) {
      float msk = amask[(b * 8 + hd) * 8 + m] ? -__builtin_inff() : 0.0f;
      sc[hd * 8 + m] = part + pos_b[m * 8 + hd] + msk;
    }
  }
  {  // slot 7 = new k (LDS) + pos_w[7]; mask forced to +5.0
    float* dst = o_k + ((size_t)((b * 8 + 7) * 8 + hd)) * 512;
    const float* pw = pos_w + 7 * 4096 + hd * 512;
    float part = 0.f;
#pragma unroll
    for (int i = 0; i < 16; ++i) {
      int d = l32 + 32 * i;
      float kf = Xb[(hd * 8 + (d >> 6)) * 65 + (d & 63)] + pw[d];
      dst[d] = kf;
      part = fmaf(qv[i], kf, part);
    }
#pragma unroll
    for (int off = 16; off >= 1; off >>= 1) part += __shfl_xor(part, off);
    if (l32 == 0) sc[hd * 8 + 7] = part + pos_b[7 * 8 + hd] + 5.0f;
  }
  __syncthreads();

  if (tid < 8) {  // softmax per head
    float mx = -__builtin_inff();
#pragma unroll
    for (int m = 0; m < 8; ++m) mx = fmaxf(mx, sc[tid * 8 + m]);
    float e[8], s = 0.f;
#pragma unroll
    for (int m = 0; m < 8; ++m) { e[m] = __expf(sc[tid * 8 + m] - mx); s += e[m]; }
    float inv = 1.0f / s;
#pragma unroll
    for (int m = 0; m < 8; ++m) wt[tid * 8 + m] = e[m] * inv;
  }
  __syncthreads();

  // ---- Phase 4: input restage + v stream-copy + PV + attn->comb ----
#pragma unroll
  for (int i = 0; i < 16; ++i) {
    int idx = i * 256 + tid;
    Xb[(idx >> 6) * 65 + (idx & 63)] = input[b * 4096 + idx];
  }
  float at[16];
#pragma unroll
  for (int i = 0; i < 16; ++i) at[i] = 0.f;
#pragma unroll 1
  for (int m = 0; m < 7; ++m) {
    float w_m = wt[hd * 8 + m];
    const float* src = cv + ((size_t)((b * 8 + m + 1) * 8 + hd)) * 512;
    float* dst = o_v + ((size_t)((b * 8 + m) * 8 + hd)) * 512;
#pragma unroll
    for (int i = 0; i < 16; ++i) {
      int d = l32 + 32 * i;
      float vv = src[d];
      dst[d] = vv;
      at[i] = fmaf(w_m, vv, at[i]);
    }
  }
  {
    float w7 = wt[hd * 8 + 7];
    float* dst = o_v + ((size_t)((b * 8 + 7) * 8 + hd)) * 512;
#pragma unroll
    for (int i = 0; i < 16; ++i) {
      int d = l32 + 32 * i;
      float vv = Vb[(hd * 8 + (d >> 6)) * 65 + (d & 63)];
      dst[d] = vv;
      at[i] = fmaf(w7, vv, at[i]);
    }
  }
#pragma unroll
  for (int i = 0; i < 16; ++i) {  // attn -> padded bf16 tile (ci 0..63)
    int d = l32 + 32 * i;
    int c = hd * 8 + (d >> 6), p = d & 63;
    int pp = ((p >> 3) + 1) * 10 + (p & 7) + 1;
    comb[pp * 128 + ((c + pp * 8) & 127)] = f2bf(at[i]);
  }
  __syncthreads();

  // ---- Phase 5: conv3, M=64 N=64 K=576 ----
  f32x4 acc3[4];
#pragma unroll
  for (int m = 0; m < 4; ++m) acc3[m] = (f32x4){0.f, 0.f, 0.f, 0.f};
  for (int s = 0; s < 18; ++s) {
    int tap = s >> 1, cib = s & 1;
    int kh = tap / 3, kw = tap % 3;
    short8 a[4];
#pragma unroll
    for (int m = 0; m < 4; ++m) {
      int p = m * 16 + col;
      int pp = ((p >> 3) + kh) * 10 + (p & 7) + kw;
      int slot = (cib * 32 + g4 * 8 + pp * 8) & 127;
      a[m] = *(const short8*)&comb[pp * 128 + slot];
    }
    int kb8 = s * 4 + g4;
    short8 bb = *(const short8*)&pk3[(kb8 * 64 + ch) * 8];
#pragma unroll
    for (int m = 0; m < 4; ++m) acc3[m] = mfma16(a[m], bb, acc3[m]);
  }

  // residual + LN stats
  float ov_[16], s1 = 0.f, s2 = 0.f;
  {
    float ob = out_b[ch];
#pragma unroll
    for (int m = 0; m < 4; ++m)
#pragma unroll
      for (int r = 0; r < 4; ++r) {
        int p = m * 16 + g4 * 4 + r;
        float v = acc3[m][r] + ob + Xb[ch * 65 + p];
        ov_[m * 4 + r] = v;
        s1 += v;
        s2 += v * v;
      }
  }
#pragma unroll
  for (int off = 32; off >= 1; off >>= 1) {
    s1 += __shfl_xor(s1, off);
    s2 += __shfl_xor(s2, off);
  }
  if (lane == 0) { red[wave] = s1; red[4 + wave] = s2; }
  __syncthreads();
  float ts1 = red[0] + red[1] + red[2] + red[3];
  float ts2 = red[4] + red[5] + red[6] + red[7];
  float mu = ts1 * (1.0f / 4096.0f);
  float var = ts2 * (1.0f / 4096.0f) - mu * mu;
  float rstd = rsqrtf(var + 1e-5f);

  // LN + LSTM epilogue; h->Qb, c->Vb for coalesced writeout
#pragma unroll
  for (int m = 0; m < 4; ++m)
#pragma unroll
    for (int r = 0; r < 4; ++r) {
      int p = m * 16 + g4 * 4 + r;
      float oln = (ov_[m * 4 + r] - mu) * rstd * ln_w[ch * 64 + p] + ln_b[ch * 64 + p];
      float cn = ct_r[m * 4 + r] + a_r[m * 4 + r] * tanhf(oln);
      float hv = o_r[m * 4 + r] * tanhf(cn);
      Qb[ch * 65 + p] = hv;
      Vb[ch * 65 + p] = cn;
    }
  __syncthreads();
#pragma unroll
  for (int i = 0; i < 16; ++i) {
    int idx = i * 256 + tid;
    int c = idx >> 6, p = idx & 63;
    o_h[b * 4096 + idx] = Qb[c * 65 + p];
    o_c[b * 4096 + idx] = Vb[c * 65 + p];
  }
}

extern "C" void kernel_launch(void* const* d_in, const int* in_sizes, int n_in,
                              void* d_out, int out_size, void* d_ws, size_t ws_size,
                              hipStream_t stream) {
  (void)in_sizes; (void)n_in; (void)out_size; (void)ws_size;
  const float* input  = (const float*)d_in[0];
  const float* h_cur  = (const float*)d_in[1];
  const float* c_cur  = (const float*)d_in[2];
  const float* ck     = (const float*)d_in[3];
  const float* cv     = (const float*)d_in[4];
  const int*   amask  = (const int*)d_in[5];
  const float* conv_w = (const float*)d_in[6];
  const float* conv_b = (const float*)d_in[7];
  const float* proj_w = (const float*)d_in[8];
  const float* proj_b = (const float*)d_in[9];
  const float* out_w  = (const float*)d_in[10];
  const float* out_b  = (const float*)d_in[11];
  const float* ln_w   = (const float*)d_in[12];
  const float* ln_b   = (const float*)d_in[13];
  const float* pos_w  = (const float*)d_in[14];
  const float* pos_b  = (const float*)d_in[15];

  short* pk = (short*)d_ws;                 // 516096 bf16 = 1.03 MB
  float* o_h = (float*)d_out;
  float* o_c = o_h + 2097152;
  float* o_k = o_h + 4194304;
  float* o_v = o_h + 20971520;

  pack_w<<<252, 256, 0, stream>>>(conv_w, proj_w, out_w, pk);
  cell_k<<<512, 256, 0, stream>>>(input, h_cur, c_cur, ck, cv, amask,
                                  conv_b, proj_b, out_b, ln_w, ln_b,
                                  pos_w, pos_b,
                                  pk, pk + 368640, pk + 479232,
                                  o_h, o_c, o_k, o_v);
}

// Round 2
// 127.123 us; speedup vs baseline: 1.3925x; 1.3925x over previous
//
#include <hip/hip_runtime.h>

typedef short short8 __attribute__((ext_vector_type(8)));
typedef __bf16 bf16x8 __attribute__((ext_vector_type(8)));
typedef float f32x4 __attribute__((ext_vector_type(4)));

__device__ __forceinline__ short f2bf(float f) {
  unsigned u = __builtin_bit_cast(unsigned, f);
  u = (u + 0x7FFFu + ((u >> 16) & 1u)) >> 16;
  return (short)u;
}
__device__ __forceinline__ f32x4 mfma16(short8 a, short8 b, f32x4 c) {
  return __builtin_amdgcn_mfma_f32_16x16x32_bf16(
      __builtin_bit_cast(bf16x8, a), __builtin_bit_cast(bf16x8, b), c, 0, 0, 0);
}
__device__ __forceinline__ float sigm(float x) { return 1.0f / (1.0f + __expf(-x)); }
__device__ __forceinline__ float ftanh(float x) {
  return 1.0f - 2.0f / (1.0f + __expf(2.0f * x));
}
__device__ __forceinline__ f32x4 ntld4(const float* p) {
  return __builtin_nontemporal_load((const f32x4*)p);
}
__device__ __forceinline__ void ntst4(float* p, f32x4 v) {
  __builtin_nontemporal_store(v, (f32x4*)p);
}

// ---------------------------------------------------------------------------
// Weight pre-pack: f32 [CO][CI][3][3] -> bf16 [K/8][CO][8], K = tap*CI + ci.
// ---------------------------------------------------------------------------
__global__ void pack_w(const float* __restrict__ w1, const float* __restrict__ w2,
                       const float* __restrict__ w3, short* __restrict__ out) {
  int e = blockIdx.x * 256 + threadIdx.x;
  if (e < 46080) {
    int kb8 = e / 320, n = e % 320;
    short8 v;
#pragma unroll
    for (int j = 0; j < 8; ++j) {
      int k = kb8 * 8 + j;
      int tap = k >> 7, ci = k & 127;
      v[j] = f2bf(w1[(n * 128 + ci) * 9 + tap]);
    }
    *(short8*)&out[e * 8] = v;
    return;
  }
  e -= 46080;
  if (e < 13824) {
    int kb8 = e / 192, n = e % 192;
    short8 v;
#pragma unroll
    for (int j = 0; j < 8; ++j) {
      int k = kb8 * 8 + j;
      int tap = k >> 6, ci = k & 63;
      v[j] = f2bf(w2[(n * 64 + ci) * 9 + tap]);
    }
    *(short8*)&out[(46080 + e) * 8] = v;
    return;
  }
  e -= 13824;
  {
    int kb8 = e / 64, n = e % 64;
    short8 v;
#pragma unroll
    for (int j = 0; j < 8; ++j) {
      int k = kb8 * 8 + j;
      int tap = k >> 6, ci = k & 63;
      v[j] = f2bf(w3[(n * 64 + ci) * 9 + tap]);
    }
    *(short8*)&out[(46080 + 13824 + e) * 8] = v;
  }
}

// ---------------------------------------------------------------------------
// One workgroup (512 thr = 8 waves) per sample. Wave (wc,wm): wc=wave>>1 owns
// channels [16wc,16wc+16), wm=wave&1 owns pixel halves {wm*2, wm*2+1}.
// Phase 3/4: wave == head (8 heads), 64 lanes stream 512 floats as float4.
// __launch_bounds__(512,4): 16 waves/CU (2 blocks x 8 waves), VGPR<=128.
// ---------------------------------------------------------------------------
__launch_bounds__(512, 4)
__global__ void cell_k(
    const float* __restrict__ input, const float* __restrict__ h_cur,
    const float* __restrict__ c_cur, const float* __restrict__ ck,
    const float* __restrict__ cv, const int* __restrict__ amask,
    const float* __restrict__ conv_b, const float* __restrict__ proj_b,
    const float* __restrict__ out_b, const float* __restrict__ ln_w,
    const float* __restrict__ ln_b, const float* __restrict__ pos_w,
    const float* __restrict__ pos_b,
    const short* __restrict__ pk1, const short* __restrict__ pk2,
    const short* __restrict__ pk3,
    float* __restrict__ o_h, float* __restrict__ o_c,
    float* __restrict__ o_k, float* __restrict__ o_v) {
  __shared__ short comb[12800];            // 25.6 KB padded bf16 tile
  __shared__ float Xb[4160];               // c_cur -> k_new -> input restage
  __shared__ float Qb[4160];               // q_scaled -> h out
  __shared__ float Vb[4160];               // v_new -> c out
  __shared__ float sc[64], wt[64], red[16];

  const int b = blockIdx.x;
  const int tid = threadIdx.x;
  const int wave = tid >> 6, lane = tid & 63;
  const int col = lane & 15, g4 = lane >> 4;
  const int wc = wave >> 1, wm = wave & 1;
  const int ch = wc * 16 + col;            // this lane's output channel

  // ---- Phase 0: stage input/h into comb (bf16), c_cur into Xb ----
#pragma unroll
  for (int i = 0; i < 2; ++i) {
    int idx = (tid + 512 * i) * 4;
    int c = idx >> 6, p0 = idx & 63;
    f32x4 vi = *(const f32x4*)&input[b * 4096 + idx];
    f32x4 vh = *(const f32x4*)&h_cur[b * 4096 + idx];
    f32x4 vc = *(const f32x4*)&c_cur[b * 4096 + idx];
#pragma unroll
    for (int j = 0; j < 4; ++j) {
      int p = p0 + j;
      int pp = ((p >> 3) + 1) * 10 + (p & 7) + 1;
      comb[pp * 128 + ((c + pp * 8) & 127)] = f2bf(vi[j]);
      comb[pp * 128 + ((c + 64 + pp * 8) & 127)] = f2bf(vh[j]);
      Xb[c * 65 + p] = vc[j];
    }
  }
  for (int i = tid; i < 4608; i += 512) {   // zero pad ring (36 pixels x 128)
    int pr = i >> 7, c = i & 127;
    int pp = (pr < 10) ? pr
             : (pr < 20) ? (80 + pr)
             : (pr < 28) ? ((pr - 19) * 10)
                         : ((pr - 27) * 10 + 9);
    comb[pp * 128 + c] = 0;
  }
  __syncthreads();

  // ---- Phase 1: conv1 gates, M=64 N=320 K=1152 (wave does 2 M-tiles) ----
  f32x4 acc1[2][5];
#pragma unroll
  for (int m = 0; m < 2; ++m)
#pragma unroll
    for (int g = 0; g < 5; ++g) acc1[m][g] = (f32x4){0.f, 0.f, 0.f, 0.f};

  short8 bb1[5];
#pragma unroll
  for (int g = 0; g < 5; ++g)
    bb1[g] = *(const short8*)&pk1[((g4)*320 + g * 64 + ch) * 8];

  for (int s = 0; s < 36; ++s) {
    short8 bbn[5];
    if (s < 35) {
      int kb8 = (s + 1) * 4 + g4;
#pragma unroll
      for (int g = 0; g < 5; ++g)
        bbn[g] = *(const short8*)&pk1[(kb8 * 320 + g * 64 + ch) * 8];
    }
    int tap = s >> 2, cib = s & 3;
    int kh = tap / 3, kw = tap % 3;
    short8 a[2];
#pragma unroll
    for (int m = 0; m < 2; ++m) {
      int p = (wm * 2 + m) * 16 + col;
      int pp = ((p >> 3) + kh) * 10 + (p & 7) + kw;
      int slot = (cib * 32 + g4 * 8 + pp * 8) & 127;
      a[m] = *(const short8*)&comb[pp * 128 + slot];
    }
#pragma unroll
    for (int m = 0; m < 2; ++m)
#pragma unroll
      for (int g = 0; g < 5; ++g) acc1[m][g] = mfma16(a[m], bb1[g], acc1[m][g]);
    if (s < 35) {
#pragma unroll
      for (int g = 0; g < 5; ++g) bb1[g] = bbn[g];
    }
  }

  // gates in-register (lane owns i,f,o,g,a for its (p,ch))
  float ct_r[8], o_r[8], a_r[8];
  {
    float bi0 = conv_b[ch], bi1 = conv_b[64 + ch], bi2 = conv_b[128 + ch];
    float bi3 = conv_b[192 + ch], bi4 = conv_b[256 + ch];
#pragma unroll
    for (int m = 0; m < 2; ++m)
#pragma unroll
      for (int r = 0; r < 4; ++r) {
        int p = (wm * 2 + m) * 16 + g4 * 4 + r;
        float iv = sigm(acc1[m][0][r] + bi0);
        float fv = sigm(acc1[m][1][r] + bi1);
        float ov = sigm(acc1[m][2][r] + bi2);
        float gv = ftanh(acc1[m][3][r] + bi3);
        float av = sigm(acc1[m][4][r] + bi4);
        ct_r[m * 4 + r] = fv * Xb[ch * 65 + p] + iv * gv;
        o_r[m * 4 + r] = ov;
        a_r[m * 4 + r] = av;
      }
  }
  __syncthreads();  // c_cur consumed; Xb reusable

  // ---- Phase 2: conv2 kqv, M=64 N=192 K=576 ----
  f32x4 acc2[2][3];
#pragma unroll
  for (int m = 0; m < 2; ++m)
#pragma unroll
    for (int g = 0; g < 3; ++g) acc2[m][g] = (f32x4){0.f, 0.f, 0.f, 0.f};

  short8 bb2[3];
#pragma unroll
  for (int g = 0; g < 3; ++g)
    bb2[g] = *(const short8*)&pk2[((g4)*192 + g * 64 + ch) * 8];

  for (int s = 0; s < 18; ++s) {
    short8 bbn[3];
    if (s < 17) {
      int kb8 = (s + 1) * 4 + g4;
#pragma unroll
      for (int g = 0; g < 3; ++g)
        bbn[g] = *(const short8*)&pk2[(kb8 * 192 + g * 64 + ch) * 8];
    }
    int tap = s >> 1, cib = s & 1;
    int kh = tap / 3, kw = tap % 3;
    short8 a[2];
#pragma unroll
    for (int m = 0; m < 2; ++m) {
      int p = (wm * 2 + m) * 16 + col;
      int pp = ((p >> 3) + kh) * 10 + (p & 7) + kw;
      int slot = (cib * 32 + g4 * 8 + pp * 8) & 127;
      a[m] = *(const short8*)&comb[pp * 128 + slot];
    }
#pragma unroll
    for (int m = 0; m < 2; ++m)
#pragma unroll
      for (int g = 0; g < 3; ++g) acc2[m][g] = mfma16(a[m], bb2[g], acc2[m][g]);
    if (s < 17) {
#pragma unroll
      for (int g = 0; g < 3; ++g) bb2[g] = bbn[g];
    }
  }
  {
    float pb0 = proj_b[ch], pb1 = proj_b[64 + ch], pb2 = proj_b[128 + ch];
    const float rsq = 0.044194173824159216f;  // 1/sqrt(512)
#pragma unroll
    for (int m = 0; m < 2; ++m)
#pragma unroll
      for (int r = 0; r < 4; ++r) {
        int p = (wm * 2 + m) * 16 + g4 * 4 + r;
        Xb[ch * 65 + p] = acc2[m][0][r] + pb0;          // k_new
        Qb[ch * 65 + p] = (acc2[m][1][r] + pb1) * rsq;  // q_scaled
        Vb[ch * 65 + p] = acc2[m][2][r] + pb2;          // v_new
      }
  }
  __syncthreads();

  // ---- Phase 3: scores + k stream-copy (wave == head, 64 lanes) ----
  const int hd = wave;
  f32x4 qv[2];
#pragma unroll
  for (int i = 0; i < 2; ++i) {
    int d4 = lane + 64 * i;
    int cs = d4 >> 4, p0 = (d4 & 15) * 4;
#pragma unroll
    for (int j = 0; j < 4; ++j) qv[i][j] = Qb[(hd * 8 + cs) * 65 + p0 + j];
  }
  for (int m = 0; m < 7; ++m) {
    const float* src = ck + ((size_t)((b * 8 + m + 1) * 8 + hd)) * 512;
    float* dst = o_k + ((size_t)((b * 8 + m) * 8 + hd)) * 512;
    const float* pw = pos_w + m * 4096 + hd * 512;
    float part = 0.f;
#pragma unroll
    for (int i = 0; i < 2; ++i) {
      int d4 = lane + 64 * i;
      f32x4 kf = ntld4(src + d4 * 4);
      f32x4 pv = *(const f32x4*)&pw[d4 * 4];
      kf = kf + pv;
      ntst4(dst + d4 * 4, kf);
#pragma unroll
      for (int j = 0; j < 4; ++j) part = fmaf(qv[i][j], kf[j], part);
    }
#pragma unroll
    for (int off = 32; off >= 1; off >>= 1) part += __shfl_xor(part, off);
    if (lane == 0) {
      float msk = amask[(b * 8 + hd) * 8 + m] ? -__builtin_inff() : 0.0f;
      sc[hd * 8 + m] = part + pos_b[m * 8 + hd] + msk;
    }
  }
  {  // slot 7 = new k (LDS) + pos_w[7]; mask forced to +5.0
    float* dst = o_k + ((size_t)((b * 8 + 7) * 8 + hd)) * 512;
    const float* pw = pos_w + 7 * 4096 + hd * 512;
    float part = 0.f;
#pragma unroll
    for (int i = 0; i < 2; ++i) {
      int d4 = lane + 64 * i;
      int cs = d4 >> 4, p0 = (d4 & 15) * 4;
      f32x4 kf;
#pragma unroll
      for (int j = 0; j < 4; ++j) kf[j] = Xb[(hd * 8 + cs) * 65 + p0 + j];
      f32x4 pv = *(const f32x4*)&pw[d4 * 4];
      kf = kf + pv;
      ntst4(dst + d4 * 4, kf);
#pragma unroll
      for (int j = 0; j < 4; ++j) part = fmaf(qv[i][j], kf[j], part);
    }
#pragma unroll
    for (int off = 32; off >= 1; off >>= 1) part += __shfl_xor(part, off);
    if (lane == 0) sc[hd * 8 + 7] = part + pos_b[7 * 8 + hd] + 5.0f;
  }
  __syncthreads();

  if (tid < 8) {  // softmax per head
    float mx = -__builtin_inff();
#pragma unroll
    for (int m = 0; m < 8; ++m) mx = fmaxf(mx, sc[tid * 8 + m]);
    float e[8], s = 0.f;
#pragma unroll
    for (int m = 0; m < 8; ++m) { e[m] = __expf(sc[tid * 8 + m] - mx); s += e[m]; }
    float inv = 1.0f / s;
#pragma unroll
    for (int m = 0; m < 8; ++m) wt[tid * 8 + m] = e[m] * inv;
  }
  __syncthreads();

  // ---- Phase 4: input restage + v stream-copy + PV + attn->comb ----
#pragma unroll
  for (int i = 0; i < 2; ++i) {
    int idx = (tid + 512 * i) * 4;
    int c = idx >> 6, p0 = idx & 63;
    f32x4 vi = *(const f32x4*)&input[b * 4096 + idx];
#pragma unroll
    for (int j = 0; j < 4; ++j) Xb[c * 65 + p0 + j] = vi[j];
  }
  f32x4 at[2];
  at[0] = (f32x4){0.f, 0.f, 0.f, 0.f};
  at[1] = (f32x4){0.f, 0.f, 0.f, 0.f};
  for (int m = 0; m < 7; ++m) {
    float w_m = wt[hd * 8 + m];
    const float* src = cv + ((size_t)((b * 8 + m + 1) * 8 + hd)) * 512;
    float* dst = o_v + ((size_t)((b * 8 + m) * 8 + hd)) * 512;
#pragma unroll
    for (int i = 0; i < 2; ++i) {
      int d4 = lane + 64 * i;
      f32x4 vv = ntld4(src + d4 * 4);
      ntst4(dst + d4 * 4, vv);
      at[i] += vv * w_m;
    }
  }
  {
    float w7 = wt[hd * 8 + 7];
    float* dst = o_v + ((size_t)((b * 8 + 7) * 8 + hd)) * 512;
#pragma unroll
    for (int i = 0; i < 2; ++i) {
      int d4 = lane + 64 * i;
      int cs = d4 >> 4, p0 = (d4 & 15) * 4;
      f32x4 vv;
#pragma unroll
      for (int j = 0; j < 4; ++j) vv[j] = Vb[(hd * 8 + cs) * 65 + p0 + j];
      ntst4(dst + d4 * 4, vv);
      at[i] += vv * w7;
    }
  }
#pragma unroll
  for (int i = 0; i < 2; ++i) {  // attn -> padded bf16 tile (ci 0..63)
    int d4 = lane + 64 * i;
    int c = hd * 8 + (d4 >> 4), p0 = (d4 & 15) * 4;
#pragma unroll
    for (int j = 0; j < 4; ++j) {
      int p = p0 + j;
      int pp = ((p >> 3) + 1) * 10 + (p & 7) + 1;
      comb[pp * 128 + ((c + pp * 8) & 127)] = f2bf(at[i][j]);
    }
  }
  __syncthreads();

  // ---- Phase 5: conv3, M=64 N=64 K=576 ----
  f32x4 acc3[2];
  acc3[0] = (f32x4){0.f, 0.f, 0.f, 0.f};
  acc3[1] = (f32x4){0.f, 0.f, 0.f, 0.f};
  short8 bb3 = *(const short8*)&pk3[((g4)*64 + ch) * 8];
  for (int s = 0; s < 18; ++s) {
    short8 bbn;
    if (s < 17) {
      int kb8 = (s + 1) * 4 + g4;
      bbn = *(const short8*)&pk3[(kb8 * 64 + ch) * 8];
    }
    int tap = s >> 1, cib = s & 1;
    int kh = tap / 3, kw = tap % 3;
    short8 a[2];
#pragma unroll
    for (int m = 0; m < 2; ++m) {
      int p = (wm * 2 + m) * 16 + col;
      int pp = ((p >> 3) + kh) * 10 + (p & 7) + kw;
      int slot = (cib * 32 + g4 * 8 + pp * 8) & 127;
      a[m] = *(const short8*)&comb[pp * 128 + slot];
    }
#pragma unroll
    for (int m = 0; m < 2; ++m) acc3[m] = mfma16(a[m], bb3, acc3[m]);
    if (s < 17) bb3 = bbn;
  }

  // residual + LN stats
  float ov_[8], s1 = 0.f, s2 = 0.f;
  {
    float ob = out_b[ch];
#pragma unroll
    for (int m = 0; m < 2; ++m)
#pragma unroll
      for (int r = 0; r < 4; ++r) {
        int p = (wm * 2 + m) * 16 + g4 * 4 + r;
        float v = acc3[m][r] + ob + Xb[ch * 65 + p];
        ov_[m * 4 + r] = v;
        s1 += v;
        s2 += v * v;
      }
  }
#pragma unroll
  for (int off = 32; off >= 1; off >>= 1) {
    s1 += __shfl_xor(s1, off);
    s2 += __shfl_xor(s2, off);
  }
  if (lane == 0) { red[wave] = s1; red[8 + wave] = s2; }
  __syncthreads();
  float ts1 = 0.f, ts2 = 0.f;
#pragma unroll
  for (int w = 0; w < 8; ++w) { ts1 += red[w]; ts2 += red[8 + w]; }
  float mu = ts1 * (1.0f / 4096.0f);
  float var = ts2 * (1.0f / 4096.0f) - mu * mu;
  float rstd = rsqrtf(var + 1e-5f);

  // LN + LSTM epilogue; h->Qb, c->Vb for coalesced writeout
#pragma unroll
  for (int m = 0; m < 2; ++m)
#pragma unroll
    for (int r = 0; r < 4; ++r) {
      int p = (wm * 2 + m) * 16 + g4 * 4 + r;
      float oln = (ov_[m * 4 + r] - mu) * rstd * ln_w[ch * 64 + p] + ln_b[ch * 64 + p];
      float cn = ct_r[m * 4 + r] + a_r[m * 4 + r] * ftanh(oln);
      float hv = o_r[m * 4 + r] * ftanh(cn);
      Qb[ch * 65 + p] = hv;
      Vb[ch * 65 + p] = cn;
    }
  __syncthreads();
#pragma unroll
  for (int i = 0; i < 2; ++i) {
    int idx = (tid + 512 * i) * 4;
    int c = idx >> 6, p0 = idx & 63;
    f32x4 hv, cvv;
#pragma unroll
    for (int j = 0; j < 4; ++j) {
      hv[j] = Qb[c * 65 + p0 + j];
      cvv[j] = Vb[c * 65 + p0 + j];
    }
    *(f32x4*)&o_h[b * 4096 + idx] = hv;
    *(f32x4*)&o_c[b * 4096 + idx] = cvv;
  }
}

extern "C" void kernel_launch(void* const* d_in, const int* in_sizes, int n_in,
                              void* d_out, int out_size, void* d_ws, size_t ws_size,
                              hipStream_t stream) {
  (void)in_sizes; (void)n_in; (void)out_size; (void)ws_size;
  const float* input  = (const float*)d_in[0];
  const float* h_cur  = (const float*)d_in[1];
  const float* c_cur  = (const float*)d_in[2];
  const float* ck     = (const float*)d_in[3];
  const float* cv     = (const float*)d_in[4];
  const int*   amask  = (const int*)d_in[5];
  const float* conv_w = (const float*)d_in[6];
  const float* conv_b = (const float*)d_in[7];
  const float* proj_w = (const float*)d_in[8];
  const float* proj_b = (const float*)d_in[9];
  const float* out_w  = (const float*)d_in[10];
  const float* out_b  = (const float*)d_in[11];
  const float* ln_w   = (const float*)d_in[12];
  const float* ln_b   = (const float*)d_in[13];
  const float* pos_w  = (const float*)d_in[14];
  const float* pos_b  = (const float*)d_in[15];

  short* pk = (short*)d_ws;                 // 516096 bf16 = 1.03 MB
  float* o_h = (float*)d_out;
  float* o_c = o_h + 2097152;
  float* o_k = o_h + 4194304;
  float* o_v = o_h + 20971520;

  pack_w<<<252, 256, 0, stream>>>(conv_w, proj_w, out_w, pk);
  cell_k<<<512, 512, 0, stream>>>(input, h_cur, c_cur, ck, cv, amask,
                                  conv_b, proj_b, out_b, ln_w, ln_b,
                                  pos_w, pos_b,
                                  pk, pk + 368640, pk + 479232,
                                  o_h, o_c, o_k, o_v);
}

// Round 3
// 113.717 us; speedup vs baseline: 1.5566x; 1.1179x over previous
//
#include <hip/hip_runtime.h>

typedef short short8 __attribute__((ext_vector_type(8)));
typedef __bf16 bf16x8 __attribute__((ext_vector_type(8)));
typedef float f32x4 __attribute__((ext_vector_type(4)));

__device__ __forceinline__ short f2bf(float f) {
  unsigned u = __builtin_bit_cast(unsigned, f);
  u = (u + 0x7FFFu + ((u >> 16) & 1u)) >> 16;
  return (short)u;
}
__device__ __forceinline__ f32x4 mfma16(short8 a, short8 b, f32x4 c) {
  return __builtin_amdgcn_mfma_f32_16x16x32_bf16(
      __builtin_bit_cast(bf16x8, a), __builtin_bit_cast(bf16x8, b), c, 0, 0, 0);
}
__device__ __forceinline__ float sigm(float x) { return 1.0f / (1.0f + __expf(-x)); }
__device__ __forceinline__ float ftanh(float x) {
  return 1.0f - 2.0f / (1.0f + __expf(2.0f * x));
}
__device__ __forceinline__ f32x4 ntld4(const float* p) {
  return __builtin_nontemporal_load((const f32x4*)p);
}
__device__ __forceinline__ void ntst4(float* p, f32x4 v) {
  __builtin_nontemporal_store(v, (f32x4*)p);
}

// ---------------------------------------------------------------------------
// Weight pre-pack: f32 [CO][CI][3][3] -> bf16 [K/8][CO][8], K = tap*CI + ci.
// ---------------------------------------------------------------------------
__global__ void pack_w(const float* __restrict__ w1, const float* __restrict__ w2,
                       const float* __restrict__ w3, short* __restrict__ out) {
  int e = blockIdx.x * 256 + threadIdx.x;
  if (e < 46080) {
    int kb8 = e / 320, n = e % 320;
    short8 v;
#pragma unroll
    for (int j = 0; j < 8; ++j) {
      int k = kb8 * 8 + j;
      int tap = k >> 7, ci = k & 127;
      v[j] = f2bf(w1[(n * 128 + ci) * 9 + tap]);
    }
    *(short8*)&out[e * 8] = v;
    return;
  }
  e -= 46080;
  if (e < 13824) {
    int kb8 = e / 192, n = e % 192;
    short8 v;
#pragma unroll
    for (int j = 0; j < 8; ++j) {
      int k = kb8 * 8 + j;
      int tap = k >> 6, ci = k & 63;
      v[j] = f2bf(w2[(n * 64 + ci) * 9 + tap]);
    }
    *(short8*)&out[(46080 + e) * 8] = v;
    return;
  }
  e -= 13824;
  {
    int kb8 = e / 64, n = e % 64;
    short8 v;
#pragma unroll
    for (int j = 0; j < 8; ++j) {
      int k = kb8 * 8 + j;
      int tap = k >> 6, ci = k & 63;
      v[j] = f2bf(w3[(n * 64 + ci) * 9 + tap]);
    }
    *(short8*)&out[(46080 + 13824 + e) * 8] = v;
  }
}

// ---------------------------------------------------------------------------
// Kernel A: conv2 (kqv projection) per sample. 512 thr = 8 waves.
// Writes q (scaled, +bias) -> q_out (o_h scratch region, [b][ch*64+p]),
// k_new+pos_w[7]+bias -> o_k slot 7, v_new+bias -> o_v slot 7 (coalesced via
// LDS restage; slot-7 region is contiguous 4096 floats with same ch*64+p map).
// ---------------------------------------------------------------------------
__launch_bounds__(512, 4)
__global__ void kqv_k(const float* __restrict__ input,
                      const float* __restrict__ proj_b,
                      const float* __restrict__ pos_w,
                      const short* __restrict__ pk2,
                      float* __restrict__ q_out, float* __restrict__ o_k,
                      float* __restrict__ o_v) {
  __shared__ short comb[6400];   // 10x10 x 64ch bf16, rotated
  __shared__ float Xk[4160], Xq[4160], Xv[4160];

  const int b = blockIdx.x;
  const int tid = threadIdx.x;
  const int wave = tid >> 6, lane = tid & 63;
  const int col = lane & 15, g4 = lane >> 4;
  const int wc = wave >> 1, wm = wave & 1;
  const int ch = wc * 16 + col;

  // stage input
#pragma unroll
  for (int i = 0; i < 2; ++i) {
    int idx = (tid + 512 * i) * 4;
    int c = idx >> 6, p0 = idx & 63;
    f32x4 vi = *(const f32x4*)&input[b * 4096 + idx];
#pragma unroll
    for (int j = 0; j < 4; ++j) {
      int p = p0 + j;
      int pp = ((p >> 3) + 1) * 10 + (p & 7) + 1;
      comb[pp * 64 + ((c + pp * 8) & 63)] = f2bf(vi[j]);
    }
  }
  for (int i = tid; i < 2304; i += 512) {  // zero pad ring: 36 pixels x 64
    int pr = i >> 6, c = i & 63;
    int pp = (pr < 10) ? pr
             : (pr < 20) ? (80 + pr)
             : (pr < 28) ? ((pr - 19) * 10)
                         : ((pr - 27) * 10 + 9);
    comb[pp * 64 + c] = 0;
  }
  __syncthreads();

  f32x4 acc2[2][3];
#pragma unroll
  for (int m = 0; m < 2; ++m)
#pragma unroll
    for (int g = 0; g < 3; ++g) acc2[m][g] = (f32x4){0.f, 0.f, 0.f, 0.f};

  short8 bb2[3];
#pragma unroll
  for (int g = 0; g < 3; ++g)
    bb2[g] = *(const short8*)&pk2[((g4)*192 + g * 64 + ch) * 8];

  for (int s = 0; s < 18; ++s) {
    short8 bbn[3];
    if (s < 17) {
      int kb8 = (s + 1) * 4 + g4;
#pragma unroll
      for (int g = 0; g < 3; ++g)
        bbn[g] = *(const short8*)&pk2[(kb8 * 192 + g * 64 + ch) * 8];
    }
    int tap = s >> 1, cib = s & 1;
    int kh = tap / 3, kw = tap % 3;
    short8 a[2];
#pragma unroll
    for (int m = 0; m < 2; ++m) {
      int p = (wm * 2 + m) * 16 + col;
      int pp = ((p >> 3) + kh) * 10 + (p & 7) + kw;
      int slot = (cib * 32 + g4 * 8 + pp * 8) & 63;
      a[m] = *(const short8*)&comb[pp * 64 + slot];
    }
#pragma unroll
    for (int m = 0; m < 2; ++m)
#pragma unroll
      for (int g = 0; g < 3; ++g) acc2[m][g] = mfma16(a[m], bb2[g], acc2[m][g]);
    if (s < 17) {
#pragma unroll
      for (int g = 0; g < 3; ++g) bb2[g] = bbn[g];
    }
  }
  {
    float pb0 = proj_b[ch], pb1 = proj_b[64 + ch], pb2 = proj_b[128 + ch];
    const float rsq = 0.044194173824159216f;  // 1/sqrt(512)
#pragma unroll
    for (int m = 0; m < 2; ++m)
#pragma unroll
      for (int r = 0; r < 4; ++r) {
        int p = (wm * 2 + m) * 16 + g4 * 4 + r;
        // pos_w[7][hd*512 + (ch&7)*64 + p] == pos_w[7*4096 + ch*64 + p]
        Xk[ch * 65 + p] = acc2[m][0][r] + pb0 + pos_w[7 * 4096 + ch * 64 + p];
        Xq[ch * 65 + p] = (acc2[m][1][r] + pb1) * rsq;
        Xv[ch * 65 + p] = acc2[m][2][r] + pb2;
      }
  }
  __syncthreads();

  const size_t base7 = (size_t)(b * 64 + 56) * 512;  // o_k/o_v slot-7 region
#pragma unroll
  for (int i = 0; i < 2; ++i) {
    int idx = (tid + 512 * i) * 4;
    int c = idx >> 6, p0 = idx & 63;
    f32x4 kq, qq, vq;
#pragma unroll
    for (int j = 0; j < 4; ++j) {
      kq[j] = Xk[c * 65 + p0 + j];
      qq[j] = Xq[c * 65 + p0 + j];
      vq[j] = Xv[c * 65 + p0 + j];
    }
    *(f32x4*)&o_k[base7 + idx] = kq;
    *(f32x4*)&q_out[(size_t)b * 4096 + idx] = qq;
    *(f32x4*)&o_v[base7 + idx] = vq;
  }
}

// ---------------------------------------------------------------------------
// Kernel B: attention streaming. One wave per (b, head) -> 4096 blocks of 64.
// No LDS, no barriers. Streams ck/cv slots 1..7 -> o_k/o_v slots 0..6 with
// pos_w added to k; in-wave butterfly reduce for scores; redundant softmax in
// all lanes; PV accumulate; attn -> attn_out (o_c scratch).
// ---------------------------------------------------------------------------
__launch_bounds__(64, 4)
__global__ void attn_k(const float* __restrict__ ck, const float* __restrict__ cv,
                       const int* __restrict__ amask,
                       const float* __restrict__ pos_w,
                       const float* __restrict__ pos_b,
                       const float* __restrict__ q_in,
                       float* __restrict__ o_k, float* __restrict__ o_v,
                       float* __restrict__ attn_out) {
  const int b = blockIdx.x >> 3;
  const int hd = blockIdx.x & 7;
  const int lane = threadIdx.x;
  const int d0 = lane * 4, d1 = (lane + 64) * 4;

  const float* qp = q_in + (size_t)b * 4096 + hd * 512;
  f32x4 q0 = *(const f32x4*)&qp[d0];
  f32x4 q1 = *(const f32x4*)&qp[d1];

  float sc[8];
#pragma unroll
  for (int m = 0; m < 7; ++m) {
    const float* kp = ck + ((size_t)((b * 8 + m + 1) * 8 + hd)) * 512;
    const float* pw = pos_w + m * 4096 + hd * 512;
    f32x4 k0 = ntld4(kp + d0) + *(const f32x4*)&pw[d0];
    f32x4 k1 = ntld4(kp + d1) + *(const f32x4*)&pw[d1];
    float* dst = o_k + ((size_t)((b * 8 + m) * 8 + hd)) * 512;
    ntst4(dst + d0, k0);
    ntst4(dst + d1, k1);
    float part = 0.f;
#pragma unroll
    for (int j = 0; j < 4; ++j) {
      part = fmaf(q0[j], k0[j], part);
      part = fmaf(q1[j], k1[j], part);
    }
#pragma unroll
    for (int off = 32; off >= 1; off >>= 1) part += __shfl_xor(part, off);
    float msk = amask[(b * 8 + hd) * 8 + m] ? -__builtin_inff() : 0.0f;
    sc[m] = part + pos_b[m * 8 + hd] + msk;
  }
  {  // slot 7: k (already +pos_w[7]) written by kqv_k
    const float* kp = o_k + ((size_t)((b * 8 + 7) * 8 + hd)) * 512;
    f32x4 k0 = *(const f32x4*)&kp[d0];
    f32x4 k1 = *(const f32x4*)&kp[d1];
    float part = 0.f;
#pragma unroll
    for (int j = 0; j < 4; ++j) {
      part = fmaf(q0[j], k0[j], part);
      part = fmaf(q1[j], k1[j], part);
    }
#pragma unroll
    for (int off = 32; off >= 1; off >>= 1) part += __shfl_xor(part, off);
    sc[7] = part + pos_b[7 * 8 + hd] + 5.0f;  // attn_mask_b
  }

  // softmax over 8 slots (redundant in every lane)
  float mx = sc[0];
#pragma unroll
  for (int m = 1; m < 8; ++m) mx = fmaxf(mx, sc[m]);
  float w[8], s = 0.f;
#pragma unroll
  for (int m = 0; m < 8; ++m) {
    w[m] = __expf(sc[m] - mx);
    s += w[m];
  }
  float inv = 1.0f / s;
#pragma unroll
  for (int m = 0; m < 8; ++m) w[m] *= inv;

  f32x4 a0 = (f32x4){0.f, 0.f, 0.f, 0.f};
  f32x4 a1 = (f32x4){0.f, 0.f, 0.f, 0.f};
#pragma unroll
  for (int m = 0; m < 7; ++m) {
    const float* vp = cv + ((size_t)((b * 8 + m + 1) * 8 + hd)) * 512;
    f32x4 v0 = ntld4(vp + d0);
    f32x4 v1 = ntld4(vp + d1);
    float* dst = o_v + ((size_t)((b * 8 + m) * 8 + hd)) * 512;
    ntst4(dst + d0, v0);
    ntst4(dst + d1, v1);
    a0 += v0 * w[m];
    a1 += v1 * w[m];
  }
  {  // slot 7 v from kqv_k
    const float* vp = o_v + ((size_t)((b * 8 + 7) * 8 + hd)) * 512;
    a0 += *(const f32x4*)&vp[d0] * w[7];
    a1 += *(const f32x4*)&vp[d1] * w[7];
  }
  float* ap = attn_out + (size_t)b * 4096 + hd * 512;
  *(f32x4*)&ap[d0] = a0;  // plain store: consumed by cell2_k soon (keep in L2)
  *(f32x4*)&ap[d1] = a1;
}

// ---------------------------------------------------------------------------
// Kernel C: conv1 gates + conv3 + LN + LSTM epilogue. 512 thr = 8 waves.
// attn read from attn_in (= o_c scratch), h/c written last (overwrite).
// ---------------------------------------------------------------------------
__launch_bounds__(512, 4)
__global__ void cell2_k(
    const float* __restrict__ input, const float* __restrict__ h_cur,
    const float* __restrict__ c_cur, const float* __restrict__ attn_in,
    const float* __restrict__ conv_b, const float* __restrict__ out_b,
    const float* __restrict__ ln_w, const float* __restrict__ ln_b,
    const short* __restrict__ pk1, const short* __restrict__ pk3,
    float* __restrict__ o_h, float* __restrict__ o_c) {
  __shared__ short comb[12800];  // 10x10 x 128ch bf16, rotated
  __shared__ float Xb[4160];     // c_cur -> input (residual)
  __shared__ float Qb[4160];     // h staging
  __shared__ float Vb[4160];     // c staging
  __shared__ float red[16];

  const int b = blockIdx.x;
  const int tid = threadIdx.x;
  const int wave = tid >> 6, lane = tid & 63;
  const int col = lane & 15, g4 = lane >> 4;
  const int wc = wave >> 1, wm = wave & 1;
  const int ch = wc * 16 + col;

  // ---- stage input/h into comb (bf16), c_cur into Xb ----
#pragma unroll
  for (int i = 0; i < 2; ++i) {
    int idx = (tid + 512 * i) * 4;
    int c = idx >> 6, p0 = idx & 63;
    f32x4 vi = *(const f32x4*)&input[b * 4096 + idx];
    f32x4 vh = *(const f32x4*)&h_cur[b * 4096 + idx];
    f32x4 vc = *(const f32x4*)&c_cur[b * 4096 + idx];
#pragma unroll
    for (int j = 0; j < 4; ++j) {
      int p = p0 + j;
      int pp = ((p >> 3) + 1) * 10 + (p & 7) + 1;
      comb[pp * 128 + ((c + pp * 8) & 127)] = f2bf(vi[j]);
      comb[pp * 128 + ((c + 64 + pp * 8) & 127)] = f2bf(vh[j]);
      Xb[c * 65 + p] = vc[j];
    }
  }
  for (int i = tid; i < 4608; i += 512) {  // zero pad ring
    int pr = i >> 7, c = i & 127;
    int pp = (pr < 10) ? pr
             : (pr < 20) ? (80 + pr)
             : (pr < 28) ? ((pr - 19) * 10)
                         : ((pr - 27) * 10 + 9);
    comb[pp * 128 + c] = 0;
  }
  __syncthreads();

  // ---- conv1 gates, M=64 N=320 K=1152 ----
  f32x4 acc1[2][5];
#pragma unroll
  for (int m = 0; m < 2; ++m)
#pragma unroll
    for (int g = 0; g < 5; ++g) acc1[m][g] = (f32x4){0.f, 0.f, 0.f, 0.f};

  short8 bb1[5];
#pragma unroll
  for (int g = 0; g < 5; ++g)
    bb1[g] = *(const short8*)&pk1[((g4)*320 + g * 64 + ch) * 8];

  for (int s = 0; s < 36; ++s) {
    short8 bbn[5];
    if (s < 35) {
      int kb8 = (s + 1) * 4 + g4;
#pragma unroll
      for (int g = 0; g < 5; ++g)
        bbn[g] = *(const short8*)&pk1[(kb8 * 320 + g * 64 + ch) * 8];
    }
    int tap = s >> 2, cib = s & 3;
    int kh = tap / 3, kw = tap % 3;
    short8 a[2];
#pragma unroll
    for (int m = 0; m < 2; ++m) {
      int p = (wm * 2 + m) * 16 + col;
      int pp = ((p >> 3) + kh) * 10 + (p & 7) + kw;
      int slot = (cib * 32 + g4 * 8 + pp * 8) & 127;
      a[m] = *(const short8*)&comb[pp * 128 + slot];
    }
#pragma unroll
    for (int m = 0; m < 2; ++m)
#pragma unroll
      for (int g = 0; g < 5; ++g) acc1[m][g] = mfma16(a[m], bb1[g], acc1[m][g]);
    if (s < 35) {
#pragma unroll
      for (int g = 0; g < 5; ++g) bb1[g] = bbn[g];
    }
  }

  float ct_r[8], o_r[8], a_r[8];
  {
    float bi0 = conv_b[ch], bi1 = conv_b[64 + ch], bi2 = conv_b[128 + ch];
    float bi3 = conv_b[192 + ch], bi4 = conv_b[256 + ch];
#pragma unroll
    for (int m = 0; m < 2; ++m)
#pragma unroll
      for (int r = 0; r < 4; ++r) {
        int p = (wm * 2 + m) * 16 + g4 * 4 + r;
        float iv = sigm(acc1[m][0][r] + bi0);
        float fv = sigm(acc1[m][1][r] + bi1);
        float ov = sigm(acc1[m][2][r] + bi2);
        float gv = ftanh(acc1[m][3][r] + bi3);
        float av = sigm(acc1[m][4][r] + bi4);
        ct_r[m * 4 + r] = fv * Xb[ch * 65 + p] + iv * gv;
        o_r[m * 4 + r] = ov;
        a_r[m * 4 + r] = av;
      }
  }
  __syncthreads();  // comb input slots + Xb(c) consumed

  // ---- restage: attn -> comb (ci 0..63 slots), input(f32) -> Xb ----
  {
    f32x4 av[2], iv[2];
#pragma unroll
    for (int i = 0; i < 2; ++i) {
      int idx = (tid + 512 * i) * 4;
      av[i] = *(const f32x4*)&attn_in[b * 4096 + idx];
      iv[i] = *(const f32x4*)&input[b * 4096 + idx];
    }
#pragma unroll
    for (int i = 0; i < 2; ++i) {
      int idx = (tid + 512 * i) * 4;
      int c = idx >> 6, p0 = idx & 63;
#pragma unroll
      for (int j = 0; j < 4; ++j) {
        int p = p0 + j;
        int pp = ((p >> 3) + 1) * 10 + (p & 7) + 1;
        comb[pp * 128 + ((c + pp * 8) & 127)] = f2bf(av[i][j]);
        Xb[c * 65 + p] = iv[i][j];
      }
    }
  }
  __syncthreads();

  // ---- conv3, M=64 N=64 K=576 ----
  f32x4 acc3[2];
  acc3[0] = (f32x4){0.f, 0.f, 0.f, 0.f};
  acc3[1] = (f32x4){0.f, 0.f, 0.f, 0.f};
  short8 bb3 = *(const short8*)&pk3[((g4)*64 + ch) * 8];
  for (int s = 0; s < 18; ++s) {
    short8 bbn;
    if (s < 17) {
      int kb8 = (s + 1) * 4 + g4;
      bbn = *(const short8*)&pk3[(kb8 * 64 + ch) * 8];
    }
    int tap = s >> 1, cib = s & 1;
    int kh = tap / 3, kw = tap % 3;
    short8 a[2];
#pragma unroll
    for (int m = 0; m < 2; ++m) {
      int p = (wm * 2 + m) * 16 + col;
      int pp = ((p >> 3) + kh) * 10 + (p & 7) + kw;
      int slot = (cib * 32 + g4 * 8 + pp * 8) & 127;
      a[m] = *(const short8*)&comb[pp * 128 + slot];
    }
#pragma unroll
    for (int m = 0; m < 2; ++m) acc3[m] = mfma16(a[m], bb3, acc3[m]);
    if (s < 17) bb3 = bbn;
  }

  // residual + LN stats
  float ov_[8], s1 = 0.f, s2 = 0.f;
  {
    float ob = out_b[ch];
#pragma unroll
    for (int m = 0; m < 2; ++m)
#pragma unroll
      for (int r = 0; r < 4; ++r) {
        int p = (wm * 2 + m) * 16 + g4 * 4 + r;
        float v = acc3[m][r] + ob + Xb[ch * 65 + p];
        ov_[m * 4 + r] = v;
        s1 += v;
        s2 += v * v;
      }
  }
#pragma unroll
  for (int off = 32; off >= 1; off >>= 1) {
    s1 += __shfl_xor(s1, off);
    s2 += __shfl_xor(s2, off);
  }
  if (lane == 0) { red[wave] = s1; red[8 + wave] = s2; }
  __syncthreads();
  float ts1 = 0.f, ts2 = 0.f;
#pragma unroll
  for (int w = 0; w < 8; ++w) { ts1 += red[w]; ts2 += red[8 + w]; }
  float mu = ts1 * (1.0f / 4096.0f);
  float var = ts2 * (1.0f / 4096.0f) - mu * mu;
  float rstd = rsqrtf(var + 1e-5f);

  // LN + LSTM epilogue; h->Qb, c->Vb for coalesced writeout
#pragma unroll
  for (int m = 0; m < 2; ++m)
#pragma unroll
    for (int r = 0; r < 4; ++r) {
      int p = (wm * 2 + m) * 16 + g4 * 4 + r;
      float oln = (ov_[m * 4 + r] - mu) * rstd * ln_w[ch * 64 + p] + ln_b[ch * 64 + p];
      float cn = ct_r[m * 4 + r] + a_r[m * 4 + r] * ftanh(oln);
      float hv = o_r[m * 4 + r] * ftanh(cn);
      Qb[ch * 65 + p] = hv;
      Vb[ch * 65 + p] = cn;
    }
  __syncthreads();
#pragma unroll
  for (int i = 0; i < 2; ++i) {
    int idx = (tid + 512 * i) * 4;
    int c = idx >> 6, p0 = idx & 63;
    f32x4 hv, cvv;
#pragma unroll
    for (int j = 0; j < 4; ++j) {
      hv[j] = Qb[c * 65 + p0 + j];
      cvv[j] = Vb[c * 65 + p0 + j];
    }
    *(f32x4*)&o_h[b * 4096 + idx] = hv;
    *(f32x4*)&o_c[b * 4096 + idx] = cvv;
  }
}

extern "C" void kernel_launch(void* const* d_in, const int* in_sizes, int n_in,
                              void* d_out, int out_size, void* d_ws, size_t ws_size,
                              hipStream_t stream) {
  (void)in_sizes; (void)n_in; (void)out_size; (void)ws_size;
  const float* input  = (const float*)d_in[0];
  const float* h_cur  = (const float*)d_in[1];
  const float* c_cur  = (const float*)d_in[2];
  const float* ck     = (const float*)d_in[3];
  const float* cv     = (const float*)d_in[4];
  const int*   amask  = (const int*)d_in[5];
  const float* conv_w = (const float*)d_in[6];
  const float* conv_b = (const float*)d_in[7];
  const float* proj_w = (const float*)d_in[8];
  const float* proj_b = (const float*)d_in[9];
  const float* out_w  = (const float*)d_in[10];
  const float* out_b  = (const float*)d_in[11];
  const float* ln_w   = (const float*)d_in[12];
  const float* ln_b   = (const float*)d_in[13];
  const float* pos_w  = (const float*)d_in[14];
  const float* pos_b  = (const float*)d_in[15];

  short* pk = (short*)d_ws;  // 516096 bf16 = 1.03 MB
  float* o_h = (float*)d_out;
  float* o_c = o_h + 2097152;
  float* o_k = o_h + 4194304;
  float* o_v = o_h + 20971520;
  // scratch-in-d_out: q lives in o_h, attn lives in o_c until cell2_k
  // overwrites both with the real h/c outputs (write-before-read chain).

  pack_w<<<252, 256, 0, stream>>>(conv_w, proj_w, out_w, pk);
  kqv_k<<<512, 512, 0, stream>>>(input, proj_b, pos_w, pk + 368640,
                                 o_h, o_k, o_v);
  attn_k<<<4096, 64, 0, stream>>>(ck, cv, amask, pos_w, pos_b, o_h,
                                  o_k, o_v, o_c);
  cell2_k<<<512, 512, 0, stream>>>(input, h_cur, c_cur, o_c,
                                   conv_b, out_b, ln_w, ln_b,
                                   pk, pk + 479232, o_h, o_c);
}

// Round 5
// 109.193 us; speedup vs baseline: 1.6211x; 1.0414x over previous
//
#include <hip/hip_runtime.h>

typedef short short8 __attribute__((ext_vector_type(8)));
typedef __bf16 bf16x8 __attribute__((ext_vector_type(8)));
typedef float f32x4 __attribute__((ext_vector_type(4)));
typedef short s16x4 __attribute__((ext_vector_type(4)));
typedef unsigned u32x4 __attribute__((ext_vector_type(4)));

__device__ __forceinline__ short f2bf(float f) {
  unsigned u = __builtin_bit_cast(unsigned, f);
  u = (u + 0x7FFFu + ((u >> 16) & 1u)) >> 16;
  return (short)u;
}
__device__ __forceinline__ f32x4 mfma16(short8 a, short8 b, f32x4 c) {
  return __builtin_amdgcn_mfma_f32_16x16x32_bf16(
      __builtin_bit_cast(bf16x8, a), __builtin_bit_cast(bf16x8, b), c, 0, 0, 0);
}
__device__ __forceinline__ float sigm(float x) { return 1.0f / (1.0f + __expf(-x)); }
__device__ __forceinline__ float ftanh(float x) {
  return 1.0f - 2.0f / (1.0f + __expf(2.0f * x));
}
__device__ __forceinline__ f32x4 ntld4(const float* p) {
  return __builtin_nontemporal_load((const f32x4*)p);
}
__device__ __forceinline__ void ntst4(float* p, f32x4 v) {
  __builtin_nontemporal_store(v, (f32x4*)p);
}

// ---------------------------------------------------------------------------
// Weight pre-pack: f32 [CO][CI][3][3] -> bf16 [K/8][CO][8], K = tap*CI + ci.
// ---------------------------------------------------------------------------
__global__ void pack_w(const float* __restrict__ w1, const float* __restrict__ w2,
                       const float* __restrict__ w3, short* __restrict__ out) {
  int e = blockIdx.x * 256 + threadIdx.x;
  if (e < 46080) {
    int kb8 = e / 320, n = e % 320;
    short8 v;
#pragma unroll
    for (int j = 0; j < 8; ++j) {
      int k = kb8 * 8 + j;
      int tap = k >> 7, ci = k & 127;
      v[j] = f2bf(w1[(n * 128 + ci) * 9 + tap]);
    }
    *(short8*)&out[e * 8] = v;
    return;
  }
  e -= 46080;
  if (e < 13824) {
    int kb8 = e / 192, n = e % 192;
    short8 v;
#pragma unroll
    for (int j = 0; j < 8; ++j) {
      int k = kb8 * 8 + j;
      int tap = k >> 6, ci = k & 63;
      v[j] = f2bf(w2[(n * 64 + ci) * 9 + tap]);
    }
    *(short8*)&out[(46080 + e) * 8] = v;
    return;
  }
  e -= 13824;
  {
    int kb8 = e / 64, n = e % 64;
    short8 v;
#pragma unroll
    for (int j = 0; j < 8; ++j) {
      int k = kb8 * 8 + j;
      int tap = k >> 6, ci = k & 63;
      v[j] = f2bf(w3[(n * 64 + ci) * 9 + tap]);
    }
    *(short8*)&out[(46080 + 13824 + e) * 8] = v;
  }
}

// ===========================================================================
// Main path: mid_k (attn blocks 0..511 | gate blocks 512..1023) + back_k.
// ===========================================================================

// mid_k attn block: conv2 inline (k,q,v), slot-7 score via LDS atomic, write
// k7/v7 to o_k/o_v slot 7, stream ck/cv slots 1..7 -> 0..6 with scores/PV,
// write attn (bf16) to ws_attn.
// mid_k gate block: conv1 -> ct (f32) + packed o,a (bf16 pair) scratch.
__launch_bounds__(512, 4)
__global__ void mid_k(const float* __restrict__ input, const float* __restrict__ h_cur,
                      const float* __restrict__ c_cur, const float* __restrict__ ck,
                      const float* __restrict__ cv, const int* __restrict__ amask,
                      const float* __restrict__ conv_b, const float* __restrict__ proj_b,
                      const float* __restrict__ pos_w, const float* __restrict__ pos_b,
                      const short* __restrict__ pk1, const short* __restrict__ pk2,
                      float* __restrict__ o_k, float* __restrict__ o_v,
                      short* __restrict__ ws_attn, float* __restrict__ ws_ct,
                      unsigned* __restrict__ ws_oa) {
  __shared__ short comb[12800];  // 25.6 KB: bf16 tile, later reused as f32[4160]
  __shared__ float Xb[4160];     // 16.64 KB multi-purpose
  __shared__ float sc_lds[8];
  float* combf = (float*)comb;
  unsigned* Xbu = (unsigned*)Xb;

  const int tid = threadIdx.x;
  const int wave = tid >> 6, lane = tid & 63;
  const int col = lane & 15, g4 = lane >> 4;
  const int wc = wave >> 1, wm = wave & 1;
  const int ch = wc * 16 + col;

  if (blockIdx.x < 512) {
    // ---------------- ATTENTION BLOCK ----------------
    const int b = blockIdx.x;
    if (tid < 8) sc_lds[tid] = 0.f;

    // stage input -> 64ch rotated bf16 tile
#pragma unroll
    for (int i = 0; i < 2; ++i) {
      int idx = (tid + 512 * i) * 4;
      int c = idx >> 6, p0 = idx & 63;
      f32x4 vi = *(const f32x4*)&input[b * 4096 + idx];
#pragma unroll
      for (int j = 0; j < 4; ++j) {
        int p = p0 + j;
        int pp = ((p >> 3) + 1) * 10 + (p & 7) + 1;
        comb[pp * 64 + ((c + pp * 8) & 63)] = f2bf(vi[j]);
      }
    }
    for (int i = tid; i < 2304; i += 512) {  // pad ring
      int pr = i >> 6, c = i & 63;
      int pp = (pr < 10) ? pr
               : (pr < 20) ? (80 + pr)
               : (pr < 28) ? ((pr - 19) * 10)
                           : ((pr - 27) * 10 + 9);
      comb[pp * 64 + c] = 0;
    }
    __syncthreads();

    // conv2: M=64 N=192 K=576
    f32x4 acc2[2][3];
#pragma unroll
    for (int m = 0; m < 2; ++m)
#pragma unroll
      for (int g = 0; g < 3; ++g) acc2[m][g] = (f32x4){0.f, 0.f, 0.f, 0.f};
    short8 bb2[3];
#pragma unroll
    for (int g = 0; g < 3; ++g)
      bb2[g] = *(const short8*)&pk2[((g4)*192 + g * 64 + ch) * 8];
    for (int s = 0; s < 18; ++s) {
      short8 bbn[3];
      if (s < 17) {
        int kb8 = (s + 1) * 4 + g4;
#pragma unroll
        for (int g = 0; g < 3; ++g)
          bbn[g] = *(const short8*)&pk2[(kb8 * 192 + g * 64 + ch) * 8];
      }
      int tap = s >> 1, cib = s & 1;
      int kh = tap / 3, kw = tap % 3;
      short8 a[2];
#pragma unroll
      for (int m = 0; m < 2; ++m) {
        int p = (wm * 2 + m) * 16 + col;
        int pp = ((p >> 3) + kh) * 10 + (p & 7) + kw;
        int slot = (cib * 32 + g4 * 8 + pp * 8) & 63;
        a[m] = *(const short8*)&comb[pp * 64 + slot];
      }
#pragma unroll
      for (int m = 0; m < 2; ++m)
#pragma unroll
        for (int g = 0; g < 3; ++g) acc2[m][g] = mfma16(a[m], bb2[g], acc2[m][g]);
      if (s < 17) {
#pragma unroll
        for (int g = 0; g < 3; ++g) bb2[g] = bbn[g];
      }
    }

    // k,q,v in (ch,p) regs; slot-7 score partial
    float kreg[8], qreg[8], vreg[8], part7 = 0.f;
    {
      float pb0 = proj_b[ch], pb1 = proj_b[64 + ch], pb2 = proj_b[128 + ch];
      const float rsq = 0.044194173824159216f;  // 1/sqrt(512)
#pragma unroll
      for (int m = 0; m < 2; ++m)
#pragma unroll
        for (int r = 0; r < 4; ++r) {
          int p = (wm * 2 + m) * 16 + g4 * 4 + r;
          float kf = acc2[m][0][r] + pb0 + pos_w[7 * 4096 + ch * 64 + p];
          float qf = (acc2[m][1][r] + pb1) * rsq;
          float vf = acc2[m][2][r] + pb2;
          kreg[m * 4 + r] = kf;
          qreg[m * 4 + r] = qf;
          vreg[m * 4 + r] = vf;
          part7 = fmaf(qf, kf, part7);
        }
    }
    atomicAdd(&sc_lds[ch >> 3], part7);
    __syncthreads();  // conv2 tile consumed, atomics done

    // bounce k -> combf, q -> Xb
#pragma unroll
    for (int m = 0; m < 2; ++m)
#pragma unroll
      for (int r = 0; r < 4; ++r) {
        int p = (wm * 2 + m) * 16 + g4 * 4 + r;
        combf[ch * 65 + p] = kreg[m * 4 + r];
        Xb[ch * 65 + p] = qreg[m * 4 + r];
      }
    __syncthreads();

    const size_t base7 = (size_t)(b * 64 + 56) * 512;
#pragma unroll
    for (int i = 0; i < 2; ++i) {  // coalesced k7 (incl pos_w[7]) -> o_k slot 7
      int idx = (tid + 512 * i) * 4;
      int c = idx >> 6, p0 = idx & 63;
      f32x4 kq;
#pragma unroll
      for (int j = 0; j < 4; ++j) kq[j] = combf[c * 65 + p0 + j];
      ntst4(&o_k[base7 + idx], kq);
    }
    const int hd = wave;
    const int d0 = lane * 4, d1 = (lane + 64) * 4;
    const int cs0 = d0 >> 6, po0 = d0 & 63, cs1 = d1 >> 6, po1 = d1 & 63;
    f32x4 q0, q1;
#pragma unroll
    for (int j = 0; j < 4; ++j) {
      q0[j] = Xb[(hd * 8 + cs0) * 65 + po0 + j];
      q1[j] = Xb[(hd * 8 + cs1) * 65 + po1 + j];
    }
    float sc7 = sc_lds[hd] + pos_b[7 * 8 + hd] + 5.0f;  // attn_mask_b
    __syncthreads();

    // bounce v -> combf
#pragma unroll
    for (int m = 0; m < 2; ++m)
#pragma unroll
      for (int r = 0; r < 4; ++r) {
        int p = (wm * 2 + m) * 16 + g4 * 4 + r;
        combf[ch * 65 + p] = vreg[m * 4 + r];
      }
    __syncthreads();
#pragma unroll
    for (int i = 0; i < 2; ++i) {  // coalesced v7 -> o_v slot 7
      int idx = (tid + 512 * i) * 4;
      int c = idx >> 6, p0 = idx & 63;
      f32x4 vq;
#pragma unroll
      for (int j = 0; j < 4; ++j) vq[j] = combf[c * 65 + p0 + j];
      ntst4(&o_v[base7 + idx], vq);
    }
    f32x4 v70, v71;
#pragma unroll
    for (int j = 0; j < 4; ++j) {
      v70[j] = combf[(hd * 8 + cs0) * 65 + po0 + j];
      v71[j] = combf[(hd * 8 + cs1) * 65 + po1 + j];
    }

    // ---- stream slots 1..7 -> 0..6 ----
    float scv[8];
    scv[7] = sc7;
#pragma unroll
    for (int m = 0; m < 7; ++m) {
      const float* kp = ck + ((size_t)((b * 8 + m + 1) * 8 + hd)) * 512;
      const float* pw = pos_w + m * 4096 + hd * 512;
      f32x4 k0 = ntld4(kp + d0) + *(const f32x4*)&pw[d0];
      f32x4 k1 = ntld4(kp + d1) + *(const f32x4*)&pw[d1];
      float* dst = o_k + ((size_t)((b * 8 + m) * 8 + hd)) * 512;
      ntst4(dst + d0, k0);
      ntst4(dst + d1, k1);
      float part = 0.f;
#pragma unroll
      for (int j = 0; j < 4; ++j) {
        part = fmaf(q0[j], k0[j], part);
        part = fmaf(q1[j], k1[j], part);
      }
#pragma unroll
      for (int off = 32; off >= 1; off >>= 1) part += __shfl_xor(part, off);
      float msk = amask[(b * 8 + hd) * 8 + m] ? -__builtin_inff() : 0.0f;
      scv[m] = part + pos_b[m * 8 + hd] + msk;
    }
    float mx = scv[0];
#pragma unroll
    for (int m = 1; m < 8; ++m) mx = fmaxf(mx, scv[m]);
    float w[8], s = 0.f;
#pragma unroll
    for (int m = 0; m < 8; ++m) {
      w[m] = __expf(scv[m] - mx);
      s += w[m];
    }
    float inv = 1.0f / s;
#pragma unroll
    for (int m = 0; m < 8; ++m) w[m] *= inv;

    f32x4 a0 = (f32x4){0.f, 0.f, 0.f, 0.f};
    f32x4 a1 = (f32x4){0.f, 0.f, 0.f, 0.f};
#pragma unroll
    for (int m = 0; m < 7; ++m) {
      const float* vp = cv + ((size_t)((b * 8 + m + 1) * 8 + hd)) * 512;
      f32x4 v0 = ntld4(vp + d0);
      f32x4 v1 = ntld4(vp + d1);
      float* dst = o_v + ((size_t)((b * 8 + m) * 8 + hd)) * 512;
      ntst4(dst + d0, v0);
      ntst4(dst + d1, v1);
      a0 += v0 * w[m];
      a1 += v1 * w[m];
    }
    a0 += v70 * w[7];
    a1 += v71 * w[7];

    s16x4 s0, s1;
#pragma unroll
    for (int j = 0; j < 4; ++j) {
      s0[j] = f2bf(a0[j]);
      s1[j] = f2bf(a1[j]);
    }
    // FIX (R4 bug): include the head offset hd*512 in the attn scratch store.
    *(s16x4*)&ws_attn[(size_t)b * 4096 + hd * 512 + d0] = s0;
    *(s16x4*)&ws_attn[(size_t)b * 4096 + hd * 512 + d1] = s1;
  } else {
    // ---------------- GATE BLOCK ----------------
    const int b = blockIdx.x - 512;
    // stage input+h -> 128ch rotated bf16 tile, c -> Xb
#pragma unroll
    for (int i = 0; i < 2; ++i) {
      int idx = (tid + 512 * i) * 4;
      int c = idx >> 6, p0 = idx & 63;
      f32x4 vi = *(const f32x4*)&input[b * 4096 + idx];
      f32x4 vh = *(const f32x4*)&h_cur[b * 4096 + idx];
      f32x4 vc = *(const f32x4*)&c_cur[b * 4096 + idx];
#pragma unroll
      for (int j = 0; j < 4; ++j) {
        int p = p0 + j;
        int pp = ((p >> 3) + 1) * 10 + (p & 7) + 1;
        comb[pp * 128 + ((c + pp * 8) & 127)] = f2bf(vi[j]);
        comb[pp * 128 + ((c + 64 + pp * 8) & 127)] = f2bf(vh[j]);
        Xb[c * 65 + p] = vc[j];
      }
    }
    for (int i = tid; i < 4608; i += 512) {  // pad ring
      int pr = i >> 7, c = i & 127;
      int pp = (pr < 10) ? pr
               : (pr < 20) ? (80 + pr)
               : (pr < 28) ? ((pr - 19) * 10)
                           : ((pr - 27) * 10 + 9);
      comb[pp * 128 + c] = 0;
    }
    __syncthreads();

    // conv1: M=64 N=320 K=1152
    f32x4 acc1[2][5];
#pragma unroll
    for (int m = 0; m < 2; ++m)
#pragma unroll
      for (int g = 0; g < 5; ++g) acc1[m][g] = (f32x4){0.f, 0.f, 0.f, 0.f};
    short8 bb1[5];
#pragma unroll
    for (int g = 0; g < 5; ++g)
      bb1[g] = *(const short8*)&pk1[((g4)*320 + g * 64 + ch) * 8];
    for (int s = 0; s < 36; ++s) {
      short8 bbn[5];
      if (s < 35) {
        int kb8 = (s + 1) * 4 + g4;
#pragma unroll
        for (int g = 0; g < 5; ++g)
          bbn[g] = *(const short8*)&pk1[(kb8 * 320 + g * 64 + ch) * 8];
      }
      int tap = s >> 2, cib = s & 3;
      int kh = tap / 3, kw = tap % 3;
      short8 a[2];
#pragma unroll
      for (int m = 0; m < 2; ++m) {
        int p = (wm * 2 + m) * 16 + col;
        int pp = ((p >> 3) + kh) * 10 + (p & 7) + kw;
        int slot = (cib * 32 + g4 * 8 + pp * 8) & 127;
        a[m] = *(const short8*)&comb[pp * 128 + slot];
      }
#pragma unroll
      for (int m = 0; m < 2; ++m)
#pragma unroll
        for (int g = 0; g < 5; ++g) acc1[m][g] = mfma16(a[m], bb1[g], acc1[m][g]);
      if (s < 35) {
#pragma unroll
        for (int g = 0; g < 5; ++g) bb1[g] = bbn[g];
      }
    }

    float ctv[8];
    unsigned oav[8];
    {
      float bi0 = conv_b[ch], bi1 = conv_b[64 + ch], bi2 = conv_b[128 + ch];
      float bi3 = conv_b[192 + ch], bi4 = conv_b[256 + ch];
#pragma unroll
      for (int m = 0; m < 2; ++m)
#pragma unroll
        for (int r = 0; r < 4; ++r) {
          int p = (wm * 2 + m) * 16 + g4 * 4 + r;
          float iv = sigm(acc1[m][0][r] + bi0);
          float fv = sigm(acc1[m][1][r] + bi1);
          float ov = sigm(acc1[m][2][r] + bi2);
          float gv = ftanh(acc1[m][3][r] + bi3);
          float av = sigm(acc1[m][4][r] + bi4);
          ctv[m * 4 + r] = fv * Xb[ch * 65 + p] + iv * gv;
          oav[m * 4 + r] = ((unsigned)(unsigned short)f2bf(av) << 16) |
                           (unsigned)(unsigned short)f2bf(ov);
        }
    }
    __syncthreads();  // conv tile + Xb(c) consumed
#pragma unroll
    for (int m = 0; m < 2; ++m)
#pragma unroll
      for (int r = 0; r < 4; ++r) {
        int p = (wm * 2 + m) * 16 + g4 * 4 + r;
        combf[ch * 65 + p] = ctv[m * 4 + r];
        Xbu[ch * 65 + p] = oav[m * 4 + r];
      }
    __syncthreads();
#pragma unroll
    for (int i = 0; i < 2; ++i) {  // coalesced scratch writes
      int idx = (tid + 512 * i) * 4;
      int c = idx >> 6, p0 = idx & 63;
      f32x4 cq;
      u32x4 oq;
#pragma unroll
      for (int j = 0; j < 4; ++j) {
        cq[j] = combf[c * 65 + p0 + j];
        oq[j] = Xbu[c * 65 + p0 + j];
      }
      *(f32x4*)&ws_ct[(size_t)b * 4096 + idx] = cq;
      *(u32x4*)&ws_oa[(size_t)b * 4096 + idx] = oq;
    }
  }
}

// back_k: conv3 + residual + LN + LSTM epilogue.
__launch_bounds__(512, 4)
__global__ void back_k(const float* __restrict__ input,
                       const short* __restrict__ ws_attn,
                       const float* __restrict__ ws_ct,
                       const unsigned* __restrict__ ws_oa,
                       const float* __restrict__ out_b,
                       const float* __restrict__ ln_w, const float* __restrict__ ln_b,
                       const short* __restrict__ pk3,
                       float* __restrict__ o_h, float* __restrict__ o_c) {
  __shared__ short comb[8320];  // 16.64 KB; first 6400 = 64ch tile, alias f32[4160]
  __shared__ float Xb[4160];
  __shared__ float red[16];
  float* combf = (float*)comb;
  unsigned* Xbu = (unsigned*)Xb;

  const int b = blockIdx.x;
  const int tid = threadIdx.x;
  const int wave = tid >> 6, lane = tid & 63;
  const int col = lane & 15, g4 = lane >> 4;
  const int wc = wave >> 1, wm = wave & 1;
  const int ch = wc * 16 + col;

  f32x4 ctr[2];
  u32x4 oar[2];
#pragma unroll
  for (int i = 0; i < 2; ++i) {  // early gate scratch loads (hide under conv3)
    int idx = (tid + 512 * i) * 4;
    ctr[i] = *(const f32x4*)&ws_ct[(size_t)b * 4096 + idx];
    oar[i] = *(const u32x4*)&ws_oa[(size_t)b * 4096 + idx];
  }
#pragma unroll
  for (int i = 0; i < 2; ++i) {  // stage attn(bf16) -> tile, input -> Xb
    int idx = (tid + 512 * i) * 4;
    int c = idx >> 6, p0 = idx & 63;
    s16x4 av = *(const s16x4*)&ws_attn[(size_t)b * 4096 + idx];
    f32x4 vi = *(const f32x4*)&input[b * 4096 + idx];
#pragma unroll
    for (int j = 0; j < 4; ++j) {
      int p = p0 + j;
      int pp = ((p >> 3) + 1) * 10 + (p & 7) + 1;
      comb[pp * 64 + ((c + pp * 8) & 63)] = av[j];
      Xb[c * 65 + p] = vi[j];
    }
  }
  for (int i = tid; i < 2304; i += 512) {  // pad ring
    int pr = i >> 6, c = i & 63;
    int pp = (pr < 10) ? pr
             : (pr < 20) ? (80 + pr)
             : (pr < 28) ? ((pr - 19) * 10)
                         : ((pr - 27) * 10 + 9);
    comb[pp * 64 + c] = 0;
  }
  __syncthreads();

  // conv3: M=64 N=64 K=576
  f32x4 acc3[2];
  acc3[0] = (f32x4){0.f, 0.f, 0.f, 0.f};
  acc3[1] = (f32x4){0.f, 0.f, 0.f, 0.f};
  short8 bb3 = *(const short8*)&pk3[((g4)*64 + ch) * 8];
  for (int s = 0; s < 18; ++s) {
    short8 bbn;
    if (s < 17) {
      int kb8 = (s + 1) * 4 + g4;
      bbn = *(const short8*)&pk3[(kb8 * 64 + ch) * 8];
    }
    int tap = s >> 1, cib = s & 1;
    int kh = tap / 3, kw = tap % 3;
    short8 a[2];
#pragma unroll
    for (int m = 0; m < 2; ++m) {
      int p = (wm * 2 + m) * 16 + col;
      int pp = ((p >> 3) + kh) * 10 + (p & 7) + kw;
      int slot = (cib * 32 + g4 * 8 + pp * 8) & 63;
      a[m] = *(const short8*)&comb[pp * 64 + slot];
    }
#pragma unroll
    for (int m = 0; m < 2; ++m) acc3[m] = mfma16(a[m], bb3, acc3[m]);
    if (s < 17) bb3 = bbn;
  }

  // residual + LN stats
  float ov_[8], s1 = 0.f, s2 = 0.f;
  {
    float ob = out_b[ch];
#pragma unroll
    for (int m = 0; m < 2; ++m)
#pragma unroll
      for (int r = 0; r < 4; ++r) {
        int p = (wm * 2 + m) * 16 + g4 * 4 + r;
        float v = acc3[m][r] + ob + Xb[ch * 65 + p];
        ov_[m * 4 + r] = v;
        s1 += v;
        s2 += v * v;
      }
  }
#pragma unroll
  for (int off = 32; off >= 1; off >>= 1) {
    s1 += __shfl_xor(s1, off);
    s2 += __shfl_xor(s2, off);
  }
  if (lane == 0) { red[wave] = s1; red[8 + wave] = s2; }
  __syncthreads();
  float ts1 = 0.f, ts2 = 0.f;
#pragma unroll
  for (int w = 0; w < 8; ++w) { ts1 += red[w]; ts2 += red[8 + w]; }
  float mu = ts1 * (1.0f / 4096.0f);
  float var = ts2 * (1.0f / 4096.0f) - mu * mu;
  float rstd = rsqrtf(var + 1e-5f);

  // bounce gate scratch regs (idx-order) -> LDS (ch,p)-order
#pragma unroll
  for (int i = 0; i < 2; ++i) {
    int idx = (tid + 512 * i) * 4;
    int c = idx >> 6, p0 = idx & 63;
#pragma unroll
    for (int j = 0; j < 4; ++j) {
      combf[c * 65 + p0 + j] = ctr[i][j];
      Xbu[c * 65 + p0 + j] = oar[i][j];
    }
  }
  __syncthreads();

  // epilogue: each lane owns its (ch,p); read ct/oa then overwrite with h/c
#pragma unroll
  for (int m = 0; m < 2; ++m)
#pragma unroll
    for (int r = 0; r < 4; ++r) {
      int p = (wm * 2 + m) * 16 + g4 * 4 + r;
      float ct = combf[ch * 65 + p];
      unsigned u = Xbu[ch * 65 + p];
      float og = __builtin_bit_cast(float, u << 16);
      float ag = __builtin_bit_cast(float, u & 0xffff0000u);
      float oln = (ov_[m * 4 + r] - mu) * rstd * ln_w[ch * 64 + p] + ln_b[ch * 64 + p];
      float cn = ct + ag * ftanh(oln);
      float hv = og * ftanh(cn);
      combf[ch * 65 + p] = hv;
      Xb[ch * 65 + p] = cn;
    }
  __syncthreads();
#pragma unroll
  for (int i = 0; i < 2; ++i) {
    int idx = (tid + 512 * i) * 4;
    int c = idx >> 6, p0 = idx & 63;
    f32x4 hq, cq;
#pragma unroll
    for (int j = 0; j < 4; ++j) {
      hq[j] = combf[c * 65 + p0 + j];
      cq[j] = Xb[c * 65 + p0 + j];
    }
    *(f32x4*)&o_h[b * 4096 + idx] = hq;
    *(f32x4*)&o_c[b * 4096 + idx] = cq;
  }
}

// ===========================================================================
// Fallback path (R3, proven): used only if ws_size < 24 MB.
// ===========================================================================
__launch_bounds__(512, 4)
__global__ void kqv_k(const float* __restrict__ input,
                      const float* __restrict__ proj_b,
                      const float* __restrict__ pos_w,
                      const short* __restrict__ pk2,
                      float* __restrict__ q_out, float* __restrict__ o_k,
                      float* __restrict__ o_v) {
  __shared__ short comb[6400];
  __shared__ float Xk[4160], Xq[4160], Xv[4160];
  const int b = blockIdx.x;
  const int tid = threadIdx.x;
  const int wave = tid >> 6, lane = tid & 63;
  const int col = lane & 15, g4 = lane >> 4;
  const int wc = wave >> 1, wm = wave & 1;
  const int ch = wc * 16 + col;
#pragma unroll
  for (int i = 0; i < 2; ++i) {
    int idx = (tid + 512 * i) * 4;
    int c = idx >> 6, p0 = idx & 63;
    f32x4 vi = *(const f32x4*)&input[b * 4096 + idx];
#pragma unroll
    for (int j = 0; j < 4; ++j) {
      int p = p0 + j;
      int pp = ((p >> 3) + 1) * 10 + (p & 7) + 1;
      comb[pp * 64 + ((c + pp * 8) & 63)] = f2bf(vi[j]);
    }
  }
  for (int i = tid; i < 2304; i += 512) {
    int pr = i >> 6, c = i & 63;
    int pp = (pr < 10) ? pr
             : (pr < 20) ? (80 + pr)
             : (pr < 28) ? ((pr - 19) * 10)
                         : ((pr - 27) * 10 + 9);
    comb[pp * 64 + c] = 0;
  }
  __syncthreads();
  f32x4 acc2[2][3];
#pragma unroll
  for (int m = 0; m < 2; ++m)
#pragma unroll
    for (int g = 0; g < 3; ++g) acc2[m][g] = (f32x4){0.f, 0.f, 0.f, 0.f};
  short8 bb2[3];
#pragma unroll
  for (int g = 0; g < 3; ++g)
    bb2[g] = *(const short8*)&pk2[((g4)*192 + g * 64 + ch) * 8];
  for (int s = 0; s < 18; ++s) {
    short8 bbn[3];
    if (s < 17) {
      int kb8 = (s + 1) * 4 + g4;
#pragma unroll
      for (int g = 0; g < 3; ++g)
        bbn[g] = *(const short8*)&pk2[(kb8 * 192 + g * 64 + ch) * 8];
    }
    int tap = s >> 1, cib = s & 1;
    int kh = tap / 3, kw = tap % 3;
    short8 a[2];
#pragma unroll
    for (int m = 0; m < 2; ++m) {
      int p = (wm * 2 + m) * 16 + col;
      int pp = ((p >> 3) + kh) * 10 + (p & 7) + kw;
      int slot = (cib * 32 + g4 * 8 + pp * 8) & 63;
      a[m] = *(const short8*)&comb[pp * 64 + slot];
    }
#pragma unroll
    for (int m = 0; m < 2; ++m)
#pragma unroll
      for (int g = 0; g < 3; ++g) acc2[m][g] = mfma16(a[m], bb2[g], acc2[m][g]);
    if (s < 17) {
#pragma unroll
      for (int g = 0; g < 3; ++g) bb2[g] = bbn[g];
    }
  }
  {
    float pb0 = proj_b[ch], pb1 = proj_b[64 + ch], pb2 = proj_b[128 + ch];
    const float rsq = 0.044194173824159216f;
#pragma unroll
    for (int m = 0; m < 2; ++m)
#pragma unroll
      for (int r = 0; r < 4; ++r) {
        int p = (wm * 2 + m) * 16 + g4 * 4 + r;
        Xk[ch * 65 + p] = acc2[m][0][r] + pb0 + pos_w[7 * 4096 + ch * 64 + p];
        Xq[ch * 65 + p] = (acc2[m][1][r] + pb1) * rsq;
        Xv[ch * 65 + p] = acc2[m][2][r] + pb2;
      }
  }
  __syncthreads();
  const size_t base7 = (size_t)(b * 64 + 56) * 512;
#pragma unroll
  for (int i = 0; i < 2; ++i) {
    int idx = (tid + 512 * i) * 4;
    int c = idx >> 6, p0 = idx & 63;
    f32x4 kq, qq, vq;
#pragma unroll
    for (int j = 0; j < 4; ++j) {
      kq[j] = Xk[c * 65 + p0 + j];
      qq[j] = Xq[c * 65 + p0 + j];
      vq[j] = Xv[c * 65 + p0 + j];
    }
    *(f32x4*)&o_k[base7 + idx] = kq;
    *(f32x4*)&q_out[(size_t)b * 4096 + idx] = qq;
    *(f32x4*)&o_v[base7 + idx] = vq;
  }
}

__launch_bounds__(64, 4)
__global__ void attn_k(const float* __restrict__ ck, const float* __restrict__ cv,
                       const int* __restrict__ amask,
                       const float* __restrict__ pos_w,
                       const float* __restrict__ pos_b,
                       const float* __restrict__ q_in,
                       float* __restrict__ o_k, float* __restrict__ o_v,
                       float* __restrict__ attn_out) {
  const int b = blockIdx.x >> 3;
  const int hd = blockIdx.x & 7;
  const int lane = threadIdx.x;
  const int d0 = lane * 4, d1 = (lane + 64) * 4;
  const float* qp = q_in + (size_t)b * 4096 + hd * 512;
  f32x4 q0 = *(const f32x4*)&qp[d0];
  f32x4 q1 = *(const f32x4*)&qp[d1];
  float sc[8];
#pragma unroll
  for (int m = 0; m < 7; ++m) {
    const float* kp = ck + ((size_t)((b * 8 + m + 1) * 8 + hd)) * 512;
    const float* pw = pos_w + m * 4096 + hd * 512;
    f32x4 k0 = ntld4(kp + d0) + *(const f32x4*)&pw[d0];
    f32x4 k1 = ntld4(kp + d1) + *(const f32x4*)&pw[d1];
    float* dst = o_k + ((size_t)((b * 8 + m) * 8 + hd)) * 512;
    ntst4(dst + d0, k0);
    ntst4(dst + d1, k1);
    float part = 0.f;
#pragma unroll
    for (int j = 0; j < 4; ++j) {
      part = fmaf(q0[j], k0[j], part);
      part = fmaf(q1[j], k1[j], part);
    }
#pragma unroll
    for (int off = 32; off >= 1; off >>= 1) part += __shfl_xor(part, off);
    float msk = amask[(b * 8 + hd) * 8 + m] ? -__builtin_inff() : 0.0f;
    sc[m] = part + pos_b[m * 8 + hd] + msk;
  }
  {
    const float* kp = o_k + ((size_t)((b * 8 + 7) * 8 + hd)) * 512;
    f32x4 k0 = *(const f32x4*)&kp[d0];
    f32x4 k1 = *(const f32x4*)&kp[d1];
    float part = 0.f;
#pragma unroll
    for (int j = 0; j < 4; ++j) {
      part = fmaf(q0[j], k0[j], part);
      part = fmaf(q1[j], k1[j], part);
    }
#pragma unroll
    for (int off = 32; off >= 1; off >>= 1) part += __shfl_xor(part, off);
    sc[7] = part + pos_b[7 * 8 + hd] + 5.0f;
  }
  float mx = sc[0];
#pragma unroll
  for (int m = 1; m < 8; ++m) mx = fmaxf(mx, sc[m]);
  float w[8], s = 0.f;
#pragma unroll
  for (int m = 0; m < 8; ++m) {
    w[m] = __expf(sc[m] - mx);
    s += w[m];
  }
  float inv = 1.0f / s;
#pragma unroll
  for (int m = 0; m < 8; ++m) w[m] *= inv;
  f32x4 a0 = (f32x4){0.f, 0.f, 0.f, 0.f};
  f32x4 a1 = (f32x4){0.f, 0.f, 0.f, 0.f};
#pragma unroll
  for (int m = 0; m < 7; ++m) {
    const float* vp = cv + ((size_t)((b * 8 + m + 1) * 8 + hd)) * 512;
    f32x4 v0 = ntld4(vp + d0);
    f32x4 v1 = ntld4(vp + d1);
    float* dst = o_v + ((size_t)((b * 8 + m) * 8 + hd)) * 512;
    ntst4(dst + d0, v0);
    ntst4(dst + d1, v1);
    a0 += v0 * w[m];
    a1 += v1 * w[m];
  }
  {
    const float* vp = o_v + ((size_t)((b * 8 + 7) * 8 + hd)) * 512;
    a0 += *(const f32x4*)&vp[d0] * w[7];
    a1 += *(const f32x4*)&vp[d1] * w[7];
  }
  float* ap = attn_out + (size_t)b * 4096 + hd * 512;
  *(f32x4*)&ap[d0] = a0;
  *(f32x4*)&ap[d1] = a1;
}

__launch_bounds__(512, 4)
__global__ void cell2_k(
    const float* __restrict__ input, const float* __restrict__ h_cur,
    const float* __restrict__ c_cur, const float* __restrict__ attn_in,
    const float* __restrict__ conv_b, const float* __restrict__ out_b,
    const float* __restrict__ ln_w, const float* __restrict__ ln_b,
    const short* __restrict__ pk1, const short* __restrict__ pk3,
    float* __restrict__ o_h, float* __restrict__ o_c) {
  __shared__ short comb[12800];
  __shared__ float Xb[4160];
  __shared__ float Qb[4160];
  __shared__ float Vb[4160];
  __shared__ float red[16];
  const int b = blockIdx.x;
  const int tid = threadIdx.x;
  const int wave = tid >> 6, lane = tid & 63;
  const int col = lane & 15, g4 = lane >> 4;
  const int wc = wave >> 1, wm = wave & 1;
  const int ch = wc * 16 + col;
#pragma unroll
  for (int i = 0; i < 2; ++i) {
    int idx = (tid + 512 * i) * 4;
    int c = idx >> 6, p0 = idx & 63;
    f32x4 vi = *(const f32x4*)&input[b * 4096 + idx];
    f32x4 vh = *(const f32x4*)&h_cur[b * 4096 + idx];
    f32x4 vc = *(const f32x4*)&c_cur[b * 4096 + idx];
#pragma unroll
    for (int j = 0; j < 4; ++j) {
      int p = p0 + j;
      int pp = ((p >> 3) + 1) * 10 + (p & 7) + 1;
      comb[pp * 128 + ((c + pp * 8) & 127)] = f2bf(vi[j]);
      comb[pp * 128 + ((c + 64 + pp * 8) & 127)] = f2bf(vh[j]);
      Xb[c * 65 + p] = vc[j];
    }
  }
  for (int i = tid; i < 4608; i += 512) {
    int pr = i >> 7, c = i & 127;
    int pp = (pr < 10) ? pr
             : (pr < 20) ? (80 + pr)
             : (pr < 28) ? ((pr - 19) * 10)
                         : ((pr - 27) * 10 + 9);
    comb[pp * 128 + c] = 0;
  }
  __syncthreads();
  f32x4 acc1[2][5];
#pragma unroll
  for (int m = 0; m < 2; ++m)
#pragma unroll
    for (int g = 0; g < 5; ++g) acc1[m][g] = (f32x4){0.f, 0.f, 0.f, 0.f};
  short8 bb1[5];
#pragma unroll
  for (int g = 0; g < 5; ++g)
    bb1[g] = *(const short8*)&pk1[((g4)*320 + g * 64 + ch) * 8];
  for (int s = 0; s < 36; ++s) {
    short8 bbn[5];
    if (s < 35) {
      int kb8 = (s + 1) * 4 + g4;
#pragma unroll
      for (int g = 0; g < 5; ++g)
        bbn[g] = *(const short8*)&pk1[(kb8 * 320 + g * 64 + ch) * 8];
    }
    int tap = s >> 2, cib = s & 3;
    int kh = tap / 3, kw = tap % 3;
    short8 a[2];
#pragma unroll
    for (int m = 0; m < 2; ++m) {
      int p = (wm * 2 + m) * 16 + col;
      int pp = ((p >> 3) + kh) * 10 + (p & 7) + kw;
      int slot = (cib * 32 + g4 * 8 + pp * 8) & 127;
      a[m] = *(const short8*)&comb[pp * 128 + slot];
    }
#pragma unroll
    for (int m = 0; m < 2; ++m)
#pragma unroll
      for (int g = 0; g < 5; ++g) acc1[m][g] = mfma16(a[m], bb1[g], acc1[m][g]);
    if (s < 35) {
#pragma unroll
      for (int g = 0; g < 5; ++g) bb1[g] = bbn[g];
    }
  }
  float ct_r[8], o_r[8], a_r[8];
  {
    float bi0 = conv_b[ch], bi1 = conv_b[64 + ch], bi2 = conv_b[128 + ch];
    float bi3 = conv_b[192 + ch], bi4 = conv_b[256 + ch];
#pragma unroll
    for (int m = 0; m < 2; ++m)
#pragma unroll
      for (int r = 0; r < 4; ++r) {
        int p = (wm * 2 + m) * 16 + g4 * 4 + r;
        float iv = sigm(acc1[m][0][r] + bi0);
        float fv = sigm(acc1[m][1][r] + bi1);
        float ov = sigm(acc1[m][2][r] + bi2);
        float gv = ftanh(acc1[m][3][r] + bi3);
        float av = sigm(acc1[m][4][r] + bi4);
        ct_r[m * 4 + r] = fv * Xb[ch * 65 + p] + iv * gv;
        o_r[m * 4 + r] = ov;
        a_r[m * 4 + r] = av;
      }
  }
  __syncthreads();
  {
    f32x4 av[2], iv[2];
#pragma unroll
    for (int i = 0; i < 2; ++i) {
      int idx = (tid + 512 * i) * 4;
      av[i] = *(const f32x4*)&attn_in[b * 4096 + idx];
      iv[i] = *(const f32x4*)&input[b * 4096 + idx];
    }
#pragma unroll
    for (int i = 0; i < 2; ++i) {
      int idx = (tid + 512 * i) * 4;
      int c = idx >> 6, p0 = idx & 63;
#pragma unroll
      for (int j = 0; j < 4; ++j) {
        int p = p0 + j;
        int pp = ((p >> 3) + 1) * 10 + (p & 7) + 1;
        comb[pp * 128 + ((c + pp * 8) & 127)] = f2bf(av[i][j]);
        Xb[c * 65 + p] = iv[i][j];
      }
    }
  }
  __syncthreads();
  f32x4 acc3[2];
  acc3[0] = (f32x4){0.f, 0.f, 0.f, 0.f};
  acc3[1] = (f32x4){0.f, 0.f, 0.f, 0.f};
  short8 bb3 = *(const short8*)&pk3[((g4)*64 + ch) * 8];
  for (int s = 0; s < 18; ++s) {
    short8 bbn;
    if (s < 17) {
      int kb8 = (s + 1) * 4 + g4;
      bbn = *(const short8*)&pk3[(kb8 * 64 + ch) * 8];
    }
    int tap = s >> 1, cib = s & 1;
    int kh = tap / 3, kw = tap % 3;
    short8 a[2];
#pragma unroll
    for (int m = 0; m < 2; ++m) {
      int p = (wm * 2 + m) * 16 + col;
      int pp = ((p >> 3) + kh) * 10 + (p & 7) + kw;
      int slot = (cib * 32 + g4 * 8 + pp * 8) & 127;
      a[m] = *(const short8*)&comb[pp * 128 + slot];
    }
#pragma unroll
    for (int m = 0; m < 2; ++m) acc3[m] = mfma16(a[m], bb3, acc3[m]);
    if (s < 17) bb3 = bbn;
  }
  float ov_[8], s1 = 0.f, s2 = 0.f;
  {
    float ob = out_b[ch];
#pragma unroll
    for (int m = 0; m < 2; ++m)
#pragma unroll
      for (int r = 0; r < 4; ++r) {
        int p = (wm * 2 + m) * 16 + g4 * 4 + r;
        float v = acc3[m][r] + ob + Xb[ch * 65 + p];
        ov_[m * 4 + r] = v;
        s1 += v;
        s2 += v * v;
      }
  }
#pragma unroll
  for (int off = 32; off >= 1; off >>= 1) {
    s1 += __shfl_xor(s1, off);
    s2 += __shfl_xor(s2, off);
  }
  if (lane == 0) { red[wave] = s1; red[8 + wave] = s2; }
  __syncthreads();
  float ts1 = 0.f, ts2 = 0.f;
#pragma unroll
  for (int w = 0; w < 8; ++w) { ts1 += red[w]; ts2 += red[8 + w]; }
  float mu = ts1 * (1.0f / 4096.0f);
  float var = ts2 * (1.0f / 4096.0f) - mu * mu;
  float rstd = rsqrtf(var + 1e-5f);
#pragma unroll
  for (int m = 0; m < 2; ++m)
#pragma unroll
    for (int r = 0; r < 4; ++r) {
      int p = (wm * 2 + m) * 16 + g4 * 4 + r;
      float oln = (ov_[m * 4 + r] - mu) * rstd * ln_w[ch * 64 + p] + ln_b[ch * 64 + p];
      float cn = ct_r[m * 4 + r] + a_r[m * 4 + r] * ftanh(oln);
      float hv = o_r[m * 4 + r] * ftanh(cn);
      Qb[ch * 65 + p] = hv;
      Vb[ch * 65 + p] = cn;
    }
  __syncthreads();
#pragma unroll
  for (int i = 0; i < 2; ++i) {
    int idx = (tid + 512 * i) * 4;
    int c = idx >> 6, p0 = idx & 63;
    f32x4 hv, cvv;
#pragma unroll
    for (int j = 0; j < 4; ++j) {
      hv[j] = Qb[c * 65 + p0 + j];
      cvv[j] = Vb[c * 65 + p0 + j];
    }
    *(f32x4*)&o_h[b * 4096 + idx] = hv;
    *(f32x4*)&o_c[b * 4096 + idx] = cvv;
  }
}

extern "C" void kernel_launch(void* const* d_in, const int* in_sizes, int n_in,
                              void* d_out, int out_size, void* d_ws, size_t ws_size,
                              hipStream_t stream) {
  (void)in_sizes; (void)n_in; (void)out_size;
  const float* input  = (const float*)d_in[0];
  const float* h_cur  = (const float*)d_in[1];
  const float* c_cur  = (const float*)d_in[2];
  const float* ck     = (const float*)d_in[3];
  const float* cv     = (const float*)d_in[4];
  const int*   amask  = (const int*)d_in[5];
  const float* conv_w = (const float*)d_in[6];
  const float* conv_b = (const float*)d_in[7];
  const float* proj_w = (const float*)d_in[8];
  const float* proj_b = (const float*)d_in[9];
  const float* out_w  = (const float*)d_in[10];
  const float* out_b  = (const float*)d_in[11];
  const float* ln_w   = (const float*)d_in[12];
  const float* ln_b   = (const float*)d_in[13];
  const float* pos_w  = (const float*)d_in[14];
  const float* pos_b  = (const float*)d_in[15];

  char* ws = (char*)d_ws;
  short* pk = (short*)ws;  // 516096 shorts = 1.03 MB
  float* o_h = (float*)d_out;
  float* o_c = o_h + 2097152;
  float* o_k = o_h + 4194304;
  float* o_v = o_h + 20971520;

  pack_w<<<252, 256, 0, stream>>>(conv_w, proj_w, out_w, pk);

  if (ws_size >= (24u << 20)) {
    short* ws_attn = (short*)(ws + (2u << 20));      // 4 MB bf16
    float* ws_ct = (float*)(ws + (8u << 20));        // 8 MB f32
    unsigned* ws_oa = (unsigned*)(ws + (16u << 20)); // 8 MB packed bf16x2
    mid_k<<<1024, 512, 0, stream>>>(input, h_cur, c_cur, ck, cv, amask,
                                    conv_b, proj_b, pos_w, pos_b,
                                    pk, pk + 368640,
                                    o_k, o_v, ws_attn, ws_ct, ws_oa);
    back_k<<<512, 512, 0, stream>>>(input, ws_attn, ws_ct, ws_oa,
                                    out_b, ln_w, ln_b, pk + 479232, o_h, o_c);
  } else {
    // fallback: proven R3 pipeline (scratch lives in d_out regions)
    kqv_k<<<512, 512, 0, stream>>>(input, proj_b, pos_w, pk + 368640,
                                   o_h, o_k, o_v);
    attn_k<<<4096, 64, 0, stream>>>(ck, cv, amask, pos_w, pos_b, o_h,
                                    o_k, o_v, o_c);
    cell2_k<<<512, 512, 0, stream>>>(input, h_cur, c_cur, o_c,
                                     conv_b, out_b, ln_w, ln_b,
                                     pk, pk + 479232, o_h, o_c);
  }
}

// Round 7
// 105.976 us; speedup vs baseline: 1.6704x; 1.0304x over previous
//
#include <hip/hip_runtime.h>

typedef short short8 __attribute__((ext_vector_type(8)));
typedef __bf16 bf16x8 __attribute__((ext_vector_type(8)));
typedef float f32x4 __attribute__((ext_vector_type(4)));
typedef short s16x4 __attribute__((ext_vector_type(4)));
typedef unsigned u32x4 __attribute__((ext_vector_type(4)));

__device__ __forceinline__ short f2bf(float f) {
  unsigned u = __builtin_bit_cast(unsigned, f);
  u = (u + 0x7FFFu + ((u >> 16) & 1u)) >> 16;
  return (short)u;
}
__device__ __forceinline__ f32x4 mfma16(short8 a, short8 b, f32x4 c) {
  return __builtin_amdgcn_mfma_f32_16x16x32_bf16(
      __builtin_bit_cast(bf16x8, a), __builtin_bit_cast(bf16x8, b), c, 0, 0, 0);
}
__device__ __forceinline__ float sigm(float x) { return 1.0f / (1.0f + __expf(-x)); }
__device__ __forceinline__ float ftanh(float x) {
  return 1.0f - 2.0f / (1.0f + __expf(2.0f * x));
}
__device__ __forceinline__ f32x4 ntld4(const float* p) {
  return __builtin_nontemporal_load((const f32x4*)p);
}
__device__ __forceinline__ void ntst4(float* p, f32x4 v) {
  __builtin_nontemporal_store(v, (f32x4*)p);
}

// ---------------------------------------------------------------------------
// Weight pre-pack: f32 [CO][CI][3][3] -> bf16 [K/8][CO][8], K = tap*CI + ci.
// ---------------------------------------------------------------------------
__global__ void pack_w(const float* __restrict__ w1, const float* __restrict__ w2,
                       const float* __restrict__ w3, short* __restrict__ out) {
  int e = blockIdx.x * 256 + threadIdx.x;
  if (e < 46080) {
    int kb8 = e / 320, n = e % 320;
    short8 v;
#pragma unroll
    for (int j = 0; j < 8; ++j) {
      int k = kb8 * 8 + j;
      int tap = k >> 7, ci = k & 127;
      v[j] = f2bf(w1[(n * 128 + ci) * 9 + tap]);
    }
    *(short8*)&out[e * 8] = v;
    return;
  }
  e -= 46080;
  if (e < 13824) {
    int kb8 = e / 192, n = e % 192;
    short8 v;
#pragma unroll
    for (int j = 0; j < 8; ++j) {
      int k = kb8 * 8 + j;
      int tap = k >> 6, ci = k & 63;
      v[j] = f2bf(w2[(n * 64 + ci) * 9 + tap]);
    }
    *(short8*)&out[(46080 + e) * 8] = v;
    return;
  }
  e -= 13824;
  {
    int kb8 = e / 64, n = e % 64;
    short8 v;
#pragma unroll
    for (int j = 0; j < 8; ++j) {
      int k = kb8 * 8 + j;
      int tap = k >> 6, ci = k & 63;
      v[j] = f2bf(w3[(n * 64 + ci) * 9 + tap]);
    }
    *(short8*)&out[(46080 + 13824 + e) * 8] = v;
  }
}

// ===========================================================================
// Main path: mid_k (attn blocks 0..511 | gate blocks 512..1023) + back_k.
// R7: R6's ILP restructure + the pre-bounce __syncthreads() restored (R6's
// NaN was a race: bounce writes alias the comb tile other waves still read).
// K-slot loads are issued BEFORE that barrier so they fly during it.
// ===========================================================================
__launch_bounds__(512, 4)
__global__ void mid_k(const float* __restrict__ input, const float* __restrict__ h_cur,
                      const float* __restrict__ c_cur, const float* __restrict__ ck,
                      const float* __restrict__ cv, const int* __restrict__ amask,
                      const float* __restrict__ conv_b, const float* __restrict__ proj_b,
                      const float* __restrict__ pos_w, const float* __restrict__ pos_b,
                      const short* __restrict__ pk1, const short* __restrict__ pk2,
                      float* __restrict__ o_k, float* __restrict__ o_v,
                      short* __restrict__ ws_attn, float* __restrict__ ws_ct,
                      unsigned* __restrict__ ws_oa) {
  __shared__ short comb[12800];  // 25.6 KB: bf16 tile, later reused as f32[4160]
  __shared__ float Xb[4160];     // 16.64 KB multi-purpose
  __shared__ float Vx[4160];     // 16.64 KB: v bounce buffer (attn branch)
  __shared__ float sc_lds[8];
  float* combf = (float*)comb;
  unsigned* Xbu = (unsigned*)Xb;

  const int tid = threadIdx.x;
  const int wave = tid >> 6, lane = tid & 63;
  const int col = lane & 15, g4 = lane >> 4;
  const int wc = wave >> 1, wm = wave & 1;
  const int ch = wc * 16 + col;

  if (blockIdx.x < 512) {
    // ---------------- ATTENTION BLOCK ----------------
    const int b = blockIdx.x;
    const int hd = wave;
    const int d0 = lane * 4, d1 = (lane + 64) * 4;
    if (tid < 8) sc_lds[tid] = 0.f;

    // stage input -> 64ch rotated bf16 tile
#pragma unroll
    for (int i = 0; i < 2; ++i) {
      int idx = (tid + 512 * i) * 4;
      int c = idx >> 6, p0 = idx & 63;
      f32x4 vi = *(const f32x4*)&input[b * 4096 + idx];
#pragma unroll
      for (int j = 0; j < 4; ++j) {
        int p = p0 + j;
        int pp = ((p >> 3) + 1) * 10 + (p & 7) + 1;
        comb[pp * 64 + ((c + pp * 8) & 63)] = f2bf(vi[j]);
      }
    }
    for (int i = tid; i < 2304; i += 512) {  // pad ring
      int pr = i >> 6, c = i & 63;
      int pp = (pr < 10) ? pr
               : (pr < 20) ? (80 + pr)
               : (pr < 28) ? ((pr - 19) * 10)
                           : ((pr - 27) * 10 + 9);
      comb[pp * 64 + c] = 0;
    }
    __syncthreads();

    // conv2: M=64 N=192 K=576
    f32x4 acc2[2][3];
#pragma unroll
    for (int m = 0; m < 2; ++m)
#pragma unroll
      for (int g = 0; g < 3; ++g) acc2[m][g] = (f32x4){0.f, 0.f, 0.f, 0.f};
    short8 bb2[3];
#pragma unroll
    for (int g = 0; g < 3; ++g)
      bb2[g] = *(const short8*)&pk2[((g4)*192 + g * 64 + ch) * 8];
    for (int s = 0; s < 18; ++s) {
      short8 bbn[3];
      if (s < 17) {
        int kb8 = (s + 1) * 4 + g4;
#pragma unroll
        for (int g = 0; g < 3; ++g)
          bbn[g] = *(const short8*)&pk2[(kb8 * 192 + g * 64 + ch) * 8];
      }
      int tap = s >> 1, cib = s & 1;
      int kh = tap / 3, kw = tap % 3;
      short8 a[2];
#pragma unroll
      for (int m = 0; m < 2; ++m) {
        int p = (wm * 2 + m) * 16 + col;
        int pp = ((p >> 3) + kh) * 10 + (p & 7) + kw;
        int slot = (cib * 32 + g4 * 8 + pp * 8) & 63;
        a[m] = *(const short8*)&comb[pp * 64 + slot];
      }
#pragma unroll
      for (int m = 0; m < 2; ++m)
#pragma unroll
        for (int g = 0; g < 3; ++g) acc2[m][g] = mfma16(a[m], bb2[g], acc2[m][g]);
      if (s < 17) {
#pragma unroll
        for (int g = 0; g < 3; ++g) bb2[g] = bbn[g];
      }
    }

    // k,q,v in (ch,p) regs; slot-7 score partial
    float kreg[8], qreg[8], vreg[8], part7 = 0.f;
    {
      float pb0 = proj_b[ch], pb1 = proj_b[64 + ch], pb2 = proj_b[128 + ch];
      const float rsq = 0.044194173824159216f;  // 1/sqrt(512)
#pragma unroll
      for (int m = 0; m < 2; ++m)
#pragma unroll
        for (int r = 0; r < 4; ++r) {
          int p = (wm * 2 + m) * 16 + g4 * 4 + r;
          float kf = acc2[m][0][r] + pb0 + pos_w[7 * 4096 + ch * 64 + p];
          float qf = (acc2[m][1][r] + pb1) * rsq;
          float vf = acc2[m][2][r] + pb2;
          kreg[m * 4 + r] = kf;
          qreg[m * 4 + r] = qf;
          vreg[m * 4 + r] = vf;
          part7 = fmaf(qf, kf, part7);
        }
    }
    atomicAdd(&sc_lds[ch >> 3], part7);

    // ILP: batch-issue ALL 7 K-slot stream loads now; they fly across the
    // barrier + bounce + k7/v7 writeout below.
    f32x4 kk0[7], kk1[7];
#pragma unroll
    for (int m = 0; m < 7; ++m) {
      const float* kp = ck + ((size_t)((b * 8 + m + 1) * 8 + hd)) * 512;
      kk0[m] = ntld4(kp + d0);
      kk1[m] = ntld4(kp + d1);
    }

    // RACE FIX (R6 bug): all waves must finish READING comb (conv2 A-frags)
    // before we overwrite combf below.
    __syncthreads();

    // single-pass bounce: k -> combf, q -> Xb, v -> Vx
#pragma unroll
    for (int m = 0; m < 2; ++m)
#pragma unroll
      for (int r = 0; r < 4; ++r) {
        int p = (wm * 2 + m) * 16 + g4 * 4 + r;
        combf[ch * 65 + p] = kreg[m * 4 + r];
        Xb[ch * 65 + p] = qreg[m * 4 + r];
        Vx[ch * 65 + p] = vreg[m * 4 + r];
      }
    __syncthreads();

    const size_t base7 = (size_t)(b * 64 + 56) * 512;
#pragma unroll
    for (int i = 0; i < 2; ++i) {  // coalesced k7/v7 -> o_k/o_v slot 7
      int idx = (tid + 512 * i) * 4;
      int c = idx >> 6, p0 = idx & 63;
      f32x4 kq, vq;
#pragma unroll
      for (int j = 0; j < 4; ++j) {
        kq[j] = combf[c * 65 + p0 + j];
        vq[j] = Vx[c * 65 + p0 + j];
      }
      ntst4(&o_k[base7 + idx], kq);
      ntst4(&o_v[base7 + idx], vq);
    }
    const int cs0 = d0 >> 6, po0 = d0 & 63, cs1 = d1 >> 6, po1 = d1 & 63;
    f32x4 q0, q1, v70, v71;
#pragma unroll
    for (int j = 0; j < 4; ++j) {
      q0[j] = Xb[(hd * 8 + cs0) * 65 + po0 + j];
      q1[j] = Xb[(hd * 8 + cs1) * 65 + po1 + j];
      v70[j] = Vx[(hd * 8 + cs0) * 65 + po0 + j];
      v71[j] = Vx[(hd * 8 + cs1) * 65 + po1 + j];
    }
    float sc7 = sc_lds[hd] + pos_b[7 * 8 + hd] + 5.0f;  // attn_mask_b

    // ---- K phase: consume kk regs (all loads already in flight) ----
    float scv[8];
    scv[7] = sc7;
#pragma unroll
    for (int m = 0; m < 7; ++m) {
      const float* pw = pos_w + m * 4096 + hd * 512;
      f32x4 k0 = kk0[m] + *(const f32x4*)&pw[d0];
      f32x4 k1 = kk1[m] + *(const f32x4*)&pw[d1];
      float* dst = o_k + ((size_t)((b * 8 + m) * 8 + hd)) * 512;
      ntst4(dst + d0, k0);
      ntst4(dst + d1, k1);
      float part = 0.f;
#pragma unroll
      for (int j = 0; j < 4; ++j) {
        part = fmaf(q0[j], k0[j], part);
        part = fmaf(q1[j], k1[j], part);
      }
#pragma unroll
      for (int off = 32; off >= 1; off >>= 1) part += __shfl_xor(part, off);
      float msk = amask[(b * 8 + hd) * 8 + m] ? -__builtin_inff() : 0.0f;
      scv[m] = part + pos_b[m * 8 + hd] + msk;
    }

    // ILP: batch-issue ALL 7 V-slot loads (independent of softmax)
    f32x4 vv0[7], vv1[7];
#pragma unroll
    for (int m = 0; m < 7; ++m) {
      const float* vp = cv + ((size_t)((b * 8 + m + 1) * 8 + hd)) * 512;
      vv0[m] = ntld4(vp + d0);
      vv1[m] = ntld4(vp + d1);
    }

    // softmax over 8 slots (redundant in every lane)
    float mx = scv[0];
#pragma unroll
    for (int m = 1; m < 8; ++m) mx = fmaxf(mx, scv[m]);
    float w[8], s = 0.f;
#pragma unroll
    for (int m = 0; m < 8; ++m) {
      w[m] = __expf(scv[m] - mx);
      s += w[m];
    }
    float inv = 1.0f / s;
#pragma unroll
    for (int m = 0; m < 8; ++m) w[m] *= inv;

    // ---- V phase: store + PV accumulate from resident regs ----
    f32x4 a0 = (f32x4){0.f, 0.f, 0.f, 0.f};
    f32x4 a1 = (f32x4){0.f, 0.f, 0.f, 0.f};
#pragma unroll
    for (int m = 0; m < 7; ++m) {
      float* dst = o_v + ((size_t)((b * 8 + m) * 8 + hd)) * 512;
      ntst4(dst + d0, vv0[m]);
      ntst4(dst + d1, vv1[m]);
      a0 += vv0[m] * w[m];
      a1 += vv1[m] * w[m];
    }
    a0 += v70 * w[7];
    a1 += v71 * w[7];

    s16x4 s0, s1;
#pragma unroll
    for (int j = 0; j < 4; ++j) {
      s0[j] = f2bf(a0[j]);
      s1[j] = f2bf(a1[j]);
    }
    // include the head offset hd*512 (R4 bug fix)
    *(s16x4*)&ws_attn[(size_t)b * 4096 + hd * 512 + d0] = s0;
    *(s16x4*)&ws_attn[(size_t)b * 4096 + hd * 512 + d1] = s1;
  } else {
    // ---------------- GATE BLOCK ----------------
    const int b = blockIdx.x - 512;
    // stage input+h -> 128ch rotated bf16 tile, c -> Xb
#pragma unroll
    for (int i = 0; i < 2; ++i) {
      int idx = (tid + 512 * i) * 4;
      int c = idx >> 6, p0 = idx & 63;
      f32x4 vi = *(const f32x4*)&input[b * 4096 + idx];
      f32x4 vh = *(const f32x4*)&h_cur[b * 4096 + idx];
      f32x4 vc = *(const f32x4*)&c_cur[b * 4096 + idx];
#pragma unroll
      for (int j = 0; j < 4; ++j) {
        int p = p0 + j;
        int pp = ((p >> 3) + 1) * 10 + (p & 7) + 1;
        comb[pp * 128 + ((c + pp * 8) & 127)] = f2bf(vi[j]);
        comb[pp * 128 + ((c + 64 + pp * 8) & 127)] = f2bf(vh[j]);
        Xb[c * 65 + p] = vc[j];
      }
    }
    for (int i = tid; i < 4608; i += 512) {  // pad ring
      int pr = i >> 7, c = i & 127;
      int pp = (pr < 10) ? pr
               : (pr < 20) ? (80 + pr)
               : (pr < 28) ? ((pr - 19) * 10)
                           : ((pr - 27) * 10 + 9);
      comb[pp * 128 + c] = 0;
    }
    __syncthreads();

    // conv1: M=64 N=320 K=1152
    f32x4 acc1[2][5];
#pragma unroll
    for (int m = 0; m < 2; ++m)
#pragma unroll
      for (int g = 0; g < 5; ++g) acc1[m][g] = (f32x4){0.f, 0.f, 0.f, 0.f};
    short8 bb1[5];
#pragma unroll
    for (int g = 0; g < 5; ++g)
      bb1[g] = *(const short8*)&pk1[((g4)*320 + g * 64 + ch) * 8];
    for (int s = 0; s < 36; ++s) {
      short8 bbn[5];
      if (s < 35) {
        int kb8 = (s + 1) * 4 + g4;
#pragma unroll
        for (int g = 0; g < 5; ++g)
          bbn[g] = *(const short8*)&pk1[(kb8 * 320 + g * 64 + ch) * 8];
      }
      int tap = s >> 2, cib = s & 3;
      int kh = tap / 3, kw = tap % 3;
      short8 a[2];
#pragma unroll
      for (int m = 0; m < 2; ++m) {
        int p = (wm * 2 + m) * 16 + col;
        int pp = ((p >> 3) + kh) * 10 + (p & 7) + kw;
        int slot = (cib * 32 + g4 * 8 + pp * 8) & 127;
        a[m] = *(const short8*)&comb[pp * 128 + slot];
      }
#pragma unroll
      for (int m = 0; m < 2; ++m)
#pragma unroll
        for (int g = 0; g < 5; ++g) acc1[m][g] = mfma16(a[m], bb1[g], acc1[m][g]);
      if (s < 35) {
#pragma unroll
        for (int g = 0; g < 5; ++g) bb1[g] = bbn[g];
      }
    }

    float ctv[8];
    unsigned oav[8];
    {
      float bi0 = conv_b[ch], bi1 = conv_b[64 + ch], bi2 = conv_b[128 + ch];
      float bi3 = conv_b[192 + ch], bi4 = conv_b[256 + ch];
#pragma unroll
      for (int m = 0; m < 2; ++m)
#pragma unroll
        for (int r = 0; r < 4; ++r) {
          int p = (wm * 2 + m) * 16 + g4 * 4 + r;
          float iv = sigm(acc1[m][0][r] + bi0);
          float fv = sigm(acc1[m][1][r] + bi1);
          float ov = sigm(acc1[m][2][r] + bi2);
          float gv = ftanh(acc1[m][3][r] + bi3);
          float av = sigm(acc1[m][4][r] + bi4);
          ctv[m * 4 + r] = fv * Xb[ch * 65 + p] + iv * gv;
          oav[m * 4 + r] = ((unsigned)(unsigned short)f2bf(av) << 16) |
                           (unsigned)(unsigned short)f2bf(ov);
        }
    }
    __syncthreads();  // conv tile + Xb(c) consumed
#pragma unroll
    for (int m = 0; m < 2; ++m)
#pragma unroll
      for (int r = 0; r < 4; ++r) {
        int p = (wm * 2 + m) * 16 + g4 * 4 + r;
        combf[ch * 65 + p] = ctv[m * 4 + r];
        Xbu[ch * 65 + p] = oav[m * 4 + r];
      }
    __syncthreads();
#pragma unroll
    for (int i = 0; i < 2; ++i) {  // coalesced scratch writes
      int idx = (tid + 512 * i) * 4;
      int c = idx >> 6, p0 = idx & 63;
      f32x4 cq;
      u32x4 oq;
#pragma unroll
      for (int j = 0; j < 4; ++j) {
        cq[j] = combf[c * 65 + p0 + j];
        oq[j] = Xbu[c * 65 + p0 + j];
      }
      *(f32x4*)&ws_ct[(size_t)b * 4096 + idx] = cq;
      *(u32x4*)&ws_oa[(size_t)b * 4096 + idx] = oq;
    }
  }
}

// back_k: conv3 + residual + LN + LSTM epilogue.
__launch_bounds__(512, 4)
__global__ void back_k(const float* __restrict__ input,
                       const short* __restrict__ ws_attn,
                       const float* __restrict__ ws_ct,
                       const unsigned* __restrict__ ws_oa,
                       const float* __restrict__ out_b,
                       const float* __restrict__ ln_w, const float* __restrict__ ln_b,
                       const short* __restrict__ pk3,
                       float* __restrict__ o_h, float* __restrict__ o_c) {
  __shared__ short comb[8320];  // 16.64 KB; first 6400 = 64ch tile, alias f32[4160]
  __shared__ float Xb[4160];
  __shared__ float red[16];
  float* combf = (float*)comb;
  unsigned* Xbu = (unsigned*)Xb;

  const int b = blockIdx.x;
  const int tid = threadIdx.x;
  const int wave = tid >> 6, lane = tid & 63;
  const int col = lane & 15, g4 = lane >> 4;
  const int wc = wave >> 1, wm = wave & 1;
  const int ch = wc * 16 + col;

  f32x4 ctr[2];
  u32x4 oar[2];
#pragma unroll
  for (int i = 0; i < 2; ++i) {  // early gate scratch loads (hide under conv3)
    int idx = (tid + 512 * i) * 4;
    ctr[i] = *(const f32x4*)&ws_ct[(size_t)b * 4096 + idx];
    oar[i] = *(const u32x4*)&ws_oa[(size_t)b * 4096 + idx];
  }
#pragma unroll
  for (int i = 0; i < 2; ++i) {  // stage attn(bf16) -> tile, input -> Xb
    int idx = (tid + 512 * i) * 4;
    int c = idx >> 6, p0 = idx & 63;
    s16x4 av = *(const s16x4*)&ws_attn[(size_t)b * 4096 + idx];
    f32x4 vi = *(const f32x4*)&input[b * 4096 + idx];
#pragma unroll
    for (int j = 0; j < 4; ++j) {
      int p = p0 + j;
      int pp = ((p >> 3) + 1) * 10 + (p & 7) + 1;
      comb[pp * 64 + ((c + pp * 8) & 63)] = av[j];
      Xb[c * 65 + p] = vi[j];
    }
  }
  for (int i = tid; i < 2304; i += 512) {  // pad ring
    int pr = i >> 6, c = i & 63;
    int pp = (pr < 10) ? pr
             : (pr < 20) ? (80 + pr)
             : (pr < 28) ? ((pr - 19) * 10)
                         : ((pr - 27) * 10 + 9);
    comb[pp * 64 + c] = 0;
  }
  __syncthreads();

  // conv3: M=64 N=64 K=576
  f32x4 acc3[2];
  acc3[0] = (f32x4){0.f, 0.f, 0.f, 0.f};
  acc3[1] = (f32x4){0.f, 0.f, 0.f, 0.f};
  short8 bb3 = *(const short8*)&pk3[((g4)*64 + ch) * 8];
  for (int s = 0; s < 18; ++s) {
    short8 bbn;
    if (s < 17) {
      int kb8 = (s + 1) * 4 + g4;
      bbn = *(const short8*)&pk3[(kb8 * 64 + ch) * 8];
    }
    int tap = s >> 1, cib = s & 1;
    int kh = tap / 3, kw = tap % 3;
    short8 a[2];
#pragma unroll
    for (int m = 0; m < 2; ++m) {
      int p = (wm * 2 + m) * 16 + col;
      int pp = ((p >> 3) + kh) * 10 + (p & 7) + kw;
      int slot = (cib * 32 + g4 * 8 + pp * 8) & 63;
      a[m] = *(const short8*)&comb[pp * 64 + slot];
    }
#pragma unroll
    for (int m = 0; m < 2; ++m) acc3[m] = mfma16(a[m], bb3, acc3[m]);
    if (s < 17) bb3 = bbn;
  }

  // residual + LN stats
  float ov_[8], s1 = 0.f, s2 = 0.f;
  {
    float ob = out_b[ch];
#pragma unroll
    for (int m = 0; m < 2; ++m)
#pragma unroll
      for (int r = 0; r < 4; ++r) {
        int p = (wm * 2 + m) * 16 + g4 * 4 + r;
        float v = acc3[m][r] + ob + Xb[ch * 65 + p];
        ov_[m * 4 + r] = v;
        s1 += v;
        s2 += v * v;
      }
  }
#pragma unroll
  for (int off = 32; off >= 1; off >>= 1) {
    s1 += __shfl_xor(s1, off);
    s2 += __shfl_xor(s2, off);
  }
  if (lane == 0) { red[wave] = s1; red[8 + wave] = s2; }
  __syncthreads();
  float ts1 = 0.f, ts2 = 0.f;
#pragma unroll
  for (int w = 0; w < 8; ++w) { ts1 += red[w]; ts2 += red[8 + w]; }
  float mu = ts1 * (1.0f / 4096.0f);
  float var = ts2 * (1.0f / 4096.0f) - mu * mu;
  float rstd = rsqrtf(var + 1e-5f);

  // bounce gate scratch regs (idx-order) -> LDS (ch,p)-order
#pragma unroll
  for (int i = 0; i < 2; ++i) {
    int idx = (tid + 512 * i) * 4;
    int c = idx >> 6, p0 = idx & 63;
#pragma unroll
    for (int j = 0; j < 4; ++j) {
      combf[c * 65 + p0 + j] = ctr[i][j];
      Xbu[c * 65 + p0 + j] = oar[i][j];
    }
  }
  __syncthreads();

  // epilogue: each lane owns its (ch,p); read ct/oa then overwrite with h/c
#pragma unroll
  for (int m = 0; m < 2; ++m)
#pragma unroll
    for (int r = 0; r < 4; ++r) {
      int p = (wm * 2 + m) * 16 + g4 * 4 + r;
      float ct = combf[ch * 65 + p];
      unsigned u = Xbu[ch * 65 + p];
      float og = __builtin_bit_cast(float, u << 16);
      float ag = __builtin_bit_cast(float, u & 0xffff0000u);
      float oln = (ov_[m * 4 + r] - mu) * rstd * ln_w[ch * 64 + p] + ln_b[ch * 64 + p];
      float cn = ct + ag * ftanh(oln);
      float hv = og * ftanh(cn);
      combf[ch * 65 + p] = hv;
      Xb[ch * 65 + p] = cn;
    }
  __syncthreads();
#pragma unroll
  for (int i = 0; i < 2; ++i) {
    int idx = (tid + 512 * i) * 4;
    int c = idx >> 6, p0 = idx & 63;
    f32x4 hq, cq;
#pragma unroll
    for (int j = 0; j < 4; ++j) {
      hq[j] = combf[c * 65 + p0 + j];
      cq[j] = Xb[c * 65 + p0 + j];
    }
    *(f32x4*)&o_h[b * 4096 + idx] = hq;
    *(f32x4*)&o_c[b * 4096 + idx] = cq;
  }
}

// ===========================================================================
// Fallback path (R3, proven): used only if ws_size < 24 MB.
// ===========================================================================
__launch_bounds__(512, 4)
__global__ void kqv_k(const float* __restrict__ input,
                      const float* __restrict__ proj_b,
                      const float* __restrict__ pos_w,
                      const short* __restrict__ pk2,
                      float* __restrict__ q_out, float* __restrict__ o_k,
                      float* __restrict__ o_v) {
  __shared__ short comb[6400];
  __shared__ float Xk[4160], Xq[4160], Xv[4160];
  const int b = blockIdx.x;
  const int tid = threadIdx.x;
  const int wave = tid >> 6, lane = tid & 63;
  const int col = lane & 15, g4 = lane >> 4;
  const int wc = wave >> 1, wm = wave & 1;
  const int ch = wc * 16 + col;
#pragma unroll
  for (int i = 0; i < 2; ++i) {
    int idx = (tid + 512 * i) * 4;
    int c = idx >> 6, p0 = idx & 63;
    f32x4 vi = *(const f32x4*)&input[b * 4096 + idx];
#pragma unroll
    for (int j = 0; j < 4; ++j) {
      int p = p0 + j;
      int pp = ((p >> 3) + 1) * 10 + (p & 7) + 1;
      comb[pp * 64 + ((c + pp * 8) & 63)] = f2bf(vi[j]);
    }
  }
  for (int i = tid; i < 2304; i += 512) {
    int pr = i >> 6, c = i & 63;
    int pp = (pr < 10) ? pr
             : (pr < 20) ? (80 + pr)
             : (pr < 28) ? ((pr - 19) * 10)
                         : ((pr - 27) * 10 + 9);
    comb[pp * 64 + c] = 0;
  }
  __syncthreads();
  f32x4 acc2[2][3];
#pragma unroll
  for (int m = 0; m < 2; ++m)
#pragma unroll
    for (int g = 0; g < 3; ++g) acc2[m][g] = (f32x4){0.f, 0.f, 0.f, 0.f};
  short8 bb2[3];
#pragma unroll
  for (int g = 0; g < 3; ++g)
    bb2[g] = *(const short8*)&pk2[((g4)*192 + g * 64 + ch) * 8];
  for (int s = 0; s < 18; ++s) {
    short8 bbn[3];
    if (s < 17) {
      int kb8 = (s + 1) * 4 + g4;
#pragma unroll
      for (int g = 0; g < 3; ++g)
        bbn[g] = *(const short8*)&pk2[(kb8 * 192 + g * 64 + ch) * 8];
    }
    int tap = s >> 1, cib = s & 1;
    int kh = tap / 3, kw = tap % 3;
    short8 a[2];
#pragma unroll
    for (int m = 0; m < 2; ++m) {
      int p = (wm * 2 + m) * 16 + col;
      int pp = ((p >> 3) + kh) * 10 + (p & 7) + kw;
      int slot = (cib * 32 + g4 * 8 + pp * 8) & 63;
      a[m] = *(const short8*)&comb[pp * 64 + slot];
    }
#pragma unroll
    for (int m = 0; m < 2; ++m)
#pragma unroll
      for (int g = 0; g < 3; ++g) acc2[m][g] = mfma16(a[m], bb2[g], acc2[m][g]);
    if (s < 17) {
#pragma unroll
      for (int g = 0; g < 3; ++g) bb2[g] = bbn[g];
    }
  }
  {
    float pb0 = proj_b[ch], pb1 = proj_b[64 + ch], pb2 = proj_b[128 + ch];
    const float rsq = 0.044194173824159216f;
#pragma unroll
    for (int m = 0; m < 2; ++m)
#pragma unroll
      for (int r = 0; r < 4; ++r) {
        int p = (wm * 2 + m) * 16 + g4 * 4 + r;
        Xk[ch * 65 + p] = acc2[m][0][r] + pb0 + pos_w[7 * 4096 + ch * 64 + p];
        Xq[ch * 65 + p] = (acc2[m][1][r] + pb1) * rsq;
        Xv[ch * 65 + p] = acc2[m][2][r] + pb2;
      }
  }
  __syncthreads();
  const size_t base7 = (size_t)(b * 64 + 56) * 512;
#pragma unroll
  for (int i = 0; i < 2; ++i) {
    int idx = (tid + 512 * i) * 4;
    int c = idx >> 6, p0 = idx & 63;
    f32x4 kq, qq, vq;
#pragma unroll
    for (int j = 0; j < 4; ++j) {
      kq[j] = Xk[c * 65 + p0 + j];
      qq[j] = Xq[c * 65 + p0 + j];
      vq[j] = Xv[c * 65 + p0 + j];
    }
    *(f32x4*)&o_k[base7 + idx] = kq;
    *(f32x4*)&q_out[(size_t)b * 4096 + idx] = qq;
    *(f32x4*)&o_v[base7 + idx] = vq;
  }
}

__launch_bounds__(64, 4)
__global__ void attn_k(const float* __restrict__ ck, const float* __restrict__ cv,
                       const int* __restrict__ amask,
                       const float* __restrict__ pos_w,
                       const float* __restrict__ pos_b,
                       const float* __restrict__ q_in,
                       float* __restrict__ o_k, float* __restrict__ o_v,
                       float* __restrict__ attn_out) {
  const int b = blockIdx.x >> 3;
  const int hd = blockIdx.x & 7;
  const int lane = threadIdx.x;
  const int d0 = lane * 4, d1 = (lane + 64) * 4;
  const float* qp = q_in + (size_t)b * 4096 + hd * 512;
  f32x4 q0 = *(const f32x4*)&qp[d0];
  f32x4 q1 = *(const f32x4*)&qp[d1];
  float sc[8];
#pragma unroll
  for (int m = 0; m < 7; ++m) {
    const float* kp = ck + ((size_t)((b * 8 + m + 1) * 8 + hd)) * 512;
    const float* pw = pos_w + m * 4096 + hd * 512;
    f32x4 k0 = ntld4(kp + d0) + *(const f32x4*)&pw[d0];
    f32x4 k1 = ntld4(kp + d1) + *(const f32x4*)&pw[d1];
    float* dst = o_k + ((size_t)((b * 8 + m) * 8 + hd)) * 512;
    ntst4(dst + d0, k0);
    ntst4(dst + d1, k1);
    float part = 0.f;
#pragma unroll
    for (int j = 0; j < 4; ++j) {
      part = fmaf(q0[j], k0[j], part);
      part = fmaf(q1[j], k1[j], part);
    }
#pragma unroll
    for (int off = 32; off >= 1; off >>= 1) part += __shfl_xor(part, off);
    float msk = amask[(b * 8 + hd) * 8 + m] ? -__builtin_inff() : 0.0f;
    sc[m] = part + pos_b[m * 8 + hd] + msk;
  }
  {
    const float* kp = o_k + ((size_t)((b * 8 + 7) * 8 + hd)) * 512;
    f32x4 k0 = *(const f32x4*)&kp[d0];
    f32x4 k1 = *(const f32x4*)&kp[d1];
    float part = 0.f;
#pragma unroll
    for (int j = 0; j < 4; ++j) {
      part = fmaf(q0[j], k0[j], part);
      part = fmaf(q1[j], k1[j], part);
    }
#pragma unroll
    for (int off = 32; off >= 1; off >>= 1) part += __shfl_xor(part, off);
    sc[7] = part + pos_b[7 * 8 + hd] + 5.0f;
  }
  float mx = sc[0];
#pragma unroll
  for (int m = 1; m < 8; ++m) mx = fmaxf(mx, sc[m]);
  float w[8], s = 0.f;
#pragma unroll
  for (int m = 0; m < 8; ++m) {
    w[m] = __expf(sc[m] - mx);
    s += w[m];
  }
  float inv = 1.0f / s;
#pragma unroll
  for (int m = 0; m < 8; ++m) w[m] *= inv;
  f32x4 a0 = (f32x4){0.f, 0.f, 0.f, 0.f};
  f32x4 a1 = (f32x4){0.f, 0.f, 0.f, 0.f};
#pragma unroll
  for (int m = 0; m < 7; ++m) {
    const float* vp = cv + ((size_t)((b * 8 + m + 1) * 8 + hd)) * 512;
    f32x4 v0 = ntld4(vp + d0);
    f32x4 v1 = ntld4(vp + d1);
    float* dst = o_v + ((size_t)((b * 8 + m) * 8 + hd)) * 512;
    ntst4(dst + d0, v0);
    ntst4(dst + d1, v1);
    a0 += v0 * w[m];
    a1 += v1 * w[m];
  }
  {
    const float* vp = o_v + ((size_t)((b * 8 + 7) * 8 + hd)) * 512;
    a0 += *(const f32x4*)&vp[d0] * w[7];
    a1 += *(const f32x4*)&vp[d1] * w[7];
  }
  float* ap = attn_out + (size_t)b * 4096 + hd * 512;
  *(f32x4*)&ap[d0] = a0;
  *(f32x4*)&ap[d1] = a1;
}

__launch_bounds__(512, 4)
__global__ void cell2_k(
    const float* __restrict__ input, const float* __restrict__ h_cur,
    const float* __restrict__ c_cur, const float* __restrict__ attn_in,
    const float* __restrict__ conv_b, const float* __restrict__ out_b,
    const float* __restrict__ ln_w, const float* __restrict__ ln_b,
    const short* __restrict__ pk1, const short* __restrict__ pk3,
    float* __restrict__ o_h, float* __restrict__ o_c) {
  __shared__ short comb[12800];
  __shared__ float Xb[4160];
  __shared__ float Qb[4160];
  __shared__ float Vb[4160];
  __shared__ float red[16];
  const int b = blockIdx.x;
  const int tid = threadIdx.x;
  const int wave = tid >> 6, lane = tid & 63;
  const int col = lane & 15, g4 = lane >> 4;
  const int wc = wave >> 1, wm = wave & 1;
  const int ch = wc * 16 + col;
#pragma unroll
  for (int i = 0; i < 2; ++i) {
    int idx = (tid + 512 * i) * 4;
    int c = idx >> 6, p0 = idx & 63;
    f32x4 vi = *(const f32x4*)&input[b * 4096 + idx];
    f32x4 vh = *(const f32x4*)&h_cur[b * 4096 + idx];
    f32x4 vc = *(const f32x4*)&c_cur[b * 4096 + idx];
#pragma unroll
    for (int j = 0; j < 4; ++j) {
      int p = p0 + j;
      int pp = ((p >> 3) + 1) * 10 + (p & 7) + 1;
      comb[pp * 128 + ((c + pp * 8) & 127)] = f2bf(vi[j]);
      comb[pp * 128 + ((c + 64 + pp * 8) & 127)] = f2bf(vh[j]);
      Xb[c * 65 + p] = vc[j];
    }
  }
  for (int i = tid; i < 4608; i += 512) {
    int pr = i >> 7, c = i & 127;
    int pp = (pr < 10) ? pr
             : (pr < 20) ? (80 + pr)
             : (pr < 28) ? ((pr - 19) * 10)
                         : ((pr - 27) * 10 + 9);
    comb[pp * 128 + c] = 0;
  }
  __syncthreads();
  f32x4 acc1[2][5];
#pragma unroll
  for (int m = 0; m < 2; ++m)
#pragma unroll
    for (int g = 0; g < 5; ++g) acc1[m][g] = (f32x4){0.f, 0.f, 0.f, 0.f};
  short8 bb1[5];
#pragma unroll
  for (int g = 0; g < 5; ++g)
    bb1[g] = *(const short8*)&pk1[((g4)*320 + g * 64 + ch) * 8];
  for (int s = 0; s < 36; ++s) {
    short8 bbn[5];
    if (s < 35) {
      int kb8 = (s + 1) * 4 + g4;
#pragma unroll
      for (int g = 0; g < 5; ++g)
        bbn[g] = *(const short8*)&pk1[(kb8 * 320 + g * 64 + ch) * 8];
    }
    int tap = s >> 2, cib = s & 3;
    int kh = tap / 3, kw = tap % 3;
    short8 a[2];
#pragma unroll
    for (int m = 0; m < 2; ++m) {
      int p = (wm * 2 + m) * 16 + col;
      int pp = ((p >> 3) + kh) * 10 + (p & 7) + kw;
      int slot = (cib * 32 + g4 * 8 + pp * 8) & 127;
      a[m] = *(const short8*)&comb[pp * 128 + slot];
    }
#pragma unroll
    for (int m = 0; m < 2; ++m)
#pragma unroll
      for (int g = 0; g < 5; ++g) acc1[m][g] = mfma16(a[m], bb1[g], acc1[m][g]);
    if (s < 35) {
#pragma unroll
      for (int g = 0; g < 5; ++g) bb1[g] = bbn[g];
    }
  }
  float ct_r[8], o_r[8], a_r[8];
  {
    float bi0 = conv_b[ch], bi1 = conv_b[64 + ch], bi2 = conv_b[128 + ch];
    float bi3 = conv_b[192 + ch], bi4 = conv_b[256 + ch];
#pragma unroll
    for (int m = 0; m < 2; ++m)
#pragma unroll
      for (int r = 0; r < 4; ++r) {
        int p = (wm * 2 + m) * 16 + g4 * 4 + r;
        float iv = sigm(acc1[m][0][r] + bi0);
        float fv = sigm(acc1[m][1][r] + bi1);
        float ov = sigm(acc1[m][2][r] + bi2);
        float gv = ftanh(acc1[m][3][r] + bi3);
        float av = sigm(acc1[m][4][r] + bi4);
        ct_r[m * 4 + r] = fv * Xb[ch * 65 + p] + iv * gv;
        o_r[m * 4 + r] = ov;
        a_r[m * 4 + r] = av;
      }
  }
  __syncthreads();
  {
    f32x4 av[2], iv[2];
#pragma unroll
    for (int i = 0; i < 2; ++i) {
      int idx = (tid + 512 * i) * 4;
      av[i] = *(const f32x4*)&attn_in[b * 4096 + idx];
      iv[i] = *(const f32x4*)&input[b * 4096 + idx];
    }
#pragma unroll
    for (int i = 0; i < 2; ++i) {
      int idx = (tid + 512 * i) * 4;
      int c = idx >> 6, p0 = idx & 63;
#pragma unroll
      for (int j = 0; j < 4; ++j) {
        int p = p0 + j;
        int pp = ((p >> 3) + 1) * 10 + (p & 7) + 1;
        comb[pp * 128 + ((c + pp * 8) & 127)] = f2bf(av[i][j]);
        Xb[c * 65 + p] = iv[i][j];
      }
    }
  }
  __syncthreads();
  f32x4 acc3[2];
  acc3[0] = (f32x4){0.f, 0.f, 0.f, 0.f};
  acc3[1] = (f32x4){0.f, 0.f, 0.f, 0.f};
  short8 bb3 = *(const short8*)&pk3[((g4)*64 + ch) * 8];
  for (int s = 0; s < 18; ++s) {
    short8 bbn;
    if (s < 17) {
      int kb8 = (s + 1) * 4 + g4;
      bbn = *(const short8*)&pk3[(kb8 * 64 + ch) * 8];
    }
    int tap = s >> 1, cib = s & 1;
    int kh = tap / 3, kw = tap % 3;
    short8 a[2];
#pragma unroll
    for (int m = 0; m < 2; ++m) {
      int p = (wm * 2 + m) * 16 + col;
      int pp = ((p >> 3) + kh) * 10 + (p & 7) + kw;
      int slot = (cib * 32 + g4 * 8 + pp * 8) & 127;
      a[m] = *(const short8*)&comb[pp * 128 + slot];
    }
#pragma unroll
    for (int m = 0; m < 2; ++m) acc3[m] = mfma16(a[m], bb3, acc3[m]);
    if (s < 17) bb3 = bbn;
  }
  float ov_[8], s1 = 0.f, s2 = 0.f;
  {
    float ob = out_b[ch];
#pragma unroll
    for (int m = 0; m < 2; ++m)
#pragma unroll
      for (int r = 0; r < 4; ++r) {
        int p = (wm * 2 + m) * 16 + g4 * 4 + r;
        float v = acc3[m][r] + ob + Xb[ch * 65 + p];
        ov_[m * 4 + r] = v;
        s1 += v;
        s2 += v * v;
      }
  }
#pragma unroll
  for (int off = 32; off >= 1; off >>= 1) {
    s1 += __shfl_xor(s1, off);
    s2 += __shfl_xor(s2, off);
  }
  if (lane == 0) { red[wave] = s1; red[8 + wave] = s2; }
  __syncthreads();
  float ts1 = 0.f, ts2 = 0.f;
#pragma unroll
  for (int w = 0; w < 8; ++w) { ts1 += red[w]; ts2 += red[8 + w]; }
  float mu = ts1 * (1.0f / 4096.0f);
  float var = ts2 * (1.0f / 4096.0f) - mu * mu;
  float rstd = rsqrtf(var + 1e-5f);
#pragma unroll
  for (int m = 0; m < 2; ++m)
#pragma unroll
    for (int r = 0; r < 4; ++r) {
      int p = (wm * 2 + m) * 16 + g4 * 4 + r;
      float oln = (ov_[m * 4 + r] - mu) * rstd * ln_w[ch * 64 + p] + ln_b[ch * 64 + p];
      float cn = ct_r[m * 4 + r] + a_r[m * 4 + r] * ftanh(oln);
      float hv = o_r[m * 4 + r] * ftanh(cn);
      Qb[ch * 65 + p] = hv;
      Vb[ch * 65 + p] = cn;
    }
  __syncthreads();
#pragma unroll
  for (int i = 0; i < 2; ++i) {
    int idx = (tid + 512 * i) * 4;
    int c = idx >> 6, p0 = idx & 63;
    f32x4 hv, cvv;
#pragma unroll
    for (int j = 0; j < 4; ++j) {
      hv[j] = Qb[c * 65 + p0 + j];
      cvv[j] = Vb[c * 65 + p0 + j];
    }
    *(f32x4*)&o_h[b * 4096 + idx] = hv;
    *(f32x4*)&o_c[b * 4096 + idx] = cvv;
  }
}

extern "C" void kernel_launch(void* const* d_in, const int* in_sizes, int n_in,
                              void* d_out, int out_size, void* d_ws, size_t ws_size,
                              hipStream_t stream) {
  (void)in_sizes; (void)n_in; (void)out_size;
  const float* input  = (const float*)d_in[0];
  const float* h_cur  = (const float*)d_in[1];
  const float* c_cur  = (const float*)d_in[2];
  const float* ck     = (const float*)d_in[3];
  const float* cv     = (const float*)d_in[4];
  const int*   amask  = (const int*)d_in[5];
  const float* conv_w = (const float*)d_in[6];
  const float* conv_b = (const float*)d_in[7];
  const float* proj_w = (const float*)d_in[8];
  const float* proj_b = (const float*)d_in[9];
  const float* out_w  = (const float*)d_in[10];
  const float* out_b  = (const float*)d_in[11];
  const float* ln_w   = (const float*)d_in[12];
  const float* ln_b   = (const float*)d_in[13];
  const float* pos_w  = (const float*)d_in[14];
  const float* pos_b  = (const float*)d_in[15];

  char* ws = (char*)d_ws;
  short* pk = (short*)ws;  // 516096 shorts = 1.03 MB
  float* o_h = (float*)d_out;
  float* o_c = o_h + 2097152;
  float* o_k = o_h + 4194304;
  float* o_v = o_h + 20971520;

  pack_w<<<252, 256, 0, stream>>>(conv_w, proj_w, out_w, pk);

  if (ws_size >= (24u << 20)) {
    short* ws_attn = (short*)(ws + (2u << 20));      // 4 MB bf16
    float* ws_ct = (float*)(ws + (8u << 20));        // 8 MB f32
    unsigned* ws_oa = (unsigned*)(ws + (16u << 20)); // 8 MB packed bf16x2
    mid_k<<<1024, 512, 0, stream>>>(input, h_cur, c_cur, ck, cv, amask,
                                    conv_b, proj_b, pos_w, pos_b,
                                    pk, pk + 368640,
                                    o_k, o_v, ws_attn, ws_ct, ws_oa);
    back_k<<<512, 512, 0, stream>>>(input, ws_attn, ws_ct, ws_oa,
                                    out_b, ln_w, ln_b, pk + 479232, o_h, o_c);
  } else {
    // fallback: proven R3 pipeline (scratch lives in d_out regions)
    kqv_k<<<512, 512, 0, stream>>>(input, proj_b, pos_w, pk + 368640,
                                   o_h, o_k, o_v);
    attn_k<<<4096, 64, 0, stream>>>(ck, cv, amask, pos_w, pos_b, o_h,
                                    o_k, o_v, o_c);
    cell2_k<<<512, 512, 0, stream>>>(input, h_cur, c_cur, o_c,
                                     conv_b, out_b, ln_w, ln_b,
                                     pk, pk + 479232, o_h, o_c);
  }
}

// Round 8
// 99.340 us; speedup vs baseline: 1.7819x; 1.0668x over previous
//
#include <hip/hip_runtime.h>

typedef short short8 __attribute__((ext_vector_type(8)));
typedef __bf16 bf16x8 __attribute__((ext_vector_type(8)));
typedef float f32x4 __attribute__((ext_vector_type(4)));
typedef short s16x4 __attribute__((ext_vector_type(4)));
typedef unsigned u32x4 __attribute__((ext_vector_type(4)));

__device__ __forceinline__ short f2bf(float f) {
  unsigned u = __builtin_bit_cast(unsigned, f);
  u = (u + 0x7FFFu + ((u >> 16) & 1u)) >> 16;
  return (short)u;
}
__device__ __forceinline__ f32x4 mfma16(short8 a, short8 b, f32x4 c) {
  return __builtin_amdgcn_mfma_f32_16x16x32_bf16(
      __builtin_bit_cast(bf16x8, a), __builtin_bit_cast(bf16x8, b), c, 0, 0, 0);
}
__device__ __forceinline__ float sigm(float x) { return 1.0f / (1.0f + __expf(-x)); }
__device__ __forceinline__ float ftanh(float x) {
  return 1.0f - 2.0f / (1.0f + __expf(2.0f * x));
}
__device__ __forceinline__ f32x4 ld4(const float* p) { return *(const f32x4*)p; }
__device__ __forceinline__ void ntst4(float* p, f32x4 v) {
  __builtin_nontemporal_store(v, (f32x4*)p);
}

// ---------------------------------------------------------------------------
// Weight pre-pack: f32 [CO][CI][3][3] -> bf16 [K/8][CO][8], K = tap*CI + ci.
// ---------------------------------------------------------------------------
__global__ void pack_w(const float* __restrict__ w1, const float* __restrict__ w2,
                       const float* __restrict__ w3, short* __restrict__ out) {
  int e = blockIdx.x * 256 + threadIdx.x;
  if (e < 46080) {
    int kb8 = e / 320, n = e % 320;
    short8 v;
#pragma unroll
    for (int j = 0; j < 8; ++j) {
      int k = kb8 * 8 + j;
      int tap = k >> 7, ci = k & 127;
      v[j] = f2bf(w1[(n * 128 + ci) * 9 + tap]);
    }
    *(short8*)&out[e * 8] = v;
    return;
  }
  e -= 46080;
  if (e < 13824) {
    int kb8 = e / 192, n = e % 192;
    short8 v;
#pragma unroll
    for (int j = 0; j < 8; ++j) {
      int k = kb8 * 8 + j;
      int tap = k >> 6, ci = k & 63;
      v[j] = f2bf(w2[(n * 64 + ci) * 9 + tap]);
    }
    *(short8*)&out[(46080 + e) * 8] = v;
    return;
  }
  e -= 13824;
  {
    int kb8 = e / 64, n = e % 64;
    short8 v;
#pragma unroll
    for (int j = 0; j < 8; ++j) {
      int k = kb8 * 8 + j;
      int tap = k >> 6, ci = k & 63;
      v[j] = f2bf(w3[(n * 64 + ci) * 9 + tap]);
    }
    *(short8*)&out[(46080 + 13824 + e) * 8] = v;
  }
}

// ===========================================================================
// R8 main path:
//   mid2_k: [0..511] conv2 + K-stream + scores + softmax -> ws_wt
//           [512..1023] conv1 gates -> ws_ct / ws_oa
//   tail_k: V-stream + PV + conv3 + LN + LSTM epilogue (fused)
// Loads are PLAIN (L2/L3-cacheable; nt loads were forcing HBM latency);
// stores to final-only streams stay nontemporal; v7 plain (re-read by tail).
// ===========================================================================
__launch_bounds__(512, 4)
__global__ void mid2_k(const float* __restrict__ input, const float* __restrict__ h_cur,
                       const float* __restrict__ c_cur, const float* __restrict__ ck,
                       const int* __restrict__ amask,
                       const float* __restrict__ conv_b, const float* __restrict__ proj_b,
                       const float* __restrict__ pos_w, const float* __restrict__ pos_b,
                       const short* __restrict__ pk1, const short* __restrict__ pk2,
                       float* __restrict__ o_k, float* __restrict__ o_v,
                       float* __restrict__ ws_wt, float* __restrict__ ws_ct,
                       unsigned* __restrict__ ws_oa) {
  __shared__ short comb[12800];  // bf16 tile; later aliased as f32[4160]
  __shared__ float Xb[4160];
  __shared__ float Vx[4160];
  __shared__ float sc_lds[8];
  float* combf = (float*)comb;
  unsigned* Xbu = (unsigned*)Xb;

  const int tid = threadIdx.x;
  const int wave = tid >> 6, lane = tid & 63;
  const int col = lane & 15, g4 = lane >> 4;
  const int wc = wave >> 1, wm = wave & 1;
  const int ch = wc * 16 + col;

  if (blockIdx.x < 512) {
    // ---------------- ATTENTION (K/scores) BLOCK ----------------
    const int b = blockIdx.x;
    const int hd = wave;
    const int d0 = lane * 4, d1 = (lane + 64) * 4;
    if (tid < 8) sc_lds[tid] = 0.f;

    // stage input -> 64ch rotated bf16 tile
#pragma unroll
    for (int i = 0; i < 2; ++i) {
      int idx = (tid + 512 * i) * 4;
      int c = idx >> 6, p0 = idx & 63;
      f32x4 vi = ld4(&input[b * 4096 + idx]);
#pragma unroll
      for (int j = 0; j < 4; ++j) {
        int p = p0 + j;
        int pp = ((p >> 3) + 1) * 10 + (p & 7) + 1;
        comb[pp * 64 + ((c + pp * 8) & 63)] = f2bf(vi[j]);
      }
    }
    for (int i = tid; i < 2304; i += 512) {  // pad ring
      int pr = i >> 6, c = i & 63;
      int pp = (pr < 10) ? pr
               : (pr < 20) ? (80 + pr)
               : (pr < 28) ? ((pr - 19) * 10)
                           : ((pr - 27) * 10 + 9);
      comb[pp * 64 + c] = 0;
    }
    __syncthreads();

    // conv2: M=64 N=192 K=576
    f32x4 acc2[2][3];
#pragma unroll
    for (int m = 0; m < 2; ++m)
#pragma unroll
      for (int g = 0; g < 3; ++g) acc2[m][g] = (f32x4){0.f, 0.f, 0.f, 0.f};
    short8 bb2[3];
#pragma unroll
    for (int g = 0; g < 3; ++g)
      bb2[g] = *(const short8*)&pk2[((g4)*192 + g * 64 + ch) * 8];
    for (int s = 0; s < 18; ++s) {
      short8 bbn[3];
      if (s < 17) {
        int kb8 = (s + 1) * 4 + g4;
#pragma unroll
        for (int g = 0; g < 3; ++g)
          bbn[g] = *(const short8*)&pk2[(kb8 * 192 + g * 64 + ch) * 8];
      }
      int tap = s >> 1, cib = s & 1;
      int kh = tap / 3, kw = tap % 3;
      short8 a[2];
#pragma unroll
      for (int m = 0; m < 2; ++m) {
        int p = (wm * 2 + m) * 16 + col;
        int pp = ((p >> 3) + kh) * 10 + (p & 7) + kw;
        int slot = (cib * 32 + g4 * 8 + pp * 8) & 63;
        a[m] = *(const short8*)&comb[pp * 64 + slot];
      }
#pragma unroll
      for (int m = 0; m < 2; ++m)
#pragma unroll
        for (int g = 0; g < 3; ++g) acc2[m][g] = mfma16(a[m], bb2[g], acc2[m][g]);
      if (s < 17) {
#pragma unroll
        for (int g = 0; g < 3; ++g) bb2[g] = bbn[g];
      }
    }

    // k,q,v in (ch,p) regs; slot-7 score partial
    float kreg[8], qreg[8], vreg[8], part7 = 0.f;
    {
      float pb0 = proj_b[ch], pb1 = proj_b[64 + ch], pb2 = proj_b[128 + ch];
      const float rsq = 0.044194173824159216f;  // 1/sqrt(512)
#pragma unroll
      for (int m = 0; m < 2; ++m)
#pragma unroll
        for (int r = 0; r < 4; ++r) {
          int p = (wm * 2 + m) * 16 + g4 * 4 + r;
          float kf = acc2[m][0][r] + pb0 + pos_w[7 * 4096 + ch * 64 + p];
          float qf = (acc2[m][1][r] + pb1) * rsq;
          float vf = acc2[m][2][r] + pb2;
          kreg[m * 4 + r] = kf;
          qreg[m * 4 + r] = qf;
          vreg[m * 4 + r] = vf;
          part7 = fmaf(qf, kf, part7);
        }
    }
    atomicAdd(&sc_lds[ch >> 3], part7);

    // hoist per-slot uniforms (were dependent loads inside the K loop)
    int msks[7];
    float pbv[7];
#pragma unroll
    for (int m = 0; m < 7; ++m) {
      msks[m] = amask[(b * 8 + hd) * 8 + m];
      pbv[m] = pos_b[m * 8 + hd];
    }

    // all waves must finish READING comb before bounce overwrites it
    __syncthreads();

    // single-pass bounce: k -> combf, q -> Xb, v -> Vx
#pragma unroll
    for (int m = 0; m < 2; ++m)
#pragma unroll
      for (int r = 0; r < 4; ++r) {
        int p = (wm * 2 + m) * 16 + g4 * 4 + r;
        combf[ch * 65 + p] = kreg[m * 4 + r];
        Xb[ch * 65 + p] = qreg[m * 4 + r];
        Vx[ch * 65 + p] = vreg[m * 4 + r];
      }
    __syncthreads();

    const size_t base7 = (size_t)(b * 64 + 56) * 512;
#pragma unroll
    for (int i = 0; i < 2; ++i) {  // coalesced k7/v7 -> o_k/o_v slot 7
      int idx = (tid + 512 * i) * 4;
      int c = idx >> 6, p0 = idx & 63;
      f32x4 kq, vq;
#pragma unroll
      for (int j = 0; j < 4; ++j) {
        kq[j] = combf[c * 65 + p0 + j];
        vq[j] = Vx[c * 65 + p0 + j];
      }
      ntst4(&o_k[base7 + idx], kq);                  // final, never re-read
      *(f32x4*)&o_v[base7 + idx] = vq;               // re-read by tail_k
    }
    const int cs0 = d0 >> 6, po0 = d0 & 63, cs1 = d1 >> 6, po1 = d1 & 63;
    f32x4 q0, q1;
#pragma unroll
    for (int j = 0; j < 4; ++j) {
      q0[j] = Xb[(hd * 8 + cs0) * 65 + po0 + j];
      q1[j] = Xb[(hd * 8 + cs1) * 65 + po1 + j];
    }
    float sc7 = sc_lds[hd] + pos_b[7 * 8 + hd] + 5.0f;  // attn_mask_b

    // ---- K-stream: plain loads (L2/L3-cacheable), nt stores ----
    float scv[8];
    scv[7] = sc7;
#pragma unroll
    for (int m = 0; m < 7; ++m) {
      const float* kp = ck + ((size_t)((b * 8 + m + 1) * 8 + hd)) * 512;
      const float* pw = pos_w + m * 4096 + hd * 512;
      f32x4 k0 = ld4(kp + d0) + ld4(pw + d0);
      f32x4 k1 = ld4(kp + d1) + ld4(pw + d1);
      float* dst = o_k + ((size_t)((b * 8 + m) * 8 + hd)) * 512;
      ntst4(dst + d0, k0);
      ntst4(dst + d1, k1);
      float part = 0.f;
#pragma unroll
      for (int j = 0; j < 4; ++j) {
        part = fmaf(q0[j], k0[j], part);
        part = fmaf(q1[j], k1[j], part);
      }
#pragma unroll
      for (int off = 32; off >= 1; off >>= 1) part += __shfl_xor(part, off);
      scv[m] = part + pbv[m] + (msks[m] ? -__builtin_inff() : 0.0f);
    }

    // softmax over 8 slots (redundant in every lane)
    float mx = scv[0];
#pragma unroll
    for (int m = 1; m < 8; ++m) mx = fmaxf(mx, scv[m]);
    float w[8], s = 0.f;
#pragma unroll
    for (int m = 0; m < 8; ++m) {
      w[m] = __expf(scv[m] - mx);
      s += w[m];
    }
    float inv = 1.0f / s;
    if (lane == 0) {
#pragma unroll
      for (int m = 0; m < 8; ++m)
        ws_wt[(size_t)b * 64 + hd * 8 + m] = w[m] * inv;
    }
  } else {
    // ---------------- GATE BLOCK ----------------
    const int b = blockIdx.x - 512;
#pragma unroll
    for (int i = 0; i < 2; ++i) {
      int idx = (tid + 512 * i) * 4;
      int c = idx >> 6, p0 = idx & 63;
      f32x4 vi = ld4(&input[b * 4096 + idx]);
      f32x4 vh = ld4(&h_cur[b * 4096 + idx]);
      f32x4 vc = ld4(&c_cur[b * 4096 + idx]);
#pragma unroll
      for (int j = 0; j < 4; ++j) {
        int p = p0 + j;
        int pp = ((p >> 3) + 1) * 10 + (p & 7) + 1;
        comb[pp * 128 + ((c + pp * 8) & 127)] = f2bf(vi[j]);
        comb[pp * 128 + ((c + 64 + pp * 8) & 127)] = f2bf(vh[j]);
        Xb[c * 65 + p] = vc[j];
      }
    }
    for (int i = tid; i < 4608; i += 512) {  // pad ring
      int pr = i >> 7, c = i & 127;
      int pp = (pr < 10) ? pr
               : (pr < 20) ? (80 + pr)
               : (pr < 28) ? ((pr - 19) * 10)
                           : ((pr - 27) * 10 + 9);
      comb[pp * 128 + c] = 0;
    }
    __syncthreads();

    // conv1: M=64 N=320 K=1152
    f32x4 acc1[2][5];
#pragma unroll
    for (int m = 0; m < 2; ++m)
#pragma unroll
      for (int g = 0; g < 5; ++g) acc1[m][g] = (f32x4){0.f, 0.f, 0.f, 0.f};
    short8 bb1[5];
#pragma unroll
    for (int g = 0; g < 5; ++g)
      bb1[g] = *(const short8*)&pk1[((g4)*320 + g * 64 + ch) * 8];
    for (int s = 0; s < 36; ++s) {
      short8 bbn[5];
      if (s < 35) {
        int kb8 = (s + 1) * 4 + g4;
#pragma unroll
        for (int g = 0; g < 5; ++g)
          bbn[g] = *(const short8*)&pk1[(kb8 * 320 + g * 64 + ch) * 8];
      }
      int tap = s >> 2, cib = s & 3;
      int kh = tap / 3, kw = tap % 3;
      short8 a[2];
#pragma unroll
      for (int m = 0; m < 2; ++m) {
        int p = (wm * 2 + m) * 16 + col;
        int pp = ((p >> 3) + kh) * 10 + (p & 7) + kw;
        int slot = (cib * 32 + g4 * 8 + pp * 8) & 127;
        a[m] = *(const short8*)&comb[pp * 128 + slot];
      }
#pragma unroll
      for (int m = 0; m < 2; ++m)
#pragma unroll
        for (int g = 0; g < 5; ++g) acc1[m][g] = mfma16(a[m], bb1[g], acc1[m][g]);
      if (s < 35) {
#pragma unroll
        for (int g = 0; g < 5; ++g) bb1[g] = bbn[g];
      }
    }

    float ctv[8];
    unsigned oav[8];
    {
      float bi0 = conv_b[ch], bi1 = conv_b[64 + ch], bi2 = conv_b[128 + ch];
      float bi3 = conv_b[192 + ch], bi4 = conv_b[256 + ch];
#pragma unroll
      for (int m = 0; m < 2; ++m)
#pragma unroll
        for (int r = 0; r < 4; ++r) {
          int p = (wm * 2 + m) * 16 + g4 * 4 + r;
          float iv = sigm(acc1[m][0][r] + bi0);
          float fv = sigm(acc1[m][1][r] + bi1);
          float ov = sigm(acc1[m][2][r] + bi2);
          float gv = ftanh(acc1[m][3][r] + bi3);
          float av = sigm(acc1[m][4][r] + bi4);
          ctv[m * 4 + r] = fv * Xb[ch * 65 + p] + iv * gv;
          oav[m * 4 + r] = ((unsigned)(unsigned short)f2bf(av) << 16) |
                           (unsigned)(unsigned short)f2bf(ov);
        }
    }
    __syncthreads();  // conv tile + Xb(c) consumed
#pragma unroll
    for (int m = 0; m < 2; ++m)
#pragma unroll
      for (int r = 0; r < 4; ++r) {
        int p = (wm * 2 + m) * 16 + g4 * 4 + r;
        combf[ch * 65 + p] = ctv[m * 4 + r];
        Xbu[ch * 65 + p] = oav[m * 4 + r];
      }
    __syncthreads();
#pragma unroll
    for (int i = 0; i < 2; ++i) {  // coalesced scratch writes
      int idx = (tid + 512 * i) * 4;
      int c = idx >> 6, p0 = idx & 63;
      f32x4 cq;
      u32x4 oq;
#pragma unroll
      for (int j = 0; j < 4; ++j) {
        cq[j] = combf[c * 65 + p0 + j];
        oq[j] = Xbu[c * 65 + p0 + j];
      }
      *(f32x4*)&ws_ct[(size_t)b * 4096 + idx] = cq;
      *(u32x4*)&ws_oa[(size_t)b * 4096 + idx] = oq;
    }
  }
}

// tail_k: V-stream + PV + conv3 + residual + LN + LSTM epilogue (fused).
__launch_bounds__(512, 4)
__global__ void tail_k(const float* __restrict__ input, const float* __restrict__ cv,
                       const float* __restrict__ ws_wt,
                       const float* __restrict__ ws_ct,
                       const unsigned* __restrict__ ws_oa,
                       const float* __restrict__ out_b,
                       const float* __restrict__ ln_w, const float* __restrict__ ln_b,
                       const short* __restrict__ pk3,
                       float* __restrict__ o_h, float* __restrict__ o_c,
                       float* __restrict__ o_v) {
  __shared__ short comb[8320];  // 64ch tile; aliased as f32[4160]
  __shared__ float Xb[4160];
  __shared__ float wt_s[64];
  __shared__ float red[16];
  float* combf = (float*)comb;
  unsigned* Xbu = (unsigned*)Xb;

  const int b = blockIdx.x;
  const int tid = threadIdx.x;
  const int wave = tid >> 6, lane = tid & 63;
  const int col = lane & 15, g4 = lane >> 4;
  const int wc = wave >> 1, wm = wave & 1;
  const int ch = wc * 16 + col;
  const int hd = wave;
  const int d0 = lane * 4, d1 = (lane + 64) * 4;

  // early independent loads: gate scratch (consumed in epilogue)
  f32x4 ctr[2];
  u32x4 oar[2];
#pragma unroll
  for (int i = 0; i < 2; ++i) {
    int idx = (tid + 512 * i) * 4;
    ctr[i] = ld4(&ws_ct[(size_t)b * 4096 + idx]);
    oar[i] = *(const u32x4*)&ws_oa[(size_t)b * 4096 + idx];
  }
  if (tid < 64) wt_s[tid] = ws_wt[(size_t)b * 64 + tid];

  // stage input -> Xb (residual), zero pad ring of conv tile
#pragma unroll
  for (int i = 0; i < 2; ++i) {
    int idx = (tid + 512 * i) * 4;
    int c = idx >> 6, p0 = idx & 63;
    f32x4 vi = ld4(&input[b * 4096 + idx]);
#pragma unroll
    for (int j = 0; j < 4; ++j) Xb[c * 65 + p0 + j] = vi[j];
  }
  for (int i = tid; i < 2304; i += 512) {  // pad ring
    int pr = i >> 6, c = i & 63;
    int pp = (pr < 10) ? pr
             : (pr < 20) ? (80 + pr)
             : (pr < 28) ? ((pr - 19) * 10)
                         : ((pr - 27) * 10 + 9);
    comb[pp * 64 + c] = 0;
  }
  __syncthreads();  // wt_s ready

  // ---- V-stream + PV: wave == head ----
  float wv[8];
#pragma unroll
  for (int m = 0; m < 8; ++m) wv[m] = wt_s[hd * 8 + m];

  f32x4 a0 = (f32x4){0.f, 0.f, 0.f, 0.f};
  f32x4 a1 = (f32x4){0.f, 0.f, 0.f, 0.f};
#pragma unroll
  for (int m = 0; m < 7; ++m) {
    const float* vp = cv + ((size_t)((b * 8 + m + 1) * 8 + hd)) * 512;
    f32x4 v0 = ld4(vp + d0);
    f32x4 v1 = ld4(vp + d1);
    float* dst = o_v + ((size_t)((b * 8 + m) * 8 + hd)) * 512;
    ntst4(dst + d0, v0);
    ntst4(dst + d1, v1);
    a0 += v0 * wv[m];
    a1 += v1 * wv[m];
  }
  {  // slot 7: written by mid2_k (plain store, cache-resident)
    const float* vp = o_v + ((size_t)((b * 8 + 7) * 8 + hd)) * 512;
    a0 += ld4(vp + d0) * wv[7];
    a1 += ld4(vp + d1) * wv[7];
  }
  // attn -> rotated bf16 conv tile
#pragma unroll
  for (int j = 0; j < 4; ++j) {
    int dA = d0 + j, dB = d1 + j;
    int cA = hd * 8 + (dA >> 6), pA = dA & 63;
    int cB = hd * 8 + (dB >> 6), pB = dB & 63;
    int ppA = ((pA >> 3) + 1) * 10 + (pA & 7) + 1;
    int ppB = ((pB >> 3) + 1) * 10 + (pB & 7) + 1;
    comb[ppA * 64 + ((cA + ppA * 8) & 63)] = f2bf(a0[j]);
    comb[ppB * 64 + ((cB + ppB * 8) & 63)] = f2bf(a1[j]);
  }
  __syncthreads();

  // conv3: M=64 N=64 K=576
  f32x4 acc3[2];
  acc3[0] = (f32x4){0.f, 0.f, 0.f, 0.f};
  acc3[1] = (f32x4){0.f, 0.f, 0.f, 0.f};
  short8 bb3 = *(const short8*)&pk3[((g4)*64 + ch) * 8];
  for (int s = 0; s < 18; ++s) {
    short8 bbn;
    if (s < 17) {
      int kb8 = (s + 1) * 4 + g4;
      bbn = *(const short8*)&pk3[(kb8 * 64 + ch) * 8];
    }
    int tap = s >> 1, cib = s & 1;
    int kh = tap / 3, kw = tap % 3;
    short8 a[2];
#pragma unroll
    for (int m = 0; m < 2; ++m) {
      int p = (wm * 2 + m) * 16 + col;
      int pp = ((p >> 3) + kh) * 10 + (p & 7) + kw;
      int slot = (cib * 32 + g4 * 8 + pp * 8) & 63;
      a[m] = *(const short8*)&comb[pp * 64 + slot];
    }
#pragma unroll
    for (int m = 0; m < 2; ++m) acc3[m] = mfma16(a[m], bb3, acc3[m]);
    if (s < 17) bb3 = bbn;
  }

  // residual + LN stats
  float ov_[8], s1 = 0.f, s2 = 0.f;
  {
    float ob = out_b[ch];
#pragma unroll
    for (int m = 0; m < 2; ++m)
#pragma unroll
      for (int r = 0; r < 4; ++r) {
        int p = (wm * 2 + m) * 16 + g4 * 4 + r;
        float v = acc3[m][r] + ob + Xb[ch * 65 + p];
        ov_[m * 4 + r] = v;
        s1 += v;
        s2 += v * v;
      }
  }
#pragma unroll
  for (int off = 32; off >= 1; off >>= 1) {
    s1 += __shfl_xor(s1, off);
    s2 += __shfl_xor(s2, off);
  }
  if (lane == 0) { red[wave] = s1; red[8 + wave] = s2; }
  __syncthreads();
  float ts1 = 0.f, ts2 = 0.f;
#pragma unroll
  for (int w = 0; w < 8; ++w) { ts1 += red[w]; ts2 += red[8 + w]; }
  float mu = ts1 * (1.0f / 4096.0f);
  float var = ts2 * (1.0f / 4096.0f) - mu * mu;
  float rstd = rsqrtf(var + 1e-5f);

  // bounce gate scratch regs (idx-order) -> LDS (ch,p)-order
#pragma unroll
  for (int i = 0; i < 2; ++i) {
    int idx = (tid + 512 * i) * 4;
    int c = idx >> 6, p0 = idx & 63;
#pragma unroll
    for (int j = 0; j < 4; ++j) {
      combf[c * 65 + p0 + j] = ctr[i][j];
      Xbu[c * 65 + p0 + j] = oar[i][j];
    }
  }
  __syncthreads();

  // epilogue: each lane owns its (ch,p)
#pragma unroll
  for (int m = 0; m < 2; ++m)
#pragma unroll
    for (int r = 0; r < 4; ++r) {
      int p = (wm * 2 + m) * 16 + g4 * 4 + r;
      float ct = combf[ch * 65 + p];
      unsigned u = Xbu[ch * 65 + p];
      float og = __builtin_bit_cast(float, u << 16);
      float ag = __builtin_bit_cast(float, u & 0xffff0000u);
      float oln = (ov_[m * 4 + r] - mu) * rstd * ln_w[ch * 64 + p] + ln_b[ch * 64 + p];
      float cn = ct + ag * ftanh(oln);
      float hv = og * ftanh(cn);
      combf[ch * 65 + p] = hv;
      Xb[ch * 65 + p] = cn;
    }
  __syncthreads();
#pragma unroll
  for (int i = 0; i < 2; ++i) {
    int idx = (tid + 512 * i) * 4;
    int c = idx >> 6, p0 = idx & 63;
    f32x4 hq, cq;
#pragma unroll
    for (int j = 0; j < 4; ++j) {
      hq[j] = combf[c * 65 + p0 + j];
      cq[j] = Xb[c * 65 + p0 + j];
    }
    *(f32x4*)&o_h[b * 4096 + idx] = hq;
    *(f32x4*)&o_c[b * 4096 + idx] = cq;
  }
}

// ===========================================================================
// Fallback path (R3, proven): used only if ws_size < 24 MB.
// ===========================================================================
__launch_bounds__(512, 4)
__global__ void kqv_k(const float* __restrict__ input,
                      const float* __restrict__ proj_b,
                      const float* __restrict__ pos_w,
                      const short* __restrict__ pk2,
                      float* __restrict__ q_out, float* __restrict__ o_k,
                      float* __restrict__ o_v) {
  __shared__ short comb[6400];
  __shared__ float Xk[4160], Xq[4160], Xv[4160];
  const int b = blockIdx.x;
  const int tid = threadIdx.x;
  const int wave = tid >> 6, lane = tid & 63;
  const int col = lane & 15, g4 = lane >> 4;
  const int wc = wave >> 1, wm = wave & 1;
  const int ch = wc * 16 + col;
#pragma unroll
  for (int i = 0; i < 2; ++i) {
    int idx = (tid + 512 * i) * 4;
    int c = idx >> 6, p0 = idx & 63;
    f32x4 vi = ld4(&input[b * 4096 + idx]);
#pragma unroll
    for (int j = 0; j < 4; ++j) {
      int p = p0 + j;
      int pp = ((p >> 3) + 1) * 10 + (p & 7) + 1;
      comb[pp * 64 + ((c + pp * 8) & 63)] = f2bf(vi[j]);
    }
  }
  for (int i = tid; i < 2304; i += 512) {
    int pr = i >> 6, c = i & 63;
    int pp = (pr < 10) ? pr
             : (pr < 20) ? (80 + pr)
             : (pr < 28) ? ((pr - 19) * 10)
                         : ((pr - 27) * 10 + 9);
    comb[pp * 64 + c] = 0;
  }
  __syncthreads();
  f32x4 acc2[2][3];
#pragma unroll
  for (int m = 0; m < 2; ++m)
#pragma unroll
    for (int g = 0; g < 3; ++g) acc2[m][g] = (f32x4){0.f, 0.f, 0.f, 0.f};
  short8 bb2[3];
#pragma unroll
  for (int g = 0; g < 3; ++g)
    bb2[g] = *(const short8*)&pk2[((g4)*192 + g * 64 + ch) * 8];
  for (int s = 0; s < 18; ++s) {
    short8 bbn[3];
    if (s < 17) {
      int kb8 = (s + 1) * 4 + g4;
#pragma unroll
      for (int g = 0; g < 3; ++g)
        bbn[g] = *(const short8*)&pk2[(kb8 * 192 + g * 64 + ch) * 8];
    }
    int tap = s >> 1, cib = s & 1;
    int kh = tap / 3, kw = tap % 3;
    short8 a[2];
#pragma unroll
    for (int m = 0; m < 2; ++m) {
      int p = (wm * 2 + m) * 16 + col;
      int pp = ((p >> 3) + kh) * 10 + (p & 7) + kw;
      int slot = (cib * 32 + g4 * 8 + pp * 8) & 63;
      a[m] = *(const short8*)&comb[pp * 64 + slot];
    }
#pragma unroll
    for (int m = 0; m < 2; ++m)
#pragma unroll
      for (int g = 0; g < 3; ++g) acc2[m][g] = mfma16(a[m], bb2[g], acc2[m][g]);
    if (s < 17) {
#pragma unroll
      for (int g = 0; g < 3; ++g) bb2[g] = bbn[g];
    }
  }
  {
    float pb0 = proj_b[ch], pb1 = proj_b[64 + ch], pb2 = proj_b[128 + ch];
    const float rsq = 0.044194173824159216f;
#pragma unroll
    for (int m = 0; m < 2; ++m)
#pragma unroll
      for (int r = 0; r < 4; ++r) {
        int p = (wm * 2 + m) * 16 + g4 * 4 + r;
        Xk[ch * 65 + p] = acc2[m][0][r] + pb0 + pos_w[7 * 4096 + ch * 64 + p];
        Xq[ch * 65 + p] = (acc2[m][1][r] + pb1) * rsq;
        Xv[ch * 65 + p] = acc2[m][2][r] + pb2;
      }
  }
  __syncthreads();
  const size_t base7 = (size_t)(b * 64 + 56) * 512;
#pragma unroll
  for (int i = 0; i < 2; ++i) {
    int idx = (tid + 512 * i) * 4;
    int c = idx >> 6, p0 = idx & 63;
    f32x4 kq, qq, vq;
#pragma unroll
    for (int j = 0; j < 4; ++j) {
      kq[j] = Xk[c * 65 + p0 + j];
      qq[j] = Xq[c * 65 + p0 + j];
      vq[j] = Xv[c * 65 + p0 + j];
    }
    *(f32x4*)&o_k[base7 + idx] = kq;
    *(f32x4*)&q_out[(size_t)b * 4096 + idx] = qq;
    *(f32x4*)&o_v[base7 + idx] = vq;
  }
}

__launch_bounds__(64, 4)
__global__ void attn_k(const float* __restrict__ ck, const float* __restrict__ cv,
                       const int* __restrict__ amask,
                       const float* __restrict__ pos_w,
                       const float* __restrict__ pos_b,
                       const float* __restrict__ q_in,
                       float* __restrict__ o_k, float* __restrict__ o_v,
                       float* __restrict__ attn_out) {
  const int b = blockIdx.x >> 3;
  const int hd = blockIdx.x & 7;
  const int lane = threadIdx.x;
  const int d0 = lane * 4, d1 = (lane + 64) * 4;
  const float* qp = q_in + (size_t)b * 4096 + hd * 512;
  f32x4 q0 = ld4(qp + d0);
  f32x4 q1 = ld4(qp + d1);
  float sc[8];
#pragma unroll
  for (int m = 0; m < 7; ++m) {
    const float* kp = ck + ((size_t)((b * 8 + m + 1) * 8 + hd)) * 512;
    const float* pw = pos_w + m * 4096 + hd * 512;
    f32x4 k0 = ld4(kp + d0) + ld4(pw + d0);
    f32x4 k1 = ld4(kp + d1) + ld4(pw + d1);
    float* dst = o_k + ((size_t)((b * 8 + m) * 8 + hd)) * 512;
    ntst4(dst + d0, k0);
    ntst4(dst + d1, k1);
    float part = 0.f;
#pragma unroll
    for (int j = 0; j < 4; ++j) {
      part = fmaf(q0[j], k0[j], part);
      part = fmaf(q1[j], k1[j], part);
    }
#pragma unroll
    for (int off = 32; off >= 1; off >>= 1) part += __shfl_xor(part, off);
    float msk = amask[(b * 8 + hd) * 8 + m] ? -__builtin_inff() : 0.0f;
    sc[m] = part + pos_b[m * 8 + hd] + msk;
  }
  {
    const float* kp = o_k + ((size_t)((b * 8 + 7) * 8 + hd)) * 512;
    f32x4 k0 = ld4(kp + d0);
    f32x4 k1 = ld4(kp + d1);
    float part = 0.f;
#pragma unroll
    for (int j = 0; j < 4; ++j) {
      part = fmaf(q0[j], k0[j], part);
      part = fmaf(q1[j], k1[j], part);
    }
#pragma unroll
    for (int off = 32; off >= 1; off >>= 1) part += __shfl_xor(part, off);
    sc[7] = part + pos_b[7 * 8 + hd] + 5.0f;
  }
  float mx = sc[0];
#pragma unroll
  for (int m = 1; m < 8; ++m) mx = fmaxf(mx, sc[m]);
  float w[8], s = 0.f;
#pragma unroll
  for (int m = 0; m < 8; ++m) {
    w[m] = __expf(sc[m] - mx);
    s += w[m];
  }
  float inv = 1.0f / s;
#pragma unroll
  for (int m = 0; m < 8; ++m) w[m] *= inv;
  f32x4 a0 = (f32x4){0.f, 0.f, 0.f, 0.f};
  f32x4 a1 = (f32x4){0.f, 0.f, 0.f, 0.f};
#pragma unroll
  for (int m = 0; m < 7; ++m) {
    const float* vp = cv + ((size_t)((b * 8 + m + 1) * 8 + hd)) * 512;
    f32x4 v0 = ld4(vp + d0);
    f32x4 v1 = ld4(vp + d1);
    float* dst = o_v + ((size_t)((b * 8 + m) * 8 + hd)) * 512;
    ntst4(dst + d0, v0);
    ntst4(dst + d1, v1);
    a0 += v0 * w[m];
    a1 += v1 * w[m];
  }
  {
    const float* vp = o_v + ((size_t)((b * 8 + 7) * 8 + hd)) * 512;
    a0 += ld4(vp + d0) * w[7];
    a1 += ld4(vp + d1) * w[7];
  }
  float* ap = attn_out + (size_t)b * 4096 + hd * 512;
  *(f32x4*)&ap[d0] = a0;
  *(f32x4*)&ap[d1] = a1;
}

__launch_bounds__(512, 4)
__global__ void cell2_k(
    const float* __restrict__ input, const float* __restrict__ h_cur,
    const float* __restrict__ c_cur, const float* __restrict__ attn_in,
    const float* __restrict__ conv_b, const float* __restrict__ out_b,
    const float* __restrict__ ln_w, const float* __restrict__ ln_b,
    const short* __restrict__ pk1, const short* __restrict__ pk3,
    float* __restrict__ o_h, float* __restrict__ o_c) {
  __shared__ short comb[12800];
  __shared__ float Xb[4160];
  __shared__ float Qb[4160];
  __shared__ float Vb[4160];
  __shared__ float red[16];
  const int b = blockIdx.x;
  const int tid = threadIdx.x;
  const int wave = tid >> 6, lane = tid & 63;
  const int col = lane & 15, g4 = lane >> 4;
  const int wc = wave >> 1, wm = wave & 1;
  const int ch = wc * 16 + col;
#pragma unroll
  for (int i = 0; i < 2; ++i) {
    int idx = (tid + 512 * i) * 4;
    int c = idx >> 6, p0 = idx & 63;
    f32x4 vi = ld4(&input[b * 4096 + idx]);
    f32x4 vh = ld4(&h_cur[b * 4096 + idx]);
    f32x4 vc = ld4(&c_cur[b * 4096 + idx]);
#pragma unroll
    for (int j = 0; j < 4; ++j) {
      int p = p0 + j;
      int pp = ((p >> 3) + 1) * 10 + (p & 7) + 1;
      comb[pp * 128 + ((c + pp * 8) & 127)] = f2bf(vi[j]);
      comb[pp * 128 + ((c + 64 + pp * 8) & 127)] = f2bf(vh[j]);
      Xb[c * 65 + p] = vc[j];
    }
  }
  for (int i = tid; i < 4608; i += 512) {
    int pr = i >> 7, c = i & 127;
    int pp = (pr < 10) ? pr
             : (pr < 20) ? (80 + pr)
             : (pr < 28) ? ((pr - 19) * 10)
                         : ((pr - 27) * 10 + 9);
    comb[pp * 128 + c] = 0;
  }
  __syncthreads();
  f32x4 acc1[2][5];
#pragma unroll
  for (int m = 0; m < 2; ++m)
#pragma unroll
    for (int g = 0; g < 5; ++g) acc1[m][g] = (f32x4){0.f, 0.f, 0.f, 0.f};
  short8 bb1[5];
#pragma unroll
  for (int g = 0; g < 5; ++g)
    bb1[g] = *(const short8*)&pk1[((g4)*320 + g * 64 + ch) * 8];
  for (int s = 0; s < 36; ++s) {
    short8 bbn[5];
    if (s < 35) {
      int kb8 = (s + 1) * 4 + g4;
#pragma unroll
      for (int g = 0; g < 5; ++g)
        bbn[g] = *(const short8*)&pk1[(kb8 * 320 + g * 64 + ch) * 8];
    }
    int tap = s >> 2, cib = s & 3;
    int kh = tap / 3, kw = tap % 3;
    short8 a[2];
#pragma unroll
    for (int m = 0; m < 2; ++m) {
      int p = (wm * 2 + m) * 16 + col;
      int pp = ((p >> 3) + kh) * 10 + (p & 7) + kw;
      int slot = (cib * 32 + g4 * 8 + pp * 8) & 127;
      a[m] = *(const short8*)&comb[pp * 128 + slot];
    }
#pragma unroll
    for (int m = 0; m < 2; ++m)
#pragma unroll
      for (int g = 0; g < 5; ++g) acc1[m][g] = mfma16(a[m], bb1[g], acc1[m][g]);
    if (s < 35) {
#pragma unroll
      for (int g = 0; g < 5; ++g) bb1[g] = bbn[g];
    }
  }
  float ct_r[8], o_r[8], a_r[8];
  {
    float bi0 = conv_b[ch], bi1 = conv_b[64 + ch], bi2 = conv_b[128 + ch];
    float bi3 = conv_b[192 + ch], bi4 = conv_b[256 + ch];
#pragma unroll
    for (int m = 0; m < 2; ++m)
#pragma unroll
      for (int r = 0; r < 4; ++r) {
        int p = (wm * 2 + m) * 16 + g4 * 4 + r;
        float iv = sigm(acc1[m][0][r] + bi0);
        float fv = sigm(acc1[m][1][r] + bi1);
        float ov = sigm(acc1[m][2][r] + bi2);
        float gv = ftanh(acc1[m][3][r] + bi3);
        float av = sigm(acc1[m][4][r] + bi4);
        ct_r[m * 4 + r] = fv * Xb[ch * 65 + p] + iv * gv;
        o_r[m * 4 + r] = ov;
        a_r[m * 4 + r] = av;
      }
  }
  __syncthreads();
  {
    f32x4 av[2], iv[2];
#pragma unroll
    for (int i = 0; i < 2; ++i) {
      int idx = (tid + 512 * i) * 4;
      av[i] = ld4(&attn_in[b * 4096 + idx]);
      iv[i] = ld4(&input[b * 4096 + idx]);
    }
#pragma unroll
    for (int i = 0; i < 2; ++i) {
      int idx = (tid + 512 * i) * 4;
      int c = idx >> 6, p0 = idx & 63;
#pragma unroll
      for (int j = 0; j < 4; ++j) {
        int p = p0 + j;
        int pp = ((p >> 3) + 1) * 10 + (p & 7) + 1;
        comb[pp * 128 + ((c + pp * 8) & 127)] = f2bf(av[i][j]);
        Xb[c * 65 + p] = iv[i][j];
      }
    }
  }
  __syncthreads();
  f32x4 acc3[2];
  acc3[0] = (f32x4){0.f, 0.f, 0.f, 0.f};
  acc3[1] = (f32x4){0.f, 0.f, 0.f, 0.f};
  short8 bb3 = *(const short8*)&pk3[((g4)*64 + ch) * 8];
  for (int s = 0; s < 18; ++s) {
    short8 bbn;
    if (s < 17) {
      int kb8 = (s + 1) * 4 + g4;
      bbn = *(const short8*)&pk3[(kb8 * 64 + ch) * 8];
    }
    int tap = s >> 1, cib = s & 1;
    int kh = tap / 3, kw = tap % 3;
    short8 a[2];
#pragma unroll
    for (int m = 0; m < 2; ++m) {
      int p = (wm * 2 + m) * 16 + col;
      int pp = ((p >> 3) + kh) * 10 + (p & 7) + kw;
      int slot = (cib * 32 + g4 * 8 + pp * 8) & 127;
      a[m] = *(const short8*)&comb[pp * 128 + slot];
    }
#pragma unroll
    for (int m = 0; m < 2; ++m) acc3[m] = mfma16(a[m], bb3, acc3[m]);
    if (s < 17) bb3 = bbn;
  }
  float ov_[8], s1 = 0.f, s2 = 0.f;
  {
    float ob = out_b[ch];
#pragma unroll
    for (int m = 0; m < 2; ++m)
#pragma unroll
      for (int r = 0; r < 4; ++r) {
        int p = (wm * 2 + m) * 16 + g4 * 4 + r;
        float v = acc3[m][r] + ob + Xb[ch * 65 + p];
        ov_[m * 4 + r] = v;
        s1 += v;
        s2 += v * v;
      }
  }
#pragma unroll
  for (int off = 32; off >= 1; off >>= 1) {
    s1 += __shfl_xor(s1, off);
    s2 += __shfl_xor(s2, off);
  }
  if (lane == 0) { red[wave] = s1; red[8 + wave] = s2; }
  __syncthreads();
  float ts1 = 0.f, ts2 = 0.f;
#pragma unroll
  for (int w = 0; w < 8; ++w) { ts1 += red[w]; ts2 += red[8 + w]; }
  float mu = ts1 * (1.0f / 4096.0f);
  float var = ts2 * (1.0f / 4096.0f) - mu * mu;
  float rstd = rsqrtf(var + 1e-5f);
#pragma unroll
  for (int m = 0; m < 2; ++m)
#pragma unroll
    for (int r = 0; r < 4; ++r) {
      int p = (wm * 2 + m) * 16 + g4 * 4 + r;
      float oln = (ov_[m * 4 + r] - mu) * rstd * ln_w[ch * 64 + p] + ln_b[ch * 64 + p];
      float cn = ct_r[m * 4 + r] + a_r[m * 4 + r] * ftanh(oln);
      float hv = o_r[m * 4 + r] * ftanh(cn);
      Qb[ch * 65 + p] = hv;
      Vb[ch * 65 + p] = cn;
    }
  __syncthreads();
#pragma unroll
  for (int i = 0; i < 2; ++i) {
    int idx = (tid + 512 * i) * 4;
    int c = idx >> 6, p0 = idx & 63;
    f32x4 hv, cvv;
#pragma unroll
    for (int j = 0; j < 4; ++j) {
      hv[j] = Qb[c * 65 + p0 + j];
      cvv[j] = Vb[c * 65 + p0 + j];
    }
    *(f32x4*)&o_h[b * 4096 + idx] = hv;
    *(f32x4*)&o_c[b * 4096 + idx] = cvv;
  }
}

extern "C" void kernel_launch(void* const* d_in, const int* in_sizes, int n_in,
                              void* d_out, int out_size, void* d_ws, size_t ws_size,
                              hipStream_t stream) {
  (void)in_sizes; (void)n_in; (void)out_size;
  const float* input  = (const float*)d_in[0];
  const float* h_cur  = (const float*)d_in[1];
  const float* c_cur  = (const float*)d_in[2];
  const float* ck     = (const float*)d_in[3];
  const float* cv     = (const float*)d_in[4];
  const int*   amask  = (const int*)d_in[5];
  const float* conv_w = (const float*)d_in[6];
  const float* conv_b = (const float*)d_in[7];
  const float* proj_w = (const float*)d_in[8];
  const float* proj_b = (const float*)d_in[9];
  const float* out_w  = (const float*)d_in[10];
  const float* out_b  = (const float*)d_in[11];
  const float* ln_w   = (const float*)d_in[12];
  const float* ln_b   = (const float*)d_in[13];
  const float* pos_w  = (const float*)d_in[14];
  const float* pos_b  = (const float*)d_in[15];

  char* ws = (char*)d_ws;
  short* pk = (short*)ws;  // 516096 shorts = 1.03 MB
  float* o_h = (float*)d_out;
  float* o_c = o_h + 2097152;
  float* o_k = o_h + 4194304;
  float* o_v = o_h + 20971520;

  pack_w<<<252, 256, 0, stream>>>(conv_w, proj_w, out_w, pk);

  if (ws_size >= (24u << 20)) {
    float* ws_wt = (float*)(ws + (2u << 20));        // 128 KB softmax weights
    float* ws_ct = (float*)(ws + (8u << 20));        // 8 MB f32
    unsigned* ws_oa = (unsigned*)(ws + (16u << 20)); // 8 MB packed bf16x2
    mid2_k<<<1024, 512, 0, stream>>>(input, h_cur, c_cur, ck, amask,
                                     conv_b, proj_b, pos_w, pos_b,
                                     pk, pk + 368640,
                                     o_k, o_v, ws_wt, ws_ct, ws_oa);
    tail_k<<<512, 512, 0, stream>>>(input, cv, ws_wt, ws_ct, ws_oa,
                                    out_b, ln_w, ln_b, pk + 479232,
                                    o_h, o_c, o_v);
  } else {
    // fallback: proven R3 pipeline (scratch lives in d_out regions)
    kqv_k<<<512, 512, 0, stream>>>(input, proj_b, pos_w, pk + 368640,
                                   o_h, o_k, o_v);
    attn_k<<<4096, 64, 0, stream>>>(ck, cv, amask, pos_w, pos_b, o_h,
                                    o_k, o_v, o_c);
    cell2_k<<<512, 512, 0, stream>>>(input, h_cur, c_cur, o_c,
                                     conv_b, out_b, ln_w, ln_b,
                                     pk, pk + 479232, o_h, o_c);
  }
}